// Round 2
// baseline (475.926 us; speedup 1.0000x reference)
//
#include <hip/hip_runtime.h>

// HGCN forward (2-layer hyperbolic GCN), Poincare ball c=1. fp32 in/out
// (values bf16-grid). Round 12 = round 11 with:
//  (a) DIM-SPLIT tangent tables: xlo/xhi two 5.12MB half-tables (dims 0-31 /
//      32-63). Each gather = 2 dispatches, one per half: random working set
//      5.12MB (~78% L2-resident vs 39%), 4 rows per wave-load (16-lane u32),
//      disjoint output dims (no RMW). gather_out finalize folded into hi pass.
//  (b) layer1 overlap rebalanced: count_rank carries 500 l1-vblocks (2048-wide
//      grid, good spread), scan 150, fill 600 (was 0/512/738 -- scan's 1024-thr
//      grid spread layer1 over too few CUs).
//  (c) count/fill edge loads vectorized int4/float4 (4 edges/thread, exact grid).
// Tiers: A (rank fill) -> B (atomic fill) -> round-9 fallback.

#define EPSV 1e-15f
#define MAXN 0.996f   // (1 - 4e-3) / sqrt(c), c = 1

typedef unsigned short bfu;
typedef __attribute__((ext_vector_type(8))) short v8s;   // 8 bf16 (4 VGPRs)
typedef __attribute__((ext_vector_type(4))) float v4f;   // MFMA acc

__device__ __forceinline__ bfu f2b(float f) {   // fp32 -> bf16, RNE
    unsigned int u;
    __builtin_memcpy(&u, &f, sizeof(u));
    u += 0x7fffu + ((u >> 16) & 1u);
    return (bfu)(u >> 16);
}

__device__ __forceinline__ float b2f(bfu s) {
    unsigned int u = ((unsigned int)s) << 16;
    float f;
    __builtin_memcpy(&f, &u, sizeof(f));
    return f;
}

// low/high bf16 of a packed u32 -> fp32
__device__ __forceinline__ float uplo(unsigned int u) {
    unsigned int v = u << 16; float f;
    __builtin_memcpy(&f, &v, sizeof(f)); return f;
}
__device__ __forceinline__ float uphi(unsigned int u) {
    unsigned int v = u & 0xffff0000u; float f;
    __builtin_memcpy(&f, &v, sizeof(f)); return f;
}

__device__ __forceinline__ v8s cvt8(const float* f) {
    v8s r;
#pragma unroll
    for (int j = 0; j < 8; ++j) r[j] = (short)f2b(f[j]);
    return r;
}

__device__ __forceinline__ float i2f(int i) {
    float f; __builtin_memcpy(&f, &i, sizeof(f)); return f;
}
__device__ __forceinline__ int f2i(float f) {
    int i; __builtin_memcpy(&i, &f, sizeof(i)); return i;
}

__device__ __forceinline__ float wredsum(float v) {
#pragma unroll
    for (int o = 32; o > 0; o >>= 1) v += __shfl_xor(v, o, 64);
    return v;
}

__device__ __forceinline__ float artanh_(float x) {
    x = fminf(fmaxf(x, -1.0f + 1e-7f), 1.0f - 1e-7f);
    return 0.5f * logf((1.0f + x) / (1.0f - x));
}

__device__ __forceinline__ float mobius_tail(float mx, float xn, float hb, float y2) {
    float mxn2 = wredsum(mx * mx);
    unsigned long long nz = __ballot(mx != 0.0f);
    float mxn = fmaxf(sqrtf(mxn2), EPSV);
    float rt = tanhf(mxn / xn * artanh_(xn));
    float mv, x2s;
    if (nz != 0ull) {
        mv = (rt / mxn) * mx;
        float mvn = fmaxf(fabsf(rt), EPSV);
        if (mvn > MAXN) mv *= MAXN / mvn;
        float cn = fminf(mvn, MAXN);
        x2s = cn * cn;
    } else { mv = 0.0f; x2s = 0.0f; }
    float xy = wredsum(mv * hb);
    float ca = 1.0f + 2.0f * xy + y2;
    float cb = 1.0f - x2s;
    float den = fmaxf(1.0f + 2.0f * xy + x2s * y2, EPSV);
    float hj = (ca * mv + cb * hb) / den;
    float hn = fmaxf(sqrtf(wredsum(hj * hj)), EPSV);
    if (hn > MAXN) { hj *= MAXN / hn; hn = MAXN; }
    return (artanh_(hn) / hn) * hj;
}

__device__ __forceinline__ float agg_transform(float a, float* xn_out) {
    float n = fmaxf(sqrtf(wredsum(a * a)), EPSV);
    float th = tanhf(n);
    float g = th / n;
    float nh = fmaxf(th, EPSV);
    if (nh > MAXN) { g *= MAXN / nh; nh = MAXN; }
    float h = g * a;
    float t = fmaxf((artanh_(nh) / nh) * h, 0.0f);
    float n2 = fmaxf(sqrtf(wredsum(t * t)), EPSV);
    float th2 = tanhf(n2);
    float g2 = th2 / n2;
    float nh2 = fmaxf(th2, EPSV);
    if (nh2 > MAXN) { g2 *= MAXN / nh2; nh2 = MAXN; }
    *xn_out = nh2;
    return g2 * t;
}

__device__ __forceinline__ float bias_point(const float* bv, int lane, float* y2) {
    float b = bv[lane];
    float bn = fmaxf(sqrtf(wredsum(b * b)), EPSV);
    float gs = tanhf(bn) / bn;
    float hbn = fmaxf(tanhf(bn), EPSV);
    if (hbn > MAXN) gs *= MAXN / hbn;
    float hb = gs * b;
    *y2 = wredsum(hb * hb);
    return hb;
}

__global__ __launch_bounds__(256) void hgA_zero(float* __restrict__ p, int n4) {
    const float4 z = make_float4(0.f, 0.f, 0.f, 0.f);
    int stride = gridDim.x * blockDim.x;
    for (int i = blockIdx.x * blockDim.x + threadIdx.x; i < n4; i += stride)
        ((float4*)p)[i] = z;
}

// ===== layer1 body (MFMA, proven) -- writes bf16 split tables =====
__device__ __forceinline__ void layer1_body(
    int bid, int tid, const float* __restrict__ x, const float* __restrict__ W1,
    const float* __restrict__ b1v, bfu* __restrict__ xlo, bfu* __restrict__ xhi,
    int N)
{
    const int lane = tid & 63, wv = tid >> 6;
    const int nodeBase = (bid * 4 + wv) * 16;
    if (nodeBase >= N) return;

    float y2;
    float hb = bias_point(b1v, lane, &y2);
    float hbv[4];
#pragma unroll
    for (int t = 0; t < 4; ++t) hbv[t] = __shfl(hb, (lane & 15) + 16 * t);

    const int m = lane & 15, q = lane >> 4;
    v4f acc0 = {0,0,0,0}, acc1 = {0,0,0,0}, acc2 = {0,0,0,0}, acc3 = {0,0,0,0};
    float usq = 0.0f;

    const float* arow = x + (size_t)(nodeBase + m) * 256 + q * 8;
#pragma unroll
    for (int s = 0; s < 8; ++s) {
        float af[8];
        *(float4*)(af)     = *(const float4*)(arow + s * 32);
        *(float4*)(af + 4) = *(const float4*)(arow + s * 32 + 4);
#pragma unroll
        for (int j = 0; j < 8; ++j) usq = fmaf(af[j], af[j], usq);
        v8s a = cvt8(af);
        const float* wbase = W1 + (size_t)m * 256 + s * 32 + q * 8;
        float wf[8];
        *(float4*)(wf) = *(const float4*)(wbase);
        *(float4*)(wf + 4) = *(const float4*)(wbase + 4);
        acc0 = __builtin_amdgcn_mfma_f32_16x16x32_bf16(a, cvt8(wf), acc0, 0, 0, 0);
        *(float4*)(wf) = *(const float4*)(wbase + 16 * 256);
        *(float4*)(wf + 4) = *(const float4*)(wbase + 16 * 256 + 4);
        acc1 = __builtin_amdgcn_mfma_f32_16x16x32_bf16(a, cvt8(wf), acc1, 0, 0, 0);
        *(float4*)(wf) = *(const float4*)(wbase + 32 * 256);
        *(float4*)(wf + 4) = *(const float4*)(wbase + 32 * 256 + 4);
        acc2 = __builtin_amdgcn_mfma_f32_16x16x32_bf16(a, cvt8(wf), acc2, 0, 0, 0);
        *(float4*)(wf) = *(const float4*)(wbase + 48 * 256);
        *(float4*)(wf + 4) = *(const float4*)(wbase + 48 * 256 + 4);
        acc3 = __builtin_amdgcn_mfma_f32_16x16x32_bf16(a, cvt8(wf), acc3, 0, 0, 0);
    }
    usq += __shfl_xor(usq, 16, 64);
    usq += __shfl_xor(usq, 32, 64);

    float P[4], Q[4];
#pragma unroll
    for (int r = 0; r < 4; ++r) {
        float s2 = acc0[r]*acc0[r] + acc1[r]*acc1[r] + acc2[r]*acc2[r] + acc3[r]*acc3[r];
        float sh = acc0[r]*hbv[0] + acc1[r]*hbv[1] + acc2[r]*hbv[2] + acc3[r]*hbv[3];
#pragma unroll
        for (int o = 1; o < 16; o <<= 1) {
            s2 += __shfl_xor(s2, o, 64);
            sh += __shfl_xor(sh, o, 64);
        }
        float usq_r = __shfl(usq, q * 4 + r);
        float n  = fmaxf(sqrtf(usq_r), EPSV);
        float th = tanhf(n);
        float gamma = th / n;
        float xn = fmaxf(th, EPSV);
        if (xn > MAXN) { gamma *= MAXN / xn; xn = MAXN; }
        float mxn = fmaxf(gamma * sqrtf(s2), EPSV);
        float rt  = tanhf(mxn / xn * artanh_(xn));
        float k1, x2s, xy;
        if (s2 != 0.0f) {
            k1 = (rt / mxn) * gamma;
            float mvn = fmaxf(fabsf(rt), EPSV);
            if (mvn > MAXN) k1 *= MAXN / mvn;
            float cn = fminf(mvn, MAXN);
            x2s = cn * cn;
            xy  = k1 * sh;
        } else { k1 = 0.0f; x2s = 0.0f; xy = 0.0f; }
        float ca = 1.0f + 2.0f * xy + y2;
        float cb = 1.0f - x2s;
        float den = fmaxf(1.0f + 2.0f * xy + x2s * y2, EPSV);
        float hn2 = ca*ca*x2s + 2.0f*ca*cb*xy + cb*cb*y2;
        float hn = fmaxf(sqrtf(hn2) / den, EPSV);
        float hs = 1.0f;
        if (hn > MAXN) { hs = MAXN / hn; hn = MAXN; }
        float lam = artanh_(hn) / hn;
        P[r] = lam * hs * ca * k1 / den;
        Q[r] = lam * hs * cb / den;
    }
#pragma unroll
    for (int r = 0; r < 4; ++r) {
        int ri = nodeBase + q * 4 + r;
        bfu* olo = xlo + (size_t)ri * 32 + m;
        bfu* ohi = xhi + (size_t)ri * 32 + m;
        olo[ 0] = f2b(P[r] * acc0[r] + Q[r] * hbv[0]);   // dim m
        olo[16] = f2b(P[r] * acc1[r] + Q[r] * hbv[1]);   // dim m+16
        ohi[ 0] = f2b(P[r] * acc2[r] + Q[r] * hbv[2]);   // dim m+32
        ohi[16] = f2b(P[r] * acc3[r] + Q[r] * hbv[3]);   // dim m+48
    }
}

// ===== CSR build =====
__global__ __launch_bounds__(256) void hgA_zero_i32(int* __restrict__ p, int n) {
    int stride = gridDim.x * blockDim.x;
    for (int i = blockIdx.x * blockDim.x + threadIdx.x; i < n; i += stride) p[i] = 0;
}

// tier B count (no rank)
__global__ __launch_bounds__(256) void hgA_count(
    const int* __restrict__ dst, int* __restrict__ deg, int E) {
    int stride = gridDim.x * blockDim.x;
    for (int e = blockIdx.x * blockDim.x + threadIdx.x; e < E; e += stride)
        atomicAdd(&deg[dst[e]], 1);
}

// tier A count_rank + layer1 share (parity-interleaved). count side:
// int4-vectorized, 4 edges/thread, exact grid (nf = ceil(E/1024)).
__global__ __launch_bounds__(256) void hgA_count_rank_l1(
    const int* __restrict__ dst, int* __restrict__ deg, int* __restrict__ rank,
    int E, int nf, int nl,
    const float* __restrict__ x, const float* __restrict__ W1,
    const float* __restrict__ b1v, bfu* __restrict__ xlo, bfu* __restrict__ xhi,
    int N)
{
    const int b = blockIdx.x;
    const int mn = nf < nl ? nf : nl;
    bool isC; int idx;
    if (b < 2 * mn) { isC = !(b & 1); idx = b >> 1; }
    else            { isC = (nf > nl); idx = mn + (b - 2 * mn); }
    if (isC) {
        int e0 = (idx * 256 + threadIdx.x) * 4;
        if (e0 + 4 <= E) {
            int4 d4 = *(const int4*)(dst + e0);
            int4 r4;
            r4.x = atomicAdd(&deg[d4.x], 1);
            r4.y = atomicAdd(&deg[d4.y], 1);
            r4.z = atomicAdd(&deg[d4.z], 1);
            r4.w = atomicAdd(&deg[d4.w], 1);
            *(int4*)(rank + e0) = r4;
        } else if (e0 < E) {
            for (int e = e0; e < E; ++e) rank[e] = atomicAdd(&deg[dst[e]], 1);
        }
    } else {
        layer1_body(idx, threadIdx.x, x, W1, b1v, xlo, xhi, N);   // l1off = 0
    }
}

// block 0: exclusive scan of deg -> row_start (+cursor). blocks >0: layer1
// vblocks [l1off, l1off+NL).
__global__ __launch_bounds__(1024) void hgA_scan_l1(
    const int* __restrict__ deg, int* __restrict__ row_start,
    int* __restrict__ cursor, int N,
    const float* __restrict__ x, const float* __restrict__ W1,
    const float* __restrict__ b1v, bfu* __restrict__ xlo, bfu* __restrict__ xhi,
    int NL, int l1off)
{
    if (blockIdx.x != 0) {
        int vb = (blockIdx.x - 1) * 4 + (threadIdx.x >> 8);
        if (vb < NL) layer1_body(l1off + vb, threadIdx.x & 255, x, W1, b1v, xlo, xhi, N);
        return;
    }
    __shared__ int wsum[16];
    __shared__ int srun;
    const int tid = threadIdx.x, lane = tid & 63, wv = tid >> 6;
    if (tid == 0) srun = 0;
    __syncthreads();
    for (int base = 0; base < N; base += 1024) {
        int i = base + tid;
        int v = (i < N) ? deg[i] : 0;
        int incl = v;
#pragma unroll
        for (int o = 1; o < 64; o <<= 1) {
            int nbr = __shfl_up(incl, o, 64);
            if (lane >= o) incl += nbr;
        }
        if (lane == 63) wsum[wv] = incl;
        __syncthreads();
        int add = 0;
#pragma unroll
        for (int w = 0; w < 16; ++w) { int s = wsum[w]; if (w < wv) add += s; }
        int excl = srun + add + incl - v;
        if (i < N) { row_start[i] = excl; cursor[i] = excl; }
        __syncthreads();
        if (tid == 1023) srun += add + incl;
        __syncthreads();
    }
    if (tid == 0) row_start[N] = srun;
}

// ===== tier B fused: fill (atomic cursor) || layer1 =====
__global__ __launch_bounds__(256) void hgA_fill_layer1(
    const int* __restrict__ src, const int* __restrict__ dst,
    const float* __restrict__ ew, int* __restrict__ cursor,
    int2* __restrict__ csr, int E, int fillBlocks,
    const float* __restrict__ x, const float* __restrict__ W1,
    const float* __restrict__ b1v, bfu* __restrict__ xlo, bfu* __restrict__ xhi,
    int N)
{
    const int b = blockIdx.x;
    if (b < fillBlocks) {
        int stride = fillBlocks * blockDim.x;
        for (int e = b * blockDim.x + threadIdx.x; e < E; e += stride) {
            int d = dst[e];
            int slot = atomicAdd(&cursor[d], 1);
            csr[slot] = make_int2(src[e], f2i(ew[e]));
        }
    } else {
        layer1_body(b - fillBlocks, threadIdx.x, x, W1, b1v, xlo, xhi, N);
    }
}

// ===== tier A fused: atomic-free fill (int4 loads) || layer1, interleaved =====
__global__ __launch_bounds__(256) void hgA_fillr_layer1(
    const int* __restrict__ src, const int* __restrict__ dst,
    const float* __restrict__ ew, const int* __restrict__ rank,
    const int* __restrict__ row_start, int2* __restrict__ csr,
    int E, int nf, int nl, int l1off,
    const float* __restrict__ x, const float* __restrict__ W1,
    const float* __restrict__ b1v, bfu* __restrict__ xlo, bfu* __restrict__ xhi,
    int N)
{
    const int b = blockIdx.x;
    const int mn = nf < nl ? nf : nl;
    bool isFill; int idx;
    if (b < 2 * mn) { isFill = !(b & 1); idx = b >> 1; }
    else            { isFill = (nf > nl); idx = mn + (b - 2 * mn); }
    if (isFill) {
        int e0 = (idx * 256 + threadIdx.x) * 4;
        if (e0 + 4 <= E) {
            int4  d4 = *(const int4*)(dst + e0);
            int4  s4 = *(const int4*)(src + e0);
            int4  r4 = *(const int4*)(rank + e0);
            float4 w4 = *(const float4*)(ew + e0);
            csr[row_start[d4.x] + r4.x] = make_int2(s4.x, f2i(w4.x));
            csr[row_start[d4.y] + r4.y] = make_int2(s4.y, f2i(w4.y));
            csr[row_start[d4.z] + r4.z] = make_int2(s4.z, f2i(w4.z));
            csr[row_start[d4.w] + r4.w] = make_int2(s4.w, f2i(w4.w));
        } else if (e0 < E) {
            for (int e = e0; e < E; ++e)
                csr[row_start[dst[e]] + rank[e]] = make_int2(src[e], f2i(ew[e]));
        }
    } else {
        layer1_body(l1off + idx, threadIdx.x, x, W1, b1v, xlo, xhi, N);
    }
}

// ===== half-table gather accumulator: 64B rows, 4 rows per wave-load =====
// lane = p4*16 + sl4; returns per-lane (dim 2*sl4, 2*sl4+1) sums, valid in
// ALL lanes (p4 groups folded).
__device__ __forceinline__ float2 gacc_half(
    int n0, int n1, const unsigned int* __restrict__ t32,
    const int2* __restrict__ csr, int lane)
{
    const int sl4 = lane & 15, p4 = lane >> 4;
    float ax0 = 0.f, ay0 = 0.f, ax1 = 0.f, ay1 = 0.f;
    float ax2 = 0.f, ay2 = 0.f, ax3 = 0.f, ay3 = 0.f;
    for (int base = n0; base < n1; base += 64) {
        int cnt = n1 - base; if (cnt > 64) cnt = 64;
        int sL = 0; float wL = 0.0f;   // lanes >= cnt keep s=0, w=0 (safe pad)
        if (lane < cnt) { int2 rec = csr[base + lane]; sL = rec.x; wL = i2f(rec.y); }
        int j = 0;
        for (; j + 16 <= cnt; j += 16) {
            int   s0 = __shfl(sL, j      + p4, 64), s1 = __shfl(sL, j +  4 + p4, 64);
            int   s2 = __shfl(sL, j +  8 + p4, 64), s3 = __shfl(sL, j + 12 + p4, 64);
            float w0 = __shfl(wL, j      + p4, 64), w1 = __shfl(wL, j +  4 + p4, 64);
            float w2 = __shfl(wL, j +  8 + p4, 64), w3 = __shfl(wL, j + 12 + p4, 64);
            unsigned int u0 = t32[(size_t)s0 * 16 + sl4];
            unsigned int u1 = t32[(size_t)s1 * 16 + sl4];
            unsigned int u2 = t32[(size_t)s2 * 16 + sl4];
            unsigned int u3 = t32[(size_t)s3 * 16 + sl4];
            ax0 = fmaf(w0, uplo(u0), ax0); ay0 = fmaf(w0, uphi(u0), ay0);
            ax1 = fmaf(w1, uplo(u1), ax1); ay1 = fmaf(w1, uphi(u1), ay1);
            ax2 = fmaf(w2, uplo(u2), ax2); ay2 = fmaf(w2, uphi(u2), ay2);
            ax3 = fmaf(w3, uplo(u3), ax3); ay3 = fmaf(w3, uphi(u3), ay3);
        }
        for (; j < cnt; j += 4) {      // j stays multiple of 4 -> j+p4 <= 63
            int   s = __shfl(sL, j + p4, 64);
            float w = __shfl(wL, j + p4, 64);
            unsigned int u = t32[(size_t)s * 16 + sl4];
            ax0 = fmaf(w, uplo(u), ax0); ay0 = fmaf(w, uphi(u), ay0);
        }
    }
    float tx = (ax0 + ax1) + (ax2 + ax3);
    float ty = (ay0 + ay1) + (ay2 + ay3);
    tx += __shfl_xor(tx, 16, 64); ty += __shfl_xor(ty, 16, 64);   // fold p4 bit0
    tx += __shfl_xor(tx, 32, 64); ty += __shfl_xor(ty, 32, 64);   // fold p4 bit1
    return make_float2(tx, ty);
}

// gather #1, one half-table -> agg dims [dimoff, dimoff+32)
__global__ __launch_bounds__(256) void hgA_gather_half(
    const int* __restrict__ row_start, const int2* __restrict__ csr,
    const bfu* __restrict__ tbl, float* __restrict__ agg, int dimoff, int N)
{
    const int lane = threadIdx.x & 63, wv = threadIdx.x >> 6;
    const int d = blockIdx.x * 4 + wv;
    if (d >= N) return;
    float2 r = gacc_half(row_start[d], row_start[d + 1],
                         (const unsigned int*)tbl, csr, lane);
    if ((lane >> 4) == 0)
        *(float2*)(agg + (size_t)d * 64 + dimoff + 2 * (lane & 15)) = r;
}

// gather #2 lo pass: partial sums (pre-transform) into out dims [0,32)
__global__ __launch_bounds__(256) void hgA_gout_lo(
    const int* __restrict__ row_start, const int2* __restrict__ csr,
    const bfu* __restrict__ tbl, float* __restrict__ out, int N)
{
    const int lane = threadIdx.x & 63, wv = threadIdx.x >> 6;
    const int d = blockIdx.x * 4 + wv;
    if (d >= N) return;
    float2 r = gacc_half(row_start[d], row_start[d + 1],
                         (const unsigned int*)tbl, csr, lane);
    if ((lane >> 4) == 0)
        *(float2*)(out + (size_t)d * 64 + 2 * (lane & 15)) = r;
}

// gather #2 hi pass + finalize: hi sums in regs, lo partial from memory,
// full-row HypAct transform, write both halves.
__global__ __launch_bounds__(256) void hgA_gout_hi_fin(
    const int* __restrict__ row_start, const int2* __restrict__ csr,
    const bfu* __restrict__ tbl, float* __restrict__ out, int N)
{
    const int lane = threadIdx.x & 63, wv = threadIdx.x >> 6;
    const int d = blockIdx.x * 4 + wv;
    if (d >= N) return;
    const int sl4 = lane & 15, p4 = lane >> 4;
    float2 hi = gacc_half(row_start[d], row_start[d + 1],
                          (const unsigned int*)tbl, csr, lane);
    float2 lo = *(const float2*)(out + (size_t)d * 64 + 2 * sl4);
    float ssq = lo.x*lo.x + lo.y*lo.y + hi.x*hi.x + hi.y*hi.y;
#pragma unroll
    for (int o = 1; o < 16; o <<= 1) ssq += __shfl_xor(ssq, o, 64);
    float n  = fmaxf(sqrtf(ssq), EPSV);
    float th = tanhf(n);
    float g  = th / n;
    float nh = fmaxf(th, EPSV);
    if (nh > MAXN) { g *= MAXN / nh; nh = MAXN; }
    float lamg = (artanh_(nh) / nh) * g;
    float t0 = fmaxf(lamg * lo.x, 0.0f);
    float t1 = fmaxf(lamg * lo.y, 0.0f);
    float t2 = fmaxf(lamg * hi.x, 0.0f);
    float t3 = fmaxf(lamg * hi.y, 0.0f);
    float tsq = t0*t0 + t1*t1 + t2*t2 + t3*t3;
#pragma unroll
    for (int o = 1; o < 16; o <<= 1) tsq += __shfl_xor(tsq, o, 64);
    float n2  = fmaxf(sqrtf(tsq), EPSV);
    float th2 = tanhf(n2);
    float g2  = th2 / n2;
    float nh2 = fmaxf(th2, EPSV);
    if (nh2 > MAXN) g2 *= MAXN / nh2;
    if (p4 == 0)
        *(float2*)(out + (size_t)d * 64 + 2 * sl4)      = make_float2(g2 * t0, g2 * t1);
    else if (p4 == 1)
        *(float2*)(out + (size_t)d * 64 + 32 + 2 * sl4) = make_float2(g2 * t2, g2 * t3);
}

// ===== layer 2: MFMA fused HypAct+matvec+tail; agg(d_out) -> split tables =====
__global__ __launch_bounds__(256) void hgA_layer2_mfma(
    const float* __restrict__ agg,   // [N,64] fp32 (d_out)
    const float* __restrict__ W2,    // [64,64] row-major
    const float* __restrict__ b2v,   // [64]
    bfu* __restrict__ xlo2, bfu* __restrict__ xhi2, int N)
{
    const int tid = threadIdx.x, lane = tid & 63, wv = tid >> 6;
    const int nodeBase = (blockIdx.x * 4 + wv) * 16;
    if (nodeBase >= N) return;

    float y2;
    float hb = bias_point(b2v, lane, &y2);
    float hbv[4];
#pragma unroll
    for (int t = 0; t < 4; ++t) hbv[t] = __shfl(hb, (lane & 15) + 16 * t);

    const int m = lane & 15, q = lane >> 4;
    const bool rowok = (nodeBase + m) < N;

    float af0[8], af1[8];
    const float* arow = agg + (size_t)(nodeBase + m) * 64 + q * 8;
    if (rowok) {
        *(float4*)(af0)     = *(const float4*)(arow);
        *(float4*)(af0 + 4) = *(const float4*)(arow + 4);
        *(float4*)(af1)     = *(const float4*)(arow + 32);
        *(float4*)(af1 + 4) = *(const float4*)(arow + 36);
    } else {
#pragma unroll
        for (int j = 0; j < 8; ++j) { af0[j] = 0.0f; af1[j] = 0.0f; }
    }
    float asq = 0.0f;
#pragma unroll
    for (int j = 0; j < 8; ++j) {
        asq = fmaf(af0[j], af0[j], asq);
        asq = fmaf(af1[j], af1[j], asq);
    }
    asq += __shfl_xor(asq, 16, 64);
    asq += __shfl_xor(asq, 32, 64);

    float n  = fmaxf(sqrtf(asq), EPSV);
    float th = tanhf(n);
    float g  = th / n;
    float nh = fmaxf(th, EPSV);
    if (nh > MAXN) { g *= MAXN / nh; nh = MAXN; }
    float lamg = (artanh_(nh) / nh) * g;
    float t0[8], t1[8], tsq = 0.0f;
#pragma unroll
    for (int j = 0; j < 8; ++j) {
        t0[j] = fmaxf(lamg * af0[j], 0.0f);
        t1[j] = fmaxf(lamg * af1[j], 0.0f);
        tsq = fmaf(t0[j], t0[j], tsq);
        tsq = fmaf(t1[j], t1[j], tsq);
    }
    tsq += __shfl_xor(tsq, 16, 64);
    tsq += __shfl_xor(tsq, 32, 64);
    float n2  = fmaxf(sqrtf(tsq), EPSV);
    float th2 = tanhf(n2);
    float g2  = th2 / n2;
    float nh2 = fmaxf(th2, EPSV);
    if (nh2 > MAXN) { g2 *= MAXN / nh2; nh2 = MAXN; }
    float xn_m = nh2;
    float x0[8], x1[8];
#pragma unroll
    for (int j = 0; j < 8; ++j) { x0[j] = g2 * t0[j]; x1[j] = g2 * t1[j]; }
    v8s a0 = cvt8(x0), a1 = cvt8(x1);

    v4f acc0 = {0,0,0,0}, acc1 = {0,0,0,0}, acc2 = {0,0,0,0}, acc3 = {0,0,0,0};
    {
        float wf[8];
        const float* wb;
        wb = W2 + (size_t)(m     ) * 64 + q * 8;
        *(float4*)(wf) = *(const float4*)(wb);     *(float4*)(wf+4) = *(const float4*)(wb+4);
        acc0 = __builtin_amdgcn_mfma_f32_16x16x32_bf16(a0, cvt8(wf), acc0, 0, 0, 0);
        *(float4*)(wf) = *(const float4*)(wb+32);  *(float4*)(wf+4) = *(const float4*)(wb+36);
        acc0 = __builtin_amdgcn_mfma_f32_16x16x32_bf16(a1, cvt8(wf), acc0, 0, 0, 0);
        wb = W2 + (size_t)(m + 16) * 64 + q * 8;
        *(float4*)(wf) = *(const float4*)(wb);     *(float4*)(wf+4) = *(const float4*)(wb+4);
        acc1 = __builtin_amdgcn_mfma_f32_16x16x32_bf16(a0, cvt8(wf), acc1, 0, 0, 0);
        *(float4*)(wf) = *(const float4*)(wb+32);  *(float4*)(wf+4) = *(const float4*)(wb+36);
        acc1 = __builtin_amdgcn_mfma_f32_16x16x32_bf16(a1, cvt8(wf), acc1, 0, 0, 0);
        wb = W2 + (size_t)(m + 32) * 64 + q * 8;
        *(float4*)(wf) = *(const float4*)(wb);     *(float4*)(wf+4) = *(const float4*)(wb+4);
        acc2 = __builtin_amdgcn_mfma_f32_16x16x32_bf16(a0, cvt8(wf), acc2, 0, 0, 0);
        *(float4*)(wf) = *(const float4*)(wb+32);  *(float4*)(wf+4) = *(const float4*)(wb+36);
        acc2 = __builtin_amdgcn_mfma_f32_16x16x32_bf16(a1, cvt8(wf), acc2, 0, 0, 0);
        wb = W2 + (size_t)(m + 48) * 64 + q * 8;
        *(float4*)(wf) = *(const float4*)(wb);     *(float4*)(wf+4) = *(const float4*)(wb+4);
        acc3 = __builtin_amdgcn_mfma_f32_16x16x32_bf16(a0, cvt8(wf), acc3, 0, 0, 0);
        *(float4*)(wf) = *(const float4*)(wb+32);  *(float4*)(wf+4) = *(const float4*)(wb+36);
        acc3 = __builtin_amdgcn_mfma_f32_16x16x32_bf16(a1, cvt8(wf), acc3, 0, 0, 0);
    }

    float P[4], Q[4];
#pragma unroll
    for (int r = 0; r < 4; ++r) {
        float s2 = acc0[r]*acc0[r] + acc1[r]*acc1[r] + acc2[r]*acc2[r] + acc3[r]*acc3[r];
        float sh = acc0[r]*hbv[0] + acc1[r]*hbv[1] + acc2[r]*hbv[2] + acc3[r]*hbv[3];
#pragma unroll
        for (int o = 1; o < 16; o <<= 1) {
            s2 += __shfl_xor(s2, o, 64);
            sh += __shfl_xor(sh, o, 64);
        }
        float xn = __shfl(xn_m, q * 4 + r);
        float mxn = fmaxf(sqrtf(s2), EPSV);
        float rt  = tanhf(mxn / xn * artanh_(xn));
        float k1, x2s, xy;
        if (s2 != 0.0f) {
            k1 = rt / mxn;
            float mvn = fmaxf(fabsf(rt), EPSV);
            if (mvn > MAXN) k1 *= MAXN / mvn;
            float cn = fminf(mvn, MAXN);
            x2s = cn * cn;
            xy  = k1 * sh;
        } else { k1 = 0.0f; x2s = 0.0f; xy = 0.0f; }
        float ca = 1.0f + 2.0f * xy + y2;
        float cb = 1.0f - x2s;
        float den = fmaxf(1.0f + 2.0f * xy + x2s * y2, EPSV);
        float hn2 = ca*ca*x2s + 2.0f*ca*cb*xy + cb*cb*y2;
        float hn = fmaxf(sqrtf(hn2) / den, EPSV);
        float hs = 1.0f;
        if (hn > MAXN) { hs = MAXN / hn; hn = MAXN; }
        float lam = artanh_(hn) / hn;
        P[r] = lam * hs * ca * k1 / den;
        Q[r] = lam * hs * cb / den;
    }
#pragma unroll
    for (int r = 0; r < 4; ++r) {
        int ri = nodeBase + q * 4 + r;
        if (ri < N) {
            bfu* olo = xlo2 + (size_t)ri * 32 + m;
            bfu* ohi = xhi2 + (size_t)ri * 32 + m;
            olo[ 0] = f2b(P[r] * acc0[r] + Q[r] * hbv[0]);
            olo[16] = f2b(P[r] * acc1[r] + Q[r] * hbv[1]);
            ohi[ 0] = f2b(P[r] * acc2[r] + Q[r] * hbv[2]);
            ohi[16] = f2b(P[r] * acc3[r] + Q[r] * hbv[3]);
        }
    }
}

// ===== fallback kernels (round-9 path, used only if ws too small) =====
__global__ __launch_bounds__(256) void hgA_layer1_fp32(
    const float* __restrict__ x, const float* __restrict__ W1,
    const float* __restrict__ b1v, float* __restrict__ xt, int N)
{
    const int tid = threadIdx.x, lane = tid & 63, wv = tid >> 6;
    const int nodeBase = (blockIdx.x * 4 + wv) * 16;
    if (nodeBase >= N) return;
    float y2;
    float hb = bias_point(b1v, lane, &y2);
    float hbv[4];
#pragma unroll
    for (int t = 0; t < 4; ++t) hbv[t] = __shfl(hb, (lane & 15) + 16 * t);
    const int m = lane & 15, q = lane >> 4;
    v4f acc0 = {0,0,0,0}, acc1 = {0,0,0,0}, acc2 = {0,0,0,0}, acc3 = {0,0,0,0};
    float usq = 0.0f;
    const float* arow = x + (size_t)(nodeBase + m) * 256 + q * 8;
#pragma unroll
    for (int s = 0; s < 8; ++s) {
        float af[8];
        *(float4*)(af)     = *(const float4*)(arow + s * 32);
        *(float4*)(af + 4) = *(const float4*)(arow + s * 32 + 4);
#pragma unroll
        for (int j = 0; j < 8; ++j) usq = fmaf(af[j], af[j], usq);
        v8s a = cvt8(af);
        const float* wbase = W1 + (size_t)m * 256 + s * 32 + q * 8;
        float wf[8];
        *(float4*)(wf) = *(const float4*)(wbase);  *(float4*)(wf+4) = *(const float4*)(wbase+4);
        acc0 = __builtin_amdgcn_mfma_f32_16x16x32_bf16(a, cvt8(wf), acc0, 0, 0, 0);
        *(float4*)(wf) = *(const float4*)(wbase+16*256); *(float4*)(wf+4) = *(const float4*)(wbase+16*256+4);
        acc1 = __builtin_amdgcn_mfma_f32_16x16x32_bf16(a, cvt8(wf), acc1, 0, 0, 0);
        *(float4*)(wf) = *(const float4*)(wbase+32*256); *(float4*)(wf+4) = *(const float4*)(wbase+32*256+4);
        acc2 = __builtin_amdgcn_mfma_f32_16x16x32_bf16(a, cvt8(wf), acc2, 0, 0, 0);
        *(float4*)(wf) = *(const float4*)(wbase+48*256); *(float4*)(wf+4) = *(const float4*)(wbase+48*256+4);
        acc3 = __builtin_amdgcn_mfma_f32_16x16x32_bf16(a, cvt8(wf), acc3, 0, 0, 0);
    }
    usq += __shfl_xor(usq, 16, 64);
    usq += __shfl_xor(usq, 32, 64);
    float P[4], Q[4];
#pragma unroll
    for (int r = 0; r < 4; ++r) {
        float s2 = acc0[r]*acc0[r] + acc1[r]*acc1[r] + acc2[r]*acc2[r] + acc3[r]*acc3[r];
        float sh = acc0[r]*hbv[0] + acc1[r]*hbv[1] + acc2[r]*hbv[2] + acc3[r]*hbv[3];
#pragma unroll
        for (int o = 1; o < 16; o <<= 1) { s2 += __shfl_xor(s2, o, 64); sh += __shfl_xor(sh, o, 64); }
        float usq_r = __shfl(usq, q * 4 + r);
        float n  = fmaxf(sqrtf(usq_r), EPSV);
        float th = tanhf(n);
        float gamma = th / n;
        float xn = fmaxf(th, EPSV);
        if (xn > MAXN) { gamma *= MAXN / xn; xn = MAXN; }
        float mxn = fmaxf(gamma * sqrtf(s2), EPSV);
        float rt  = tanhf(mxn / xn * artanh_(xn));
        float k1, x2s, xy;
        if (s2 != 0.0f) {
            k1 = (rt / mxn) * gamma;
            float mvn = fmaxf(fabsf(rt), EPSV);
            if (mvn > MAXN) k1 *= MAXN / mvn;
            float cn = fminf(mvn, MAXN);
            x2s = cn * cn; xy = k1 * sh;
        } else { k1 = 0.0f; x2s = 0.0f; xy = 0.0f; }
        float ca = 1.0f + 2.0f * xy + y2;
        float cb = 1.0f - x2s;
        float den = fmaxf(1.0f + 2.0f * xy + x2s * y2, EPSV);
        float hn2 = ca*ca*x2s + 2.0f*ca*cb*xy + cb*cb*y2;
        float hn = fmaxf(sqrtf(hn2) / den, EPSV);
        float hs = 1.0f;
        if (hn > MAXN) { hs = MAXN / hn; hn = MAXN; }
        float lam = artanh_(hn) / hn;
        P[r] = lam * hs * ca * k1 / den;
        Q[r] = lam * hs * cb / den;
    }
#pragma unroll
    for (int r = 0; r < 4; ++r) {
        float* orow = xt + (size_t)(nodeBase + q * 4 + r) * 64 + m;
        orow[ 0] = P[r] * acc0[r] + Q[r] * hbv[0];
        orow[16] = P[r] * acc1[r] + Q[r] * hbv[1];
        orow[32] = P[r] * acc2[r] + Q[r] * hbv[2];
        orow[48] = P[r] * acc3[r] + Q[r] * hbv[3];
    }
}

__global__ __launch_bounds__(256) void hgA_scatter(
    const int* __restrict__ src, const int* __restrict__ dst,
    const float* __restrict__ ew,
    const float* __restrict__ xt, float* __restrict__ agg, int E)
{
    const int lane = threadIdx.x & 63;
    const long long wid = ((long long)blockIdx.x * blockDim.x + threadIdx.x) >> 6;
    const long long nw = ((long long)gridDim.x * blockDim.x) >> 6;
    for (long long e = wid; e < E; e += nw) {
        int s = src[e], d = dst[e];
        atomicAdd(&agg[(size_t)d * 64 + lane], ew[e] * xt[(size_t)s * 64 + lane]);
    }
}

__global__ __launch_bounds__(256) void hgA_layer2_fb(
    const float* __restrict__ agg,
    const float* __restrict__ W2, const float* __restrict__ b2v,
    float* __restrict__ xt2, int N)
{
    const int lane = threadIdx.x & 63, wv = threadIdx.x >> 6;
    float y2;
    float hb = bias_point(b2v, lane, &y2);
    const int nw = gridDim.x * 4;
    for (int i = blockIdx.x * 4 + wv; i < N; i += nw) {
        float a = agg[(size_t)i * 64 + lane];
        float xn;
        float x2 = agg_transform(a, &xn);
        float acc = 0.0f;
        const float* Wrow = W2 + (size_t)lane * 64;
        for (int s = 0; s < 64; ++s)
            acc = fmaf(__shfl(x2, s), Wrow[s], acc);
        float o = mobius_tail(acc, xn, hb, y2);
        xt2[(size_t)i * 64 + lane] = o;
    }
}

__global__ __launch_bounds__(256) void hgA_final_fb(
    const float* __restrict__ agg, float* __restrict__ out, int N)
{
    const int lane = threadIdx.x & 63, wv = threadIdx.x >> 6;
    const int nw = gridDim.x * 4;
    for (int i = blockIdx.x * 4 + wv; i < N; i += nw) {
        float a = agg[(size_t)i * 64 + lane];
        float xn;
        float o = agg_transform(a, &xn);
        out[(size_t)i * 64 + lane] = o;
    }
}

extern "C" void kernel_launch(void* const* d_in, const int* in_sizes, int n_in,
                              void* d_out, int out_size, void* d_ws, size_t ws_size,
                              hipStream_t stream)
{
    const float* x  = (const float*)d_in[0];
    const int* src  = (const int*)d_in[1];
    const int* dst  = (const int*)d_in[2];
    const float* ew = (const float*)d_in[3];
    const float* W1 = (const float*)d_in[4];
    const float* b1 = (const float*)d_in[5];
    const float* W2 = (const float*)d_in[6];
    const float* b2 = (const float*)d_in[7];

    const int Dd = in_sizes[5];            // 64
    const int Ff = in_sizes[4] / Dd;       // 256
    const int N  = in_sizes[0] / Ff;       // 80000
    const int E  = in_sizes[1];            // 1280000

    float* out = (float*)d_out;
    float* agg = (float*)d_out;            // CSR path: fp32 agg lives in d_out

    // ws layouts (split tables replace xtb, same total bytes):
    // tier A: [xlo N*32*2][xhi N*32*2][deg N][rowst N+1][cursor N][rank E][pad][csr 8E]
    // tier B: same minus rank
    bfu*  xlo    = (bfu*)d_ws;
    bfu*  xhi    = xlo + (size_t)N * 32;
    size_t tbl_b = (size_t)N * Dd * 2;     // both halves
    int*  deg    = (int*)((char*)d_ws + tbl_b);
    int*  rowst  = deg + N;
    int*  cursor = rowst + (N + 1);
    int*  rank   = cursor + N;
    size_t csr_offA = (tbl_b + ((size_t)(3 * N + 1) + (size_t)E) * 4 + 7) & ~(size_t)7;
    size_t csr_offB = (tbl_b + (size_t)(3 * N + 1) * 4 + 7) & ~(size_t)7;
    const size_t needA = csr_offA + (size_t)E * 8;
    const size_t needB = csr_offB + (size_t)E * 8;

    const int blkT = (N + 63) / 64;        // wave per 16 nodes (layer kernels)
    const int blkG = (N + 3) / 4;          // wave per dst node (gathers)
    const int blkE4 = (E + 1023) / 1024;   // 4 edges/thread vblocks
    const int n4 = (N * Dd) / 4;

    if (ws_size >= needA) {
        int2* csr = (int2*)((char*)d_ws + csr_offA);
        // layer1 vblock split: count 500 | scan 150 | fill rest
        int L1C = blkT < 500 ? blkT : 500;
        int L1S = (blkT - L1C) < 150 ? (blkT - L1C) : 150;
        int L1F = blkT - L1C - L1S;
        hgA_zero_i32    <<<128, 256, 0, stream>>>(deg, N);
        hgA_count_rank_l1<<<blkE4 + L1C, 256, 0, stream>>>(
            dst, deg, rank, E, blkE4, L1C, x, W1, b1, xlo, xhi, N);
        hgA_scan_l1     <<<1 + (L1S + 3) / 4, 1024, 0, stream>>>(
            deg, rowst, cursor, N, x, W1, b1, xlo, xhi, L1S, L1C);
        hgA_fillr_layer1<<<blkE4 + L1F, 256, 0, stream>>>(
            src, dst, ew, rank, rowst, csr, E, blkE4, L1F, L1C + L1S,
            x, W1, b1, xlo, xhi, N);
        hgA_gather_half <<<blkG, 256, 0, stream>>>(rowst, csr, xlo, agg,  0, N);
        hgA_gather_half <<<blkG, 256, 0, stream>>>(rowst, csr, xhi, agg, 32, N);
        hgA_layer2_mfma <<<blkT, 256, 0, stream>>>(agg, W2, b2, xlo, xhi, N);
        hgA_gout_lo     <<<blkG, 256, 0, stream>>>(rowst, csr, xlo, out, N);
        hgA_gout_hi_fin <<<blkG, 256, 0, stream>>>(rowst, csr, xhi, out, N);
    } else if (ws_size >= needB) {
        int2* csr = (int2*)((char*)d_ws + csr_offB);
        const int fillBlocks = 2048;
        hgA_zero_i32   <<<128,  256, 0, stream>>>(deg, N);
        hgA_count      <<<2048, 256, 0, stream>>>(dst, deg, E);
        hgA_scan_l1    <<<1,   1024, 0, stream>>>(
            deg, rowst, cursor, N, x, W1, b1, xlo, xhi, 0, 0);
        hgA_fill_layer1<<<fillBlocks + blkT, 256, 0, stream>>>(
            src, dst, ew, cursor, csr, E, fillBlocks, x, W1, b1, xlo, xhi, N);
        hgA_gather_half <<<blkG, 256, 0, stream>>>(rowst, csr, xlo, agg,  0, N);
        hgA_gather_half <<<blkG, 256, 0, stream>>>(rowst, csr, xhi, agg, 32, N);
        hgA_layer2_mfma <<<blkT, 256, 0, stream>>>(agg, W2, b2, xlo, xhi, N);
        hgA_gout_lo     <<<blkG, 256, 0, stream>>>(rowst, csr, xlo, out, N);
        hgA_gout_hi_fin <<<blkG, 256, 0, stream>>>(rowst, csr, xhi, out, N);
    } else {
        // round-9 fallback: xt fp32 in d_out, agg fp32 in ws
        float* xt_fb  = (float*)d_out;
        float* agg_fb = (float*)d_ws;
        hgA_layer1_fp32<<<blkT, 256, 0, stream>>>(x, W1, b1, xt_fb, N);
        hgA_zero     <<<1024,  256, 0, stream>>>(agg_fb, n4);
        hgA_scatter  <<<16384, 256, 0, stream>>>(src, dst, ew, xt_fb, agg_fb, E);
        hgA_layer2_fb<<<2048,  256, 0, stream>>>(agg_fb, W2, b2, xt_fb, N);
        hgA_zero     <<<1024,  256, 0, stream>>>(agg_fb, n4);
        hgA_scatter  <<<16384, 256, 0, stream>>>(src, dst, ew, xt_fb, agg_fb, E);
        hgA_final_fb <<<2048,  256, 0, stream>>>(agg_fb, out, N);
    }
}

// Round 3
// 375.410 us; speedup vs baseline: 1.2678x; 1.2678x over previous
//
#include <hip/hip_runtime.h>

// HGCN forward (2-layer hyperbolic GCN), Poincare ball c=1. fp32 in/out
// (values bf16-grid). Round 13 = round 11 (430us proven: single xtb table,
// paired bf16x2 gathers, rank-based atomic-free fill) with:
//  (a) PARALLEL 3-phase scan (chunk-scan / scan-of-sums / offset-add) replacing
//      the 76us serial single-block scan (round-2 counters: 3% occupancy,
//      2.8% VALUBusy -- it was pure exposed latency once layer1 moved out).
//  (b) layer1 vblocks distributed 500 -> count_rank (vectorized int4 count),
//      750 -> fill (vectorized int4 rank-fill); both proven <=76us hosts.
//  (c) round-2's dim-split gathers REVERTED (4 dispatches re-walked the full
//      CSR twice; net negative).
// Tiers: A (rank fill + parallel scan) -> B (round-10 atomic fill) -> fallback.

#define EPSV 1e-15f
#define MAXN 0.996f   // (1 - 4e-3) / sqrt(c), c = 1

typedef unsigned short bfu;
typedef __attribute__((ext_vector_type(8))) short v8s;   // 8 bf16 (4 VGPRs)
typedef __attribute__((ext_vector_type(4))) float v4f;   // MFMA acc

__device__ __forceinline__ bfu f2b(float f) {   // fp32 -> bf16, RNE
    unsigned int u;
    __builtin_memcpy(&u, &f, sizeof(u));
    u += 0x7fffu + ((u >> 16) & 1u);
    return (bfu)(u >> 16);
}

__device__ __forceinline__ float b2f(bfu s) {
    unsigned int u = ((unsigned int)s) << 16;
    float f;
    __builtin_memcpy(&f, &u, sizeof(f));
    return f;
}

// low/high bf16 of a packed u32 -> fp32
__device__ __forceinline__ float uplo(unsigned int u) {
    unsigned int v = u << 16; float f;
    __builtin_memcpy(&f, &v, sizeof(f)); return f;
}
__device__ __forceinline__ float uphi(unsigned int u) {
    unsigned int v = u & 0xffff0000u; float f;
    __builtin_memcpy(&f, &v, sizeof(f)); return f;
}

__device__ __forceinline__ v8s cvt8(const float* f) {
    v8s r;
#pragma unroll
    for (int j = 0; j < 8; ++j) r[j] = (short)f2b(f[j]);
    return r;
}

__device__ __forceinline__ float i2f(int i) {
    float f; __builtin_memcpy(&f, &i, sizeof(f)); return f;
}
__device__ __forceinline__ int f2i(float f) {
    int i; __builtin_memcpy(&i, &f, sizeof(i)); return i;
}

__device__ __forceinline__ float wredsum(float v) {
#pragma unroll
    for (int o = 32; o > 0; o >>= 1) v += __shfl_xor(v, o, 64);
    return v;
}

// reduce within each 32-lane half (enough when both halves hold all dims)
__device__ __forceinline__ float hredsum(float v) {
#pragma unroll
    for (int o = 16; o > 0; o >>= 1) v += __shfl_xor(v, o, 64);
    return v;
}

__device__ __forceinline__ float artanh_(float x) {
    x = fminf(fmaxf(x, -1.0f + 1e-7f), 1.0f - 1e-7f);
    return 0.5f * logf((1.0f + x) / (1.0f - x));
}

__device__ __forceinline__ float mobius_tail(float mx, float xn, float hb, float y2) {
    float mxn2 = wredsum(mx * mx);
    unsigned long long nz = __ballot(mx != 0.0f);
    float mxn = fmaxf(sqrtf(mxn2), EPSV);
    float rt = tanhf(mxn / xn * artanh_(xn));
    float mv, x2s;
    if (nz != 0ull) {
        mv = (rt / mxn) * mx;
        float mvn = fmaxf(fabsf(rt), EPSV);
        if (mvn > MAXN) mv *= MAXN / mvn;
        float cn = fminf(mvn, MAXN);
        x2s = cn * cn;
    } else { mv = 0.0f; x2s = 0.0f; }
    float xy = wredsum(mv * hb);
    float ca = 1.0f + 2.0f * xy + y2;
    float cb = 1.0f - x2s;
    float den = fmaxf(1.0f + 2.0f * xy + x2s * y2, EPSV);
    float hj = (ca * mv + cb * hb) / den;
    float hn = fmaxf(sqrtf(wredsum(hj * hj)), EPSV);
    if (hn > MAXN) { hj *= MAXN / hn; hn = MAXN; }
    return (artanh_(hn) / hn) * hj;
}

__device__ __forceinline__ float agg_transform(float a, float* xn_out) {
    float n = fmaxf(sqrtf(wredsum(a * a)), EPSV);
    float th = tanhf(n);
    float g = th / n;
    float nh = fmaxf(th, EPSV);
    if (nh > MAXN) { g *= MAXN / nh; nh = MAXN; }
    float h = g * a;
    float t = fmaxf((artanh_(nh) / nh) * h, 0.0f);
    float n2 = fmaxf(sqrtf(wredsum(t * t)), EPSV);
    float th2 = tanhf(n2);
    float g2 = th2 / n2;
    float nh2 = fmaxf(th2, EPSV);
    if (nh2 > MAXN) { g2 *= MAXN / nh2; nh2 = MAXN; }
    *xn_out = nh2;
    return g2 * t;
}

__device__ __forceinline__ float bias_point(const float* bv, int lane, float* y2) {
    float b = bv[lane];
    float bn = fmaxf(sqrtf(wredsum(b * b)), EPSV);
    float gs = tanhf(bn) / bn;
    float hbn = fmaxf(tanhf(bn), EPSV);
    if (hbn > MAXN) gs *= MAXN / hbn;
    float hb = gs * b;
    *y2 = wredsum(hb * hb);
    return hb;
}

__global__ __launch_bounds__(256) void hgA_zero(float* __restrict__ p, int n4) {
    const float4 z = make_float4(0.f, 0.f, 0.f, 0.f);
    int stride = gridDim.x * blockDim.x;
    for (int i = blockIdx.x * blockDim.x + threadIdx.x; i < n4; i += stride)
        ((float4*)p)[i] = z;
}

// ===== layer1 body (MFMA, proven) -- writes bf16 xt =====
__device__ __forceinline__ void layer1_body(
    int bid, int tid, const float* __restrict__ x, const float* __restrict__ W1,
    const float* __restrict__ b1v, bfu* __restrict__ xtb, int N)
{
    const int lane = tid & 63, wv = tid >> 6;
    const int nodeBase = (bid * 4 + wv) * 16;
    if (nodeBase >= N) return;

    float y2;
    float hb = bias_point(b1v, lane, &y2);
    float hbv[4];
#pragma unroll
    for (int t = 0; t < 4; ++t) hbv[t] = __shfl(hb, (lane & 15) + 16 * t);

    const int m = lane & 15, q = lane >> 4;
    v4f acc0 = {0,0,0,0}, acc1 = {0,0,0,0}, acc2 = {0,0,0,0}, acc3 = {0,0,0,0};
    float usq = 0.0f;

    const float* arow = x + (size_t)(nodeBase + m) * 256 + q * 8;
#pragma unroll
    for (int s = 0; s < 8; ++s) {
        float af[8];
        *(float4*)(af)     = *(const float4*)(arow + s * 32);
        *(float4*)(af + 4) = *(const float4*)(arow + s * 32 + 4);
#pragma unroll
        for (int j = 0; j < 8; ++j) usq = fmaf(af[j], af[j], usq);
        v8s a = cvt8(af);
        const float* wbase = W1 + (size_t)m * 256 + s * 32 + q * 8;
        float wf[8];
        *(float4*)(wf) = *(const float4*)(wbase);
        *(float4*)(wf + 4) = *(const float4*)(wbase + 4);
        acc0 = __builtin_amdgcn_mfma_f32_16x16x32_bf16(a, cvt8(wf), acc0, 0, 0, 0);
        *(float4*)(wf) = *(const float4*)(wbase + 16 * 256);
        *(float4*)(wf + 4) = *(const float4*)(wbase + 16 * 256 + 4);
        acc1 = __builtin_amdgcn_mfma_f32_16x16x32_bf16(a, cvt8(wf), acc1, 0, 0, 0);
        *(float4*)(wf) = *(const float4*)(wbase + 32 * 256);
        *(float4*)(wf + 4) = *(const float4*)(wbase + 32 * 256 + 4);
        acc2 = __builtin_amdgcn_mfma_f32_16x16x32_bf16(a, cvt8(wf), acc2, 0, 0, 0);
        *(float4*)(wf) = *(const float4*)(wbase + 48 * 256);
        *(float4*)(wf + 4) = *(const float4*)(wbase + 48 * 256 + 4);
        acc3 = __builtin_amdgcn_mfma_f32_16x16x32_bf16(a, cvt8(wf), acc3, 0, 0, 0);
    }
    usq += __shfl_xor(usq, 16, 64);
    usq += __shfl_xor(usq, 32, 64);

    float P[4], Q[4];
#pragma unroll
    for (int r = 0; r < 4; ++r) {
        float s2 = acc0[r]*acc0[r] + acc1[r]*acc1[r] + acc2[r]*acc2[r] + acc3[r]*acc3[r];
        float sh = acc0[r]*hbv[0] + acc1[r]*hbv[1] + acc2[r]*hbv[2] + acc3[r]*hbv[3];
#pragma unroll
        for (int o = 1; o < 16; o <<= 1) {
            s2 += __shfl_xor(s2, o, 64);
            sh += __shfl_xor(sh, o, 64);
        }
        float usq_r = __shfl(usq, q * 4 + r);
        float n  = fmaxf(sqrtf(usq_r), EPSV);
        float th = tanhf(n);
        float gamma = th / n;
        float xn = fmaxf(th, EPSV);
        if (xn > MAXN) { gamma *= MAXN / xn; xn = MAXN; }
        float mxn = fmaxf(gamma * sqrtf(s2), EPSV);
        float rt  = tanhf(mxn / xn * artanh_(xn));
        float k1, x2s, xy;
        if (s2 != 0.0f) {
            k1 = (rt / mxn) * gamma;
            float mvn = fmaxf(fabsf(rt), EPSV);
            if (mvn > MAXN) k1 *= MAXN / mvn;
            float cn = fminf(mvn, MAXN);
            x2s = cn * cn;
            xy  = k1 * sh;
        } else { k1 = 0.0f; x2s = 0.0f; xy = 0.0f; }
        float ca = 1.0f + 2.0f * xy + y2;
        float cb = 1.0f - x2s;
        float den = fmaxf(1.0f + 2.0f * xy + x2s * y2, EPSV);
        float hn2 = ca*ca*x2s + 2.0f*ca*cb*xy + cb*cb*y2;
        float hn = fmaxf(sqrtf(hn2) / den, EPSV);
        float hs = 1.0f;
        if (hn > MAXN) { hs = MAXN / hn; hn = MAXN; }
        float lam = artanh_(hn) / hn;
        P[r] = lam * hs * ca * k1 / den;
        Q[r] = lam * hs * cb / den;
    }
#pragma unroll
    for (int r = 0; r < 4; ++r) {
        bfu* orow = xtb + (size_t)(nodeBase + q * 4 + r) * 64 + m;
        orow[ 0] = f2b(P[r] * acc0[r] + Q[r] * hbv[0]);
        orow[16] = f2b(P[r] * acc1[r] + Q[r] * hbv[1]);
        orow[32] = f2b(P[r] * acc2[r] + Q[r] * hbv[2]);
        orow[48] = f2b(P[r] * acc3[r] + Q[r] * hbv[3]);
    }
}

// ===== CSR build =====
__global__ __launch_bounds__(256) void hgA_zero_i32(int* __restrict__ p, int n) {
    int stride = gridDim.x * blockDim.x;
    for (int i = blockIdx.x * blockDim.x + threadIdx.x; i < n; i += stride) p[i] = 0;
}

// tier B count (no rank)
__global__ __launch_bounds__(256) void hgA_count(
    const int* __restrict__ dst, int* __restrict__ deg, int E) {
    int stride = gridDim.x * blockDim.x;
    for (int e = blockIdx.x * blockDim.x + threadIdx.x; e < E; e += stride)
        atomicAdd(&deg[dst[e]], 1);
}

// tier A count_rank + layer1 share (parity-interleaved). count side:
// int4-vectorized, 4 edges/thread, exact grid (nf = ceil(E/1024)).
__global__ __launch_bounds__(256) void hgA_count_rank_l1(
    const int* __restrict__ dst, int* __restrict__ deg, int* __restrict__ rank,
    int E, int nf, int nl,
    const float* __restrict__ x, const float* __restrict__ W1,
    const float* __restrict__ b1v, bfu* __restrict__ xtb, int N)
{
    const int b = blockIdx.x;
    const int mn = nf < nl ? nf : nl;
    bool isC; int idx;
    if (b < 2 * mn) { isC = !(b & 1); idx = b >> 1; }
    else            { isC = (nf > nl); idx = mn + (b - 2 * mn); }
    if (isC) {
        int e0 = (idx * 256 + threadIdx.x) * 4;
        if (e0 + 4 <= E) {
            int4 d4 = *(const int4*)(dst + e0);
            int4 r4;
            r4.x = atomicAdd(&deg[d4.x], 1);
            r4.y = atomicAdd(&deg[d4.y], 1);
            r4.z = atomicAdd(&deg[d4.z], 1);
            r4.w = atomicAdd(&deg[d4.w], 1);
            *(int4*)(rank + e0) = r4;
        } else if (e0 < E) {
            for (int e = e0; e < E; ++e) rank[e] = atomicAdd(&deg[dst[e]], 1);
        }
    } else {
        layer1_body(idx, threadIdx.x, x, W1, b1v, xtb, N);   // l1off = 0
    }
}

// ===== parallel scan, phase 1: per-1024-chunk exclusive scan + block sums =====
__global__ __launch_bounds__(256) void hgA_scan1(
    const int* __restrict__ deg, int* __restrict__ rowst,
    int* __restrict__ bsum, int N)
{
    __shared__ int wsum[4];
    const int tid = threadIdx.x, lane = tid & 63, wv = tid >> 6;
    const int base = blockIdx.x * 1024 + tid * 4;
    int v0 = 0, v1 = 0, v2 = 0, v3 = 0;
    if (base + 4 <= N) {
        int4 d4 = *(const int4*)(deg + base);
        v0 = d4.x; v1 = d4.y; v2 = d4.z; v3 = d4.w;
    } else {
        if (base + 0 < N) v0 = deg[base + 0];
        if (base + 1 < N) v1 = deg[base + 1];
        if (base + 2 < N) v2 = deg[base + 2];
        if (base + 3 < N) v3 = deg[base + 3];
    }
    const int tsum = v0 + v1 + v2 + v3;
    int incl = tsum;
#pragma unroll
    for (int o = 1; o < 64; o <<= 1) {
        int nb = __shfl_up(incl, o, 64);
        if (lane >= o) incl += nb;
    }
    if (lane == 63) wsum[wv] = incl;
    __syncthreads();
    int add = 0;
#pragma unroll
    for (int w = 0; w < 4; ++w) { int s = wsum[w]; if (w < wv) add += s; }
    const int excl = add + incl - tsum;
    const int e0 = excl, e1 = e0 + v0, e2 = e1 + v1, e3 = e2 + v2;
    if (base + 4 <= N) {
        *(int4*)(rowst + base) = make_int4(e0, e1, e2, e3);
    } else {
        if (base + 0 < N) rowst[base + 0] = e0;
        if (base + 1 < N) rowst[base + 1] = e1;
        if (base + 2 < N) rowst[base + 2] = e2;
        if (base + 3 < N) rowst[base + 3] = e3;
    }
    if (tid == 255) bsum[blockIdx.x] = add + incl;
}

// phase 2: single wave, exclusive-scan the NB block sums in place; total -> *tot
__global__ __launch_bounds__(64) void hgA_scan2(
    int* __restrict__ bsum, int* __restrict__ tot, int NB)
{
    const int lane = threadIdx.x;
    int run = 0;
    for (int b = 0; b < NB; b += 64) {
        int i = b + lane;
        int v = (i < NB) ? bsum[i] : 0;
        int incl = v;
#pragma unroll
        for (int o = 1; o < 64; o <<= 1) {
            int nb = __shfl_up(incl, o, 64);
            if (lane >= o) incl += nb;
        }
        if (i < NB) bsum[i] = run + incl - v;
        run += __shfl(incl, 63);
    }
    if (lane == 0) *tot = run;
}

// phase 3: add per-chunk offsets
__global__ __launch_bounds__(256) void hgA_scan3(
    int* __restrict__ rowst, const int* __restrict__ bsum, int N)
{
    const int base = blockIdx.x * 1024 + threadIdx.x * 4;
    const int off = bsum[blockIdx.x];
    if (base + 4 <= N) {
        int4 r = *(int4*)(rowst + base);
        r.x += off; r.y += off; r.z += off; r.w += off;
        *(int4*)(rowst + base) = r;
    } else {
        for (int i = base; i < N; ++i) rowst[i] += off;
    }
}

// tier B: serial scan (block 0) -- retained as safety net
__global__ __launch_bounds__(1024) void hgA_scan_l1(
    const int* __restrict__ deg, int* __restrict__ row_start,
    int* __restrict__ cursor, int N,
    const float* __restrict__ x, const float* __restrict__ W1,
    const float* __restrict__ b1v, bfu* __restrict__ xtb, int NL)
{
    if (blockIdx.x != 0) {
        int vb = (blockIdx.x - 1) * 4 + (threadIdx.x >> 8);
        if (vb < NL) layer1_body(vb, threadIdx.x & 255, x, W1, b1v, xtb, N);
        return;
    }
    __shared__ int wsum[16];
    __shared__ int srun;
    const int tid = threadIdx.x, lane = tid & 63, wv = tid >> 6;
    if (tid == 0) srun = 0;
    __syncthreads();
    for (int base = 0; base < N; base += 1024) {
        int i = base + tid;
        int v = (i < N) ? deg[i] : 0;
        int incl = v;
#pragma unroll
        for (int o = 1; o < 64; o <<= 1) {
            int nbr = __shfl_up(incl, o, 64);
            if (lane >= o) incl += nbr;
        }
        if (lane == 63) wsum[wv] = incl;
        __syncthreads();
        int add = 0;
#pragma unroll
        for (int w = 0; w < 16; ++w) { int s = wsum[w]; if (w < wv) add += s; }
        int excl = srun + add + incl - v;
        if (i < N) { row_start[i] = excl; cursor[i] = excl; }
        __syncthreads();
        if (tid == 1023) srun += add + incl;
        __syncthreads();
    }
    if (tid == 0) row_start[N] = srun;
}

// ===== tier B fused: fill (atomic cursor) || layer1 =====
__global__ __launch_bounds__(256) void hgA_fill_layer1(
    const int* __restrict__ src, const int* __restrict__ dst,
    const float* __restrict__ ew, int* __restrict__ cursor,
    int2* __restrict__ csr, int E, int fillBlocks,
    const float* __restrict__ x, const float* __restrict__ W1,
    const float* __restrict__ b1v, bfu* __restrict__ xtb, int N)
{
    const int b = blockIdx.x;
    if (b < fillBlocks) {
        int stride = fillBlocks * blockDim.x;
        for (int e = b * blockDim.x + threadIdx.x; e < E; e += stride) {
            int d = dst[e];
            int slot = atomicAdd(&cursor[d], 1);
            csr[slot] = make_int2(src[e], f2i(ew[e]));
        }
    } else {
        layer1_body(b - fillBlocks, threadIdx.x, x, W1, b1v, xtb, N);
    }
}

// ===== tier A fused: atomic-free fill (int4 loads) || layer1, interleaved =====
__global__ __launch_bounds__(256) void hgA_fillr_layer1(
    const int* __restrict__ src, const int* __restrict__ dst,
    const float* __restrict__ ew, const int* __restrict__ rank,
    const int* __restrict__ row_start, int2* __restrict__ csr,
    int E, int nf, int nl, int l1off,
    const float* __restrict__ x, const float* __restrict__ W1,
    const float* __restrict__ b1v, bfu* __restrict__ xtb, int N)
{
    const int b = blockIdx.x;
    const int mn = nf < nl ? nf : nl;
    bool isFill; int idx;
    if (b < 2 * mn) { isFill = !(b & 1); idx = b >> 1; }
    else            { isFill = (nf > nl); idx = mn + (b - 2 * mn); }
    if (isFill) {
        int e0 = (idx * 256 + threadIdx.x) * 4;
        if (e0 + 4 <= E) {
            int4  d4 = *(const int4*)(dst + e0);
            int4  s4 = *(const int4*)(src + e0);
            int4  r4 = *(const int4*)(rank + e0);
            float4 w4 = *(const float4*)(ew + e0);
            csr[row_start[d4.x] + r4.x] = make_int2(s4.x, f2i(w4.x));
            csr[row_start[d4.y] + r4.y] = make_int2(s4.y, f2i(w4.y));
            csr[row_start[d4.z] + r4.z] = make_int2(s4.z, f2i(w4.z));
            csr[row_start[d4.w] + r4.w] = make_int2(s4.w, f2i(w4.w));
        } else if (e0 < E) {
            for (int e = e0; e < E; ++e)
                csr[row_start[dst[e]] + rank[e]] = make_int2(src[e], f2i(ew[e]));
        }
    } else {
        layer1_body(l1off + idx, threadIdx.x, x, W1, b1v, xtb, N);
    }
}

// ===== gather #1: agg[d] = sum w*xtb[src]; paired bf16x2 (2 rows / load) =====
__global__ __launch_bounds__(256) void hgA_gather(
    const int* __restrict__ row_start, const int2* __restrict__ csr,
    const bfu* __restrict__ xtb, float* __restrict__ agg, int N) {
    const int lane = threadIdx.x & 63, wv = threadIdx.x >> 6;
    const int d = blockIdx.x * 4 + wv;
    if (d >= N) return;
    const int sl = lane & 31, p = lane >> 5;
    const int n0 = row_start[d], n1 = row_start[d + 1];
    const unsigned int* xt32 = (const unsigned int*)xtb;
    float a0x = 0.f, a0y = 0.f, a1x = 0.f, a1y = 0.f;
    float a2x = 0.f, a2y = 0.f, a3x = 0.f, a3y = 0.f;
    for (int base = n0; base < n1; base += 64) {
        int cnt = n1 - base; if (cnt > 64) cnt = 64;
        int sL = 0; float wL = 0.0f;   // lanes >= cnt keep s=0, w=0 (safe pad)
        if (lane < cnt) { int2 rec = csr[base + lane]; sL = rec.x; wL = i2f(rec.y); }
        int j = 0;
        for (; j + 8 <= cnt; j += 8) {
            int   s0 = __shfl(sL, j     + p, 64), s1 = __shfl(sL, j + 2 + p, 64);
            int   s2 = __shfl(sL, j + 4 + p, 64), s3 = __shfl(sL, j + 6 + p, 64);
            float w0 = __shfl(wL, j     + p, 64), w1 = __shfl(wL, j + 2 + p, 64);
            float w2 = __shfl(wL, j + 4 + p, 64), w3 = __shfl(wL, j + 6 + p, 64);
            unsigned int u0 = xt32[(size_t)s0 * 32 + sl];
            unsigned int u1 = xt32[(size_t)s1 * 32 + sl];
            unsigned int u2 = xt32[(size_t)s2 * 32 + sl];
            unsigned int u3 = xt32[(size_t)s3 * 32 + sl];
            a0x = fmaf(w0, uplo(u0), a0x); a0y = fmaf(w0, uphi(u0), a0y);
            a1x = fmaf(w1, uplo(u1), a1x); a1y = fmaf(w1, uphi(u1), a1y);
            a2x = fmaf(w2, uplo(u2), a2x); a2y = fmaf(w2, uphi(u2), a2y);
            a3x = fmaf(w3, uplo(u3), a3x); a3y = fmaf(w3, uphi(u3), a3y);
        }
        for (; j < cnt; j += 2) {       // tail (odd edge pairs with w=0 pad)
            int   s = __shfl(sL, j + p, 64);
            float w = __shfl(wL, j + p, 64);
            unsigned int u = xt32[(size_t)s * 32 + sl];
            a0x = fmaf(w, uplo(u), a0x); a0y = fmaf(w, uphi(u), a0y);
        }
    }
    float tx = (a0x + a1x) + (a2x + a3x);
    float ty = (a0y + a1y) + (a2y + a3y);
    tx += __shfl_xor(tx, 32, 64);
    ty += __shfl_xor(ty, 32, 64);
    if (p == 0)
        *(float2*)(agg + (size_t)d * 64 + 2 * sl) = make_float2(tx, ty);
}

// ===== layer 2: MFMA fused HypAct+matvec+tail; agg(d_out) -> xtb2(ws, bf16) =====
__global__ __launch_bounds__(256) void hgA_layer2_mfma(
    const float* __restrict__ agg,   // [N,64] fp32 (d_out)
    const float* __restrict__ W2,    // [64,64] row-major
    const float* __restrict__ b2v,   // [64]
    bfu* __restrict__ xtb2, int N)   // [N,64] bf16 (ws)
{
    const int tid = threadIdx.x, lane = tid & 63, wv = tid >> 6;
    const int nodeBase = (blockIdx.x * 4 + wv) * 16;
    if (nodeBase >= N) return;

    float y2;
    float hb = bias_point(b2v, lane, &y2);
    float hbv[4];
#pragma unroll
    for (int t = 0; t < 4; ++t) hbv[t] = __shfl(hb, (lane & 15) + 16 * t);

    const int m = lane & 15, q = lane >> 4;
    const bool rowok = (nodeBase + m) < N;

    float af0[8], af1[8];
    const float* arow = agg + (size_t)(nodeBase + m) * 64 + q * 8;
    if (rowok) {
        *(float4*)(af0)     = *(const float4*)(arow);
        *(float4*)(af0 + 4) = *(const float4*)(arow + 4);
        *(float4*)(af1)     = *(const float4*)(arow + 32);
        *(float4*)(af1 + 4) = *(const float4*)(arow + 36);
    } else {
#pragma unroll
        for (int j = 0; j < 8; ++j) { af0[j] = 0.0f; af1[j] = 0.0f; }
    }
    float asq = 0.0f;
#pragma unroll
    for (int j = 0; j < 8; ++j) {
        asq = fmaf(af0[j], af0[j], asq);
        asq = fmaf(af1[j], af1[j], asq);
    }
    asq += __shfl_xor(asq, 16, 64);
    asq += __shfl_xor(asq, 32, 64);

    float n  = fmaxf(sqrtf(asq), EPSV);
    float th = tanhf(n);
    float g  = th / n;
    float nh = fmaxf(th, EPSV);
    if (nh > MAXN) { g *= MAXN / nh; nh = MAXN; }
    float lamg = (artanh_(nh) / nh) * g;
    float t0[8], t1[8], tsq = 0.0f;
#pragma unroll
    for (int j = 0; j < 8; ++j) {
        t0[j] = fmaxf(lamg * af0[j], 0.0f);
        t1[j] = fmaxf(lamg * af1[j], 0.0f);
        tsq = fmaf(t0[j], t0[j], tsq);
        tsq = fmaf(t1[j], t1[j], tsq);
    }
    tsq += __shfl_xor(tsq, 16, 64);
    tsq += __shfl_xor(tsq, 32, 64);
    float n2  = fmaxf(sqrtf(tsq), EPSV);
    float th2 = tanhf(n2);
    float g2  = th2 / n2;
    float nh2 = fmaxf(th2, EPSV);
    if (nh2 > MAXN) { g2 *= MAXN / nh2; nh2 = MAXN; }
    float xn_m = nh2;
    float x0[8], x1[8];
#pragma unroll
    for (int j = 0; j < 8; ++j) { x0[j] = g2 * t0[j]; x1[j] = g2 * t1[j]; }
    v8s a0 = cvt8(x0), a1 = cvt8(x1);

    v4f acc0 = {0,0,0,0}, acc1 = {0,0,0,0}, acc2 = {0,0,0,0}, acc3 = {0,0,0,0};
    {
        float wf[8];
        const float* wb;
        wb = W2 + (size_t)(m     ) * 64 + q * 8;
        *(float4*)(wf) = *(const float4*)(wb);     *(float4*)(wf+4) = *(const float4*)(wb+4);
        acc0 = __builtin_amdgcn_mfma_f32_16x16x32_bf16(a0, cvt8(wf), acc0, 0, 0, 0);
        *(float4*)(wf) = *(const float4*)(wb+32);  *(float4*)(wf+4) = *(const float4*)(wb+36);
        acc0 = __builtin_amdgcn_mfma_f32_16x16x32_bf16(a1, cvt8(wf), acc0, 0, 0, 0);
        wb = W2 + (size_t)(m + 16) * 64 + q * 8;
        *(float4*)(wf) = *(const float4*)(wb);     *(float4*)(wf+4) = *(const float4*)(wb+4);
        acc1 = __builtin_amdgcn_mfma_f32_16x16x32_bf16(a0, cvt8(wf), acc1, 0, 0, 0);
        *(float4*)(wf) = *(const float4*)(wb+32);  *(float4*)(wf+4) = *(const float4*)(wb+36);
        acc1 = __builtin_amdgcn_mfma_f32_16x16x32_bf16(a1, cvt8(wf), acc1, 0, 0, 0);
        wb = W2 + (size_t)(m + 32) * 64 + q * 8;
        *(float4*)(wf) = *(const float4*)(wb);     *(float4*)(wf+4) = *(const float4*)(wb+4);
        acc2 = __builtin_amdgcn_mfma_f32_16x16x32_bf16(a0, cvt8(wf), acc2, 0, 0, 0);
        *(float4*)(wf) = *(const float4*)(wb+32);  *(float4*)(wf+4) = *(const float4*)(wb+36);
        acc2 = __builtin_amdgcn_mfma_f32_16x16x32_bf16(a1, cvt8(wf), acc2, 0, 0, 0);
        wb = W2 + (size_t)(m + 48) * 64 + q * 8;
        *(float4*)(wf) = *(const float4*)(wb);     *(float4*)(wf+4) = *(const float4*)(wb+4);
        acc3 = __builtin_amdgcn_mfma_f32_16x16x32_bf16(a0, cvt8(wf), acc3, 0, 0, 0);
        *(float4*)(wf) = *(const float4*)(wb+32);  *(float4*)(wf+4) = *(const float4*)(wb+36);
        acc3 = __builtin_amdgcn_mfma_f32_16x16x32_bf16(a1, cvt8(wf), acc3, 0, 0, 0);
    }

    float P[4], Q[4];
#pragma unroll
    for (int r = 0; r < 4; ++r) {
        float s2 = acc0[r]*acc0[r] + acc1[r]*acc1[r] + acc2[r]*acc2[r] + acc3[r]*acc3[r];
        float sh = acc0[r]*hbv[0] + acc1[r]*hbv[1] + acc2[r]*hbv[2] + acc3[r]*hbv[3];
#pragma unroll
        for (int o = 1; o < 16; o <<= 1) {
            s2 += __shfl_xor(s2, o, 64);
            sh += __shfl_xor(sh, o, 64);
        }
        float xn = __shfl(xn_m, q * 4 + r);
        float mxn = fmaxf(sqrtf(s2), EPSV);
        float rt  = tanhf(mxn / xn * artanh_(xn));
        float k1, x2s, xy;
        if (s2 != 0.0f) {
            k1 = rt / mxn;
            float mvn = fmaxf(fabsf(rt), EPSV);
            if (mvn > MAXN) k1 *= MAXN / mvn;
            float cn = fminf(mvn, MAXN);
            x2s = cn * cn;
            xy  = k1 * sh;
        } else { k1 = 0.0f; x2s = 0.0f; xy = 0.0f; }
        float ca = 1.0f + 2.0f * xy + y2;
        float cb = 1.0f - x2s;
        float den = fmaxf(1.0f + 2.0f * xy + x2s * y2, EPSV);
        float hn2 = ca*ca*x2s + 2.0f*ca*cb*xy + cb*cb*y2;
        float hn = fmaxf(sqrtf(hn2) / den, EPSV);
        float hs = 1.0f;
        if (hn > MAXN) { hs = MAXN / hn; hn = MAXN; }
        float lam = artanh_(hn) / hn;
        P[r] = lam * hs * ca * k1 / den;
        Q[r] = lam * hs * cb / den;
    }
#pragma unroll
    for (int r = 0; r < 4; ++r) {
        int ri = nodeBase + q * 4 + r;
        if (ri < N) {
            bfu* orow = xtb2 + (size_t)ri * 64 + m;
            orow[ 0] = f2b(P[r] * acc0[r] + Q[r] * hbv[0]);
            orow[16] = f2b(P[r] * acc1[r] + Q[r] * hbv[1]);
            orow[32] = f2b(P[r] * acc2[r] + Q[r] * hbv[2]);
            orow[48] = f2b(P[r] * acc3[r] + Q[r] * hbv[3]);
        }
    }
}

// ===== gather #2 + final HypAct fused; paired bf16x2 =====
__global__ __launch_bounds__(256) void hgA_gather_out(
    const int* __restrict__ row_start, const int2* __restrict__ csr,
    const bfu* __restrict__ xtb2, float* __restrict__ out, int N) {
    const int lane = threadIdx.x & 63, wv = threadIdx.x >> 6;
    const int d = blockIdx.x * 4 + wv;
    if (d >= N) return;
    const int sl = lane & 31, p = lane >> 5;
    const int n0 = row_start[d], n1 = row_start[d + 1];
    const unsigned int* xt32 = (const unsigned int*)xtb2;
    float a0x = 0.f, a0y = 0.f, a1x = 0.f, a1y = 0.f;
    float a2x = 0.f, a2y = 0.f, a3x = 0.f, a3y = 0.f;
    for (int base = n0; base < n1; base += 64) {
        int cnt = n1 - base; if (cnt > 64) cnt = 64;
        int sL = 0; float wL = 0.0f;
        if (lane < cnt) { int2 rec = csr[base + lane]; sL = rec.x; wL = i2f(rec.y); }
        int j = 0;
        for (; j + 8 <= cnt; j += 8) {
            int   s0 = __shfl(sL, j     + p, 64), s1 = __shfl(sL, j + 2 + p, 64);
            int   s2 = __shfl(sL, j + 4 + p, 64), s3 = __shfl(sL, j + 6 + p, 64);
            float w0 = __shfl(wL, j     + p, 64), w1 = __shfl(wL, j + 2 + p, 64);
            float w2 = __shfl(wL, j + 4 + p, 64), w3 = __shfl(wL, j + 6 + p, 64);
            unsigned int u0 = xt32[(size_t)s0 * 32 + sl];
            unsigned int u1 = xt32[(size_t)s1 * 32 + sl];
            unsigned int u2 = xt32[(size_t)s2 * 32 + sl];
            unsigned int u3 = xt32[(size_t)s3 * 32 + sl];
            a0x = fmaf(w0, uplo(u0), a0x); a0y = fmaf(w0, uphi(u0), a0y);
            a1x = fmaf(w1, uplo(u1), a1x); a1y = fmaf(w1, uphi(u1), a1y);
            a2x = fmaf(w2, uplo(u2), a2x); a2y = fmaf(w2, uphi(u2), a2y);
            a3x = fmaf(w3, uplo(u3), a3x); a3y = fmaf(w3, uphi(u3), a3y);
        }
        for (; j < cnt; j += 2) {
            int   s = __shfl(sL, j + p, 64);
            float w = __shfl(wL, j + p, 64);
            unsigned int u = xt32[(size_t)s * 32 + sl];
            a0x = fmaf(w, uplo(u), a0x); a0y = fmaf(w, uphi(u), a0y);
        }
    }
    float tx = (a0x + a1x) + (a2x + a3x);
    float ty = (a0y + a1y) + (a2y + a3y);
    tx += __shfl_xor(tx, 32, 64);
    ty += __shfl_xor(ty, 32, 64);
    // both 32-lane halves now hold all 64 dims -> half-wave reductions exact
    float ssq = hredsum(tx * tx + ty * ty);
    float n  = fmaxf(sqrtf(ssq), EPSV);
    float th = tanhf(n);
    float g  = th / n;
    float nh = fmaxf(th, EPSV);
    if (nh > MAXN) { g *= MAXN / nh; nh = MAXN; }
    float lamg = (artanh_(nh) / nh) * g;
    float t0 = fmaxf(lamg * tx, 0.0f);
    float t1 = fmaxf(lamg * ty, 0.0f);
    float tsq = hredsum(t0 * t0 + t1 * t1);
    float n2  = fmaxf(sqrtf(tsq), EPSV);
    float th2 = tanhf(n2);
    float g2  = th2 / n2;
    float nh2 = fmaxf(th2, EPSV);
    if (nh2 > MAXN) g2 *= MAXN / nh2;
    if (p == 0)
        *(float2*)(out + (size_t)d * 64 + 2 * sl) = make_float2(g2 * t0, g2 * t1);
}

// ===== fallback kernels (round-9 path, used only if ws too small) =====
__global__ __launch_bounds__(256) void hgA_layer1_fp32(
    const float* __restrict__ x, const float* __restrict__ W1,
    const float* __restrict__ b1v, float* __restrict__ xt, int N)
{
    const int tid = threadIdx.x, lane = tid & 63, wv = tid >> 6;
    const int nodeBase = (blockIdx.x * 4 + wv) * 16;
    if (nodeBase >= N) return;
    float y2;
    float hb = bias_point(b1v, lane, &y2);
    float hbv[4];
#pragma unroll
    for (int t = 0; t < 4; ++t) hbv[t] = __shfl(hb, (lane & 15) + 16 * t);
    const int m = lane & 15, q = lane >> 4;
    v4f acc0 = {0,0,0,0}, acc1 = {0,0,0,0}, acc2 = {0,0,0,0}, acc3 = {0,0,0,0};
    float usq = 0.0f;
    const float* arow = x + (size_t)(nodeBase + m) * 256 + q * 8;
#pragma unroll
    for (int s = 0; s < 8; ++s) {
        float af[8];
        *(float4*)(af)     = *(const float4*)(arow + s * 32);
        *(float4*)(af + 4) = *(const float4*)(arow + s * 32 + 4);
#pragma unroll
        for (int j = 0; j < 8; ++j) usq = fmaf(af[j], af[j], usq);
        v8s a = cvt8(af);
        const float* wbase = W1 + (size_t)m * 256 + s * 32 + q * 8;
        float wf[8];
        *(float4*)(wf) = *(const float4*)(wbase);  *(float4*)(wf+4) = *(const float4*)(wbase+4);
        acc0 = __builtin_amdgcn_mfma_f32_16x16x32_bf16(a, cvt8(wf), acc0, 0, 0, 0);
        *(float4*)(wf) = *(const float4*)(wbase+16*256); *(float4*)(wf+4) = *(const float4*)(wbase+16*256+4);
        acc1 = __builtin_amdgcn_mfma_f32_16x16x32_bf16(a, cvt8(wf), acc1, 0, 0, 0);
        *(float4*)(wf) = *(const float4*)(wbase+32*256); *(float4*)(wf+4) = *(const float4*)(wbase+32*256+4);
        acc2 = __builtin_amdgcn_mfma_f32_16x16x32_bf16(a, cvt8(wf), acc2, 0, 0, 0);
        *(float4*)(wf) = *(const float4*)(wbase+48*256); *(float4*)(wf+4) = *(const float4*)(wbase+48*256+4);
        acc3 = __builtin_amdgcn_mfma_f32_16x16x32_bf16(a, cvt8(wf), acc3, 0, 0, 0);
    }
    usq += __shfl_xor(usq, 16, 64);
    usq += __shfl_xor(usq, 32, 64);
    float P[4], Q[4];
#pragma unroll
    for (int r = 0; r < 4; ++r) {
        float s2 = acc0[r]*acc0[r] + acc1[r]*acc1[r] + acc2[r]*acc2[r] + acc3[r]*acc3[r];
        float sh = acc0[r]*hbv[0] + acc1[r]*hbv[1] + acc2[r]*hbv[2] + acc3[r]*hbv[3];
#pragma unroll
        for (int o = 1; o < 16; o <<= 1) { s2 += __shfl_xor(s2, o, 64); sh += __shfl_xor(sh, o, 64); }
        float usq_r = __shfl(usq, q * 4 + r);
        float n  = fmaxf(sqrtf(usq_r), EPSV);
        float th = tanhf(n);
        float gamma = th / n;
        float xn = fmaxf(th, EPSV);
        if (xn > MAXN) { gamma *= MAXN / xn; xn = MAXN; }
        float mxn = fmaxf(gamma * sqrtf(s2), EPSV);
        float rt  = tanhf(mxn / xn * artanh_(xn));
        float k1, x2s, xy;
        if (s2 != 0.0f) {
            k1 = (rt / mxn) * gamma;
            float mvn = fmaxf(fabsf(rt), EPSV);
            if (mvn > MAXN) k1 *= MAXN / mvn;
            float cn = fminf(mvn, MAXN);
            x2s = cn * cn; xy = k1 * sh;
        } else { k1 = 0.0f; x2s = 0.0f; xy = 0.0f; }
        float ca = 1.0f + 2.0f * xy + y2;
        float cb = 1.0f - x2s;
        float den = fmaxf(1.0f + 2.0f * xy + x2s * y2, EPSV);
        float hn2 = ca*ca*x2s + 2.0f*ca*cb*xy + cb*cb*y2;
        float hn = fmaxf(sqrtf(hn2) / den, EPSV);
        float hs = 1.0f;
        if (hn > MAXN) { hs = MAXN / hn; hn = MAXN; }
        float lam = artanh_(hn) / hn;
        P[r] = lam * hs * ca * k1 / den;
        Q[r] = lam * hs * cb / den;
    }
#pragma unroll
    for (int r = 0; r < 4; ++r) {
        float* orow = xt + (size_t)(nodeBase + q * 4 + r) * 64 + m;
        orow[ 0] = P[r] * acc0[r] + Q[r] * hbv[0];
        orow[16] = P[r] * acc1[r] + Q[r] * hbv[1];
        orow[32] = P[r] * acc2[r] + Q[r] * hbv[2];
        orow[48] = P[r] * acc3[r] + Q[r] * hbv[3];
    }
}

__global__ __launch_bounds__(256) void hgA_scatter(
    const int* __restrict__ src, const int* __restrict__ dst,
    const float* __restrict__ ew,
    const float* __restrict__ xt, float* __restrict__ agg, int E)
{
    const int lane = threadIdx.x & 63;
    const long long wid = ((long long)blockIdx.x * blockDim.x + threadIdx.x) >> 6;
    const long long nw = ((long long)gridDim.x * blockDim.x) >> 6;
    for (long long e = wid; e < E; e += nw) {
        int s = src[e], d = dst[e];
        atomicAdd(&agg[(size_t)d * 64 + lane], ew[e] * xt[(size_t)s * 64 + lane]);
    }
}

__global__ __launch_bounds__(256) void hgA_layer2_fb(
    const float* __restrict__ agg,
    const float* __restrict__ W2, const float* __restrict__ b2v,
    float* __restrict__ xt2, int N)
{
    const int lane = threadIdx.x & 63, wv = threadIdx.x >> 6;
    float y2;
    float hb = bias_point(b2v, lane, &y2);
    const int nw = gridDim.x * 4;
    for (int i = blockIdx.x * 4 + wv; i < N; i += nw) {
        float a = agg[(size_t)i * 64 + lane];
        float xn;
        float x2 = agg_transform(a, &xn);
        float acc = 0.0f;
        const float* Wrow = W2 + (size_t)lane * 64;
        for (int s = 0; s < 64; ++s)
            acc = fmaf(__shfl(x2, s), Wrow[s], acc);
        float o = mobius_tail(acc, xn, hb, y2);
        xt2[(size_t)i * 64 + lane] = o;
    }
}

__global__ __launch_bounds__(256) void hgA_final_fb(
    const float* __restrict__ agg, float* __restrict__ out, int N)
{
    const int lane = threadIdx.x & 63, wv = threadIdx.x >> 6;
    const int nw = gridDim.x * 4;
    for (int i = blockIdx.x * 4 + wv; i < N; i += nw) {
        float a = agg[(size_t)i * 64 + lane];
        float xn;
        float o = agg_transform(a, &xn);
        out[(size_t)i * 64 + lane] = o;
    }
}

extern "C" void kernel_launch(void* const* d_in, const int* in_sizes, int n_in,
                              void* d_out, int out_size, void* d_ws, size_t ws_size,
                              hipStream_t stream)
{
    const float* x  = (const float*)d_in[0];
    const int* src  = (const int*)d_in[1];
    const int* dst  = (const int*)d_in[2];
    const float* ew = (const float*)d_in[3];
    const float* W1 = (const float*)d_in[4];
    const float* b1 = (const float*)d_in[5];
    const float* W2 = (const float*)d_in[6];
    const float* b2 = (const float*)d_in[7];

    const int Dd = in_sizes[5];            // 64
    const int Ff = in_sizes[4] / Dd;       // 256
    const int N  = in_sizes[0] / Ff;       // 80000
    const int E  = in_sizes[1];            // 1280000

    float* out = (float*)d_out;
    float* agg = (float*)d_out;            // CSR path: fp32 agg lives in d_out

    const int NB = (N + 1023) / 1024;      // scan chunks

    // ws layouts:
    // tier A: [xtb bf16 N*64][deg N][rowst N+1][cursor N][rank E][bsum NB][pad][csr 8E]
    // tier B: [xtb bf16 N*64][deg N][rowst N+1][cursor N][pad][csr 8E]
    bfu*  xtb    = (bfu*)d_ws;
    size_t xtb_b = (size_t)N * Dd * 2;
    int*  deg    = (int*)((char*)d_ws + xtb_b);
    int*  rowst  = deg + N;
    int*  cursor = rowst + (N + 1);
    int*  rank   = cursor + N;
    int*  bsum   = rank + E;
    size_t csr_offA = (xtb_b + ((size_t)(3 * N + 1) + (size_t)E + (size_t)NB) * 4 + 7) & ~(size_t)7;
    size_t csr_offB = (xtb_b + (size_t)(3 * N + 1) * 4 + 7) & ~(size_t)7;
    const size_t needA = csr_offA + (size_t)E * 8;
    const size_t needB = csr_offB + (size_t)E * 8;

    const int blkT = (N + 63) / 64;        // wave per 16 nodes (layer kernels)
    const int blkG = (N + 3) / 4;          // wave per dst node (gathers)
    const int blkE4 = (E + 1023) / 1024;   // 4 edges/thread vblocks
    const int n4 = (N * Dd) / 4;

    if (ws_size >= needA) {
        int2* csr = (int2*)((char*)d_ws + csr_offA);
        // layer1 vblock split: count 500 | fill rest
        int L1C = blkT < 500 ? blkT : 500;
        int L1F = blkT - L1C;
        hgA_zero_i32    <<<128, 256, 0, stream>>>(deg, N);
        hgA_count_rank_l1<<<blkE4 + L1C, 256, 0, stream>>>(
            dst, deg, rank, E, blkE4, L1C, x, W1, b1, xtb, N);
        hgA_scan1       <<<NB, 256, 0, stream>>>(deg, rowst, bsum, N);
        hgA_scan2       <<<1,   64, 0, stream>>>(bsum, rowst + N, NB);
        hgA_scan3       <<<NB, 256, 0, stream>>>(rowst, bsum, N);
        hgA_fillr_layer1<<<blkE4 + L1F, 256, 0, stream>>>(
            src, dst, ew, rank, rowst, csr, E, blkE4, L1F, L1C,
            x, W1, b1, xtb, N);
        hgA_gather     <<<blkG, 256, 0, stream>>>(rowst, csr, xtb, agg, N);
        hgA_layer2_mfma<<<blkT, 256, 0, stream>>>(agg, W2, b2, xtb, N);
        hgA_gather_out <<<blkG, 256, 0, stream>>>(rowst, csr, xtb, out, N);
    } else if (ws_size >= needB) {
        // round-10 proven path (atomic cursor fill)
        int2* csr = (int2*)((char*)d_ws + csr_offB);
        const int fillBlocks = 2048;
        hgA_zero_i32   <<<128,  256, 0, stream>>>(deg, N);
        hgA_count      <<<2048, 256, 0, stream>>>(dst, deg, E);
        hgA_scan_l1    <<<1,   1024, 0, stream>>>(
            deg, rowst, cursor, N, x, W1, b1, xtb, 0);
        hgA_fill_layer1<<<fillBlocks + blkT, 256, 0, stream>>>(
            src, dst, ew, cursor, csr, E, fillBlocks, x, W1, b1, xtb, N);
        hgA_gather     <<<blkG, 256, 0, stream>>>(rowst, csr, xtb, agg, N);
        hgA_layer2_mfma<<<blkT, 256, 0, stream>>>(agg, W2, b2, xtb, N);
        hgA_gather_out <<<blkG, 256, 0, stream>>>(rowst, csr, xtb, out, N);
    } else {
        // round-9 fallback: xt fp32 in d_out, agg fp32 in ws
        float* xt_fb  = (float*)d_out;
        float* agg_fb = (float*)d_ws;
        hgA_layer1_fp32<<<blkT, 256, 0, stream>>>(x, W1, b1, xt_fb, N);
        hgA_zero     <<<1024,  256, 0, stream>>>(agg_fb, n4);
        hgA_scatter  <<<16384, 256, 0, stream>>>(src, dst, ew, xt_fb, agg_fb, E);
        hgA_layer2_fb<<<2048,  256, 0, stream>>>(agg_fb, W2, b2, xt_fb, N);
        hgA_zero     <<<1024,  256, 0, stream>>>(agg_fb, n4);
        hgA_scatter  <<<16384, 256, 0, stream>>>(src, dst, ew, xt_fb, agg_fb, E);
        hgA_final_fb <<<2048,  256, 0, stream>>>(agg_fb, out, N);
    }
}

// Round 4
// 341.619 us; speedup vs baseline: 1.3932x; 1.0989x over previous
//
#include <hip/hip_runtime.h>

// HGCN forward (2-layer hyperbolic GCN), Poincare ball c=1. fp32 in/out
// (values bf16-grid). Round 14 = round 13 (375us) with:
//  (a) W1/W2 PRE-CONVERTED to bf16 once (prep kernel, fused with deg-zero).
//      layer1/layer2 load weights as v8s directly -- removes ~1000 VALU
//      instr/wave of repeated fp32->bf16 conversion (layer1 was ~114us of
//      smeared work; W-conversion was ~40% of it). Bit-identical values.
//  (b) gather ILP-8: 16-edge unroll (8 row-loads in flight) + 8 + 2 ladder.
//  (c) l1 vblock split rebalanced 680 (count) / 570 (fill).
// Tiers: A (rank fill + parallel scan) -> B (atomic fill) -> fallback (fp32).

#define EPSV 1e-15f
#define MAXN 0.996f   // (1 - 4e-3) / sqrt(c), c = 1

typedef unsigned short bfu;
typedef __attribute__((ext_vector_type(8))) short v8s;   // 8 bf16 (4 VGPRs)
typedef __attribute__((ext_vector_type(4))) float v4f;   // MFMA acc

__device__ __forceinline__ bfu f2b(float f) {   // fp32 -> bf16, RNE
    unsigned int u;
    __builtin_memcpy(&u, &f, sizeof(u));
    u += 0x7fffu + ((u >> 16) & 1u);
    return (bfu)(u >> 16);
}

__device__ __forceinline__ float b2f(bfu s) {
    unsigned int u = ((unsigned int)s) << 16;
    float f;
    __builtin_memcpy(&f, &u, sizeof(f));
    return f;
}

// low/high bf16 of a packed u32 -> fp32
__device__ __forceinline__ float uplo(unsigned int u) {
    unsigned int v = u << 16; float f;
    __builtin_memcpy(&f, &v, sizeof(f)); return f;
}
__device__ __forceinline__ float uphi(unsigned int u) {
    unsigned int v = u & 0xffff0000u; float f;
    __builtin_memcpy(&f, &v, sizeof(f)); return f;
}

__device__ __forceinline__ v8s cvt8(const float* f) {
    v8s r;
#pragma unroll
    for (int j = 0; j < 8; ++j) r[j] = (short)f2b(f[j]);
    return r;
}

__device__ __forceinline__ float i2f(int i) {
    float f; __builtin_memcpy(&f, &i, sizeof(f)); return f;
}
__device__ __forceinline__ int f2i(float f) {
    int i; __builtin_memcpy(&i, &f, sizeof(i)); return i;
}

__device__ __forceinline__ float wredsum(float v) {
#pragma unroll
    for (int o = 32; o > 0; o >>= 1) v += __shfl_xor(v, o, 64);
    return v;
}

// reduce within each 32-lane half (enough when both halves hold all dims)
__device__ __forceinline__ float hredsum(float v) {
#pragma unroll
    for (int o = 16; o > 0; o >>= 1) v += __shfl_xor(v, o, 64);
    return v;
}

__device__ __forceinline__ float artanh_(float x) {
    x = fminf(fmaxf(x, -1.0f + 1e-7f), 1.0f - 1e-7f);
    return 0.5f * logf((1.0f + x) / (1.0f - x));
}

__device__ __forceinline__ float mobius_tail(float mx, float xn, float hb, float y2) {
    float mxn2 = wredsum(mx * mx);
    unsigned long long nz = __ballot(mx != 0.0f);
    float mxn = fmaxf(sqrtf(mxn2), EPSV);
    float rt = tanhf(mxn / xn * artanh_(xn));
    float mv, x2s;
    if (nz != 0ull) {
        mv = (rt / mxn) * mx;
        float mvn = fmaxf(fabsf(rt), EPSV);
        if (mvn > MAXN) mv *= MAXN / mvn;
        float cn = fminf(mvn, MAXN);
        x2s = cn * cn;
    } else { mv = 0.0f; x2s = 0.0f; }
    float xy = wredsum(mv * hb);
    float ca = 1.0f + 2.0f * xy + y2;
    float cb = 1.0f - x2s;
    float den = fmaxf(1.0f + 2.0f * xy + x2s * y2, EPSV);
    float hj = (ca * mv + cb * hb) / den;
    float hn = fmaxf(sqrtf(wredsum(hj * hj)), EPSV);
    if (hn > MAXN) { hj *= MAXN / hn; hn = MAXN; }
    return (artanh_(hn) / hn) * hj;
}

__device__ __forceinline__ float agg_transform(float a, float* xn_out) {
    float n = fmaxf(sqrtf(wredsum(a * a)), EPSV);
    float th = tanhf(n);
    float g = th / n;
    float nh = fmaxf(th, EPSV);
    if (nh > MAXN) { g *= MAXN / nh; nh = MAXN; }
    float h = g * a;
    float t = fmaxf((artanh_(nh) / nh) * h, 0.0f);
    float n2 = fmaxf(sqrtf(wredsum(t * t)), EPSV);
    float th2 = tanhf(n2);
    float g2 = th2 / n2;
    float nh2 = fmaxf(th2, EPSV);
    if (nh2 > MAXN) { g2 *= MAXN / nh2; nh2 = MAXN; }
    *xn_out = nh2;
    return g2 * t;
}

__device__ __forceinline__ float bias_point(const float* bv, int lane, float* y2) {
    float b = bv[lane];
    float bn = fmaxf(sqrtf(wredsum(b * b)), EPSV);
    float gs = tanhf(bn) / bn;
    float hbn = fmaxf(tanhf(bn), EPSV);
    if (hbn > MAXN) gs *= MAXN / hbn;
    float hb = gs * b;
    *y2 = wredsum(hb * hb);
    return hb;
}

__global__ __launch_bounds__(256) void hgA_zero(float* __restrict__ p, int n4) {
    const float4 z = make_float4(0.f, 0.f, 0.f, 0.f);
    int stride = gridDim.x * blockDim.x;
    for (int i = blockIdx.x * blockDim.x + threadIdx.x; i < n4; i += stride)
        ((float4*)p)[i] = z;
}

// ===== prep: zero deg (blocks 0..127) + convert W1/W2 to bf16 =====
__global__ __launch_bounds__(256) void hgA_prep(
    int* __restrict__ deg, int N,
    const float* __restrict__ W1, const float* __restrict__ W2,
    bfu* __restrict__ w1b, bfu* __restrict__ w2b, int NW1, int NW2)
{
    const int b = blockIdx.x, tid = threadIdx.x;
    if (b < 128) {
        for (int i = b * 256 + tid; i < N; i += 128 * 256) deg[i] = 0;
    } else if (b < 128 + (NW1 + 255) / 256) {
        int i = (b - 128) * 256 + tid;
        if (i < NW1) w1b[i] = f2b(W1[i]);
    } else {
        for (int i = tid; i < NW2; i += 256) w2b[i] = f2b(W2[i]);
    }
}

// ===== layer1 body (MFMA; bf16 weights) -- writes bf16 xt =====
__device__ __forceinline__ void layer1_body(
    int bid, int tid, const float* __restrict__ x, const bfu* __restrict__ w1b,
    const float* __restrict__ b1v, bfu* __restrict__ xtb, int N)
{
    const int lane = tid & 63, wv = tid >> 6;
    const int nodeBase = (bid * 4 + wv) * 16;
    if (nodeBase >= N) return;

    float y2;
    float hb = bias_point(b1v, lane, &y2);
    float hbv[4];
#pragma unroll
    for (int t = 0; t < 4; ++t) hbv[t] = __shfl(hb, (lane & 15) + 16 * t);

    const int m = lane & 15, q = lane >> 4;
    v4f acc0 = {0,0,0,0}, acc1 = {0,0,0,0}, acc2 = {0,0,0,0}, acc3 = {0,0,0,0};
    float usq = 0.0f;

    const float* arow = x + (size_t)(nodeBase + m) * 256 + q * 8;
    const bfu* wrow = w1b + (size_t)m * 256 + q * 8;
#pragma unroll
    for (int s = 0; s < 8; ++s) {
        float af[8];
        *(float4*)(af)     = *(const float4*)(arow + s * 32);
        *(float4*)(af + 4) = *(const float4*)(arow + s * 32 + 4);
#pragma unroll
        for (int j = 0; j < 8; ++j) usq = fmaf(af[j], af[j], usq);
        v8s a = cvt8(af);
        const bfu* wb = wrow + s * 32;
        acc0 = __builtin_amdgcn_mfma_f32_16x16x32_bf16(a, *(const v8s*)(wb), acc0, 0, 0, 0);
        acc1 = __builtin_amdgcn_mfma_f32_16x16x32_bf16(a, *(const v8s*)(wb + 16 * 256), acc1, 0, 0, 0);
        acc2 = __builtin_amdgcn_mfma_f32_16x16x32_bf16(a, *(const v8s*)(wb + 32 * 256), acc2, 0, 0, 0);
        acc3 = __builtin_amdgcn_mfma_f32_16x16x32_bf16(a, *(const v8s*)(wb + 48 * 256), acc3, 0, 0, 0);
    }
    usq += __shfl_xor(usq, 16, 64);
    usq += __shfl_xor(usq, 32, 64);

    float P[4], Q[4];
#pragma unroll
    for (int r = 0; r < 4; ++r) {
        float s2 = acc0[r]*acc0[r] + acc1[r]*acc1[r] + acc2[r]*acc2[r] + acc3[r]*acc3[r];
        float sh = acc0[r]*hbv[0] + acc1[r]*hbv[1] + acc2[r]*hbv[2] + acc3[r]*hbv[3];
#pragma unroll
        for (int o = 1; o < 16; o <<= 1) {
            s2 += __shfl_xor(s2, o, 64);
            sh += __shfl_xor(sh, o, 64);
        }
        float usq_r = __shfl(usq, q * 4 + r);
        float n  = fmaxf(sqrtf(usq_r), EPSV);
        float th = tanhf(n);
        float gamma = th / n;
        float xn = fmaxf(th, EPSV);
        if (xn > MAXN) { gamma *= MAXN / xn; xn = MAXN; }
        float mxn = fmaxf(gamma * sqrtf(s2), EPSV);
        float rt  = tanhf(mxn / xn * artanh_(xn));
        float k1, x2s, xy;
        if (s2 != 0.0f) {
            k1 = (rt / mxn) * gamma;
            float mvn = fmaxf(fabsf(rt), EPSV);
            if (mvn > MAXN) k1 *= MAXN / mvn;
            float cn = fminf(mvn, MAXN);
            x2s = cn * cn;
            xy  = k1 * sh;
        } else { k1 = 0.0f; x2s = 0.0f; xy = 0.0f; }
        float ca = 1.0f + 2.0f * xy + y2;
        float cb = 1.0f - x2s;
        float den = fmaxf(1.0f + 2.0f * xy + x2s * y2, EPSV);
        float hn2 = ca*ca*x2s + 2.0f*ca*cb*xy + cb*cb*y2;
        float hn = fmaxf(sqrtf(hn2) / den, EPSV);
        float hs = 1.0f;
        if (hn > MAXN) { hs = MAXN / hn; hn = MAXN; }
        float lam = artanh_(hn) / hn;
        P[r] = lam * hs * ca * k1 / den;
        Q[r] = lam * hs * cb / den;
    }
#pragma unroll
    for (int r = 0; r < 4; ++r) {
        bfu* orow = xtb + (size_t)(nodeBase + q * 4 + r) * 64 + m;
        orow[ 0] = f2b(P[r] * acc0[r] + Q[r] * hbv[0]);
        orow[16] = f2b(P[r] * acc1[r] + Q[r] * hbv[1]);
        orow[32] = f2b(P[r] * acc2[r] + Q[r] * hbv[2]);
        orow[48] = f2b(P[r] * acc3[r] + Q[r] * hbv[3]);
    }
}

// ===== CSR build =====
__global__ __launch_bounds__(256) void hgA_zero_i32(int* __restrict__ p, int n) {
    int stride = gridDim.x * blockDim.x;
    for (int i = blockIdx.x * blockDim.x + threadIdx.x; i < n; i += stride) p[i] = 0;
}

// tier B count (no rank)
__global__ __launch_bounds__(256) void hgA_count(
    const int* __restrict__ dst, int* __restrict__ deg, int E) {
    int stride = gridDim.x * blockDim.x;
    for (int e = blockIdx.x * blockDim.x + threadIdx.x; e < E; e += stride)
        atomicAdd(&deg[dst[e]], 1);
}

// tier A count_rank + layer1 share (parity-interleaved). count side:
// int4-vectorized, 4 edges/thread, exact grid (nf = ceil(E/1024)).
__global__ __launch_bounds__(256) void hgA_count_rank_l1(
    const int* __restrict__ dst, int* __restrict__ deg, int* __restrict__ rank,
    int E, int nf, int nl,
    const float* __restrict__ x, const bfu* __restrict__ w1b,
    const float* __restrict__ b1v, bfu* __restrict__ xtb, int N)
{
    const int b = blockIdx.x;
    const int mn = nf < nl ? nf : nl;
    bool isC; int idx;
    if (b < 2 * mn) { isC = !(b & 1); idx = b >> 1; }
    else            { isC = (nf > nl); idx = mn + (b - 2 * mn); }
    if (isC) {
        int e0 = (idx * 256 + threadIdx.x) * 4;
        if (e0 + 4 <= E) {
            int4 d4 = *(const int4*)(dst + e0);
            int4 r4;
            r4.x = atomicAdd(&deg[d4.x], 1);
            r4.y = atomicAdd(&deg[d4.y], 1);
            r4.z = atomicAdd(&deg[d4.z], 1);
            r4.w = atomicAdd(&deg[d4.w], 1);
            *(int4*)(rank + e0) = r4;
        } else if (e0 < E) {
            for (int e = e0; e < E; ++e) rank[e] = atomicAdd(&deg[dst[e]], 1);
        }
    } else {
        layer1_body(idx, threadIdx.x, x, w1b, b1v, xtb, N);   // l1off = 0
    }
}

// ===== parallel scan, phase 1: per-1024-chunk exclusive scan + block sums =====
__global__ __launch_bounds__(256) void hgA_scan1(
    const int* __restrict__ deg, int* __restrict__ rowst,
    int* __restrict__ bsum, int N)
{
    __shared__ int wsum[4];
    const int tid = threadIdx.x, lane = tid & 63, wv = tid >> 6;
    const int base = blockIdx.x * 1024 + tid * 4;
    int v0 = 0, v1 = 0, v2 = 0, v3 = 0;
    if (base + 4 <= N) {
        int4 d4 = *(const int4*)(deg + base);
        v0 = d4.x; v1 = d4.y; v2 = d4.z; v3 = d4.w;
    } else {
        if (base + 0 < N) v0 = deg[base + 0];
        if (base + 1 < N) v1 = deg[base + 1];
        if (base + 2 < N) v2 = deg[base + 2];
        if (base + 3 < N) v3 = deg[base + 3];
    }
    const int tsum = v0 + v1 + v2 + v3;
    int incl = tsum;
#pragma unroll
    for (int o = 1; o < 64; o <<= 1) {
        int nb = __shfl_up(incl, o, 64);
        if (lane >= o) incl += nb;
    }
    if (lane == 63) wsum[wv] = incl;
    __syncthreads();
    int add = 0;
#pragma unroll
    for (int w = 0; w < 4; ++w) { int s = wsum[w]; if (w < wv) add += s; }
    const int excl = add + incl - tsum;
    const int e0 = excl, e1 = e0 + v0, e2 = e1 + v1, e3 = e2 + v2;
    if (base + 4 <= N) {
        *(int4*)(rowst + base) = make_int4(e0, e1, e2, e3);
    } else {
        if (base + 0 < N) rowst[base + 0] = e0;
        if (base + 1 < N) rowst[base + 1] = e1;
        if (base + 2 < N) rowst[base + 2] = e2;
        if (base + 3 < N) rowst[base + 3] = e3;
    }
    if (tid == 255) bsum[blockIdx.x] = add + incl;
}

// phase 2: single wave, exclusive-scan the NB block sums in place; total -> *tot
__global__ __launch_bounds__(64) void hgA_scan2(
    int* __restrict__ bsum, int* __restrict__ tot, int NB)
{
    const int lane = threadIdx.x;
    int run = 0;
    for (int b = 0; b < NB; b += 64) {
        int i = b + lane;
        int v = (i < NB) ? bsum[i] : 0;
        int incl = v;
#pragma unroll
        for (int o = 1; o < 64; o <<= 1) {
            int nb = __shfl_up(incl, o, 64);
            if (lane >= o) incl += nb;
        }
        if (i < NB) bsum[i] = run + incl - v;
        run += __shfl(incl, 63);
    }
    if (lane == 0) *tot = run;
}

// phase 3: add per-chunk offsets
__global__ __launch_bounds__(256) void hgA_scan3(
    int* __restrict__ rowst, const int* __restrict__ bsum, int N)
{
    const int base = blockIdx.x * 1024 + threadIdx.x * 4;
    const int off = bsum[blockIdx.x];
    if (base + 4 <= N) {
        int4 r = *(int4*)(rowst + base);
        r.x += off; r.y += off; r.z += off; r.w += off;
        *(int4*)(rowst + base) = r;
    } else {
        for (int i = base; i < N; ++i) rowst[i] += off;
    }
}

// tier B: serial scan (block 0) -- retained as safety net
__global__ __launch_bounds__(1024) void hgA_scan_l1(
    const int* __restrict__ deg, int* __restrict__ row_start,
    int* __restrict__ cursor, int N,
    const float* __restrict__ x, const bfu* __restrict__ w1b,
    const float* __restrict__ b1v, bfu* __restrict__ xtb, int NL)
{
    if (blockIdx.x != 0) {
        int vb = (blockIdx.x - 1) * 4 + (threadIdx.x >> 8);
        if (vb < NL) layer1_body(vb, threadIdx.x & 255, x, w1b, b1v, xtb, N);
        return;
    }
    __shared__ int wsum[16];
    __shared__ int srun;
    const int tid = threadIdx.x, lane = tid & 63, wv = tid >> 6;
    if (tid == 0) srun = 0;
    __syncthreads();
    for (int base = 0; base < N; base += 1024) {
        int i = base + tid;
        int v = (i < N) ? deg[i] : 0;
        int incl = v;
#pragma unroll
        for (int o = 1; o < 64; o <<= 1) {
            int nbr = __shfl_up(incl, o, 64);
            if (lane >= o) incl += nbr;
        }
        if (lane == 63) wsum[wv] = incl;
        __syncthreads();
        int add = 0;
#pragma unroll
        for (int w = 0; w < 16; ++w) { int s = wsum[w]; if (w < wv) add += s; }
        int excl = srun + add + incl - v;
        if (i < N) { row_start[i] = excl; cursor[i] = excl; }
        __syncthreads();
        if (tid == 1023) srun += add + incl;
        __syncthreads();
    }
    if (tid == 0) row_start[N] = srun;
}

// ===== tier B fused: fill (atomic cursor) || layer1 =====
__global__ __launch_bounds__(256) void hgA_fill_layer1(
    const int* __restrict__ src, const int* __restrict__ dst,
    const float* __restrict__ ew, int* __restrict__ cursor,
    int2* __restrict__ csr, int E, int fillBlocks,
    const float* __restrict__ x, const bfu* __restrict__ w1b,
    const float* __restrict__ b1v, bfu* __restrict__ xtb, int N)
{
    const int b = blockIdx.x;
    if (b < fillBlocks) {
        int stride = fillBlocks * blockDim.x;
        for (int e = b * blockDim.x + threadIdx.x; e < E; e += stride) {
            int d = dst[e];
            int slot = atomicAdd(&cursor[d], 1);
            csr[slot] = make_int2(src[e], f2i(ew[e]));
        }
    } else {
        layer1_body(b - fillBlocks, threadIdx.x, x, w1b, b1v, xtb, N);
    }
}

// ===== tier A fused: atomic-free fill (int4 loads) || layer1, interleaved =====
__global__ __launch_bounds__(256) void hgA_fillr_layer1(
    const int* __restrict__ src, const int* __restrict__ dst,
    const float* __restrict__ ew, const int* __restrict__ rank,
    const int* __restrict__ row_start, int2* __restrict__ csr,
    int E, int nf, int nl, int l1off,
    const float* __restrict__ x, const bfu* __restrict__ w1b,
    const float* __restrict__ b1v, bfu* __restrict__ xtb, int N)
{
    const int b = blockIdx.x;
    const int mn = nf < nl ? nf : nl;
    bool isFill; int idx;
    if (b < 2 * mn) { isFill = !(b & 1); idx = b >> 1; }
    else            { isFill = (nf > nl); idx = mn + (b - 2 * mn); }
    if (isFill) {
        int e0 = (idx * 256 + threadIdx.x) * 4;
        if (e0 + 4 <= E) {
            int4  d4 = *(const int4*)(dst + e0);
            int4  s4 = *(const int4*)(src + e0);
            int4  r4 = *(const int4*)(rank + e0);
            float4 w4 = *(const float4*)(ew + e0);
            csr[row_start[d4.x] + r4.x] = make_int2(s4.x, f2i(w4.x));
            csr[row_start[d4.y] + r4.y] = make_int2(s4.y, f2i(w4.y));
            csr[row_start[d4.z] + r4.z] = make_int2(s4.z, f2i(w4.z));
            csr[row_start[d4.w] + r4.w] = make_int2(s4.w, f2i(w4.w));
        } else if (e0 < E) {
            for (int e = e0; e < E; ++e)
                csr[row_start[dst[e]] + rank[e]] = make_int2(src[e], f2i(ew[e]));
        }
    } else {
        layer1_body(l1off + idx, threadIdx.x, x, w1b, b1v, xtb, N);
    }
}

// ===== gather #1: agg[d] = sum w*xtb[src]; paired bf16x2, 16/8/2 ladder =====
__global__ __launch_bounds__(256) void hgA_gather(
    const int* __restrict__ row_start, const int2* __restrict__ csr,
    const bfu* __restrict__ xtb, float* __restrict__ agg, int N) {
    const int lane = threadIdx.x & 63, wv = threadIdx.x >> 6;
    const int d = blockIdx.x * 4 + wv;
    if (d >= N) return;
    const int sl = lane & 31, p = lane >> 5;
    const int n0 = row_start[d], n1 = row_start[d + 1];
    const unsigned int* xt32 = (const unsigned int*)xtb;
    float a0x = 0.f, a0y = 0.f, a1x = 0.f, a1y = 0.f;
    float a2x = 0.f, a2y = 0.f, a3x = 0.f, a3y = 0.f;
    for (int base = n0; base < n1; base += 64) {
        int cnt = n1 - base; if (cnt > 64) cnt = 64;
        int sL = 0; float wL = 0.0f;   // lanes >= cnt keep s=0, w=0 (safe pad)
        if (lane < cnt) { int2 rec = csr[base + lane]; sL = rec.x; wL = i2f(rec.y); }
        int j = 0;
        for (; j + 16 <= cnt; j += 16) {   // 8 loads in flight
            int   s0 = __shfl(sL, j      + p, 64), s1 = __shfl(sL, j +  2 + p, 64);
            int   s2 = __shfl(sL, j +  4 + p, 64), s3 = __shfl(sL, j +  6 + p, 64);
            int   s4 = __shfl(sL, j +  8 + p, 64), s5 = __shfl(sL, j + 10 + p, 64);
            int   s6 = __shfl(sL, j + 12 + p, 64), s7 = __shfl(sL, j + 14 + p, 64);
            float w0 = __shfl(wL, j      + p, 64), w1 = __shfl(wL, j +  2 + p, 64);
            float w2 = __shfl(wL, j +  4 + p, 64), w3 = __shfl(wL, j +  6 + p, 64);
            float w4 = __shfl(wL, j +  8 + p, 64), w5 = __shfl(wL, j + 10 + p, 64);
            float w6 = __shfl(wL, j + 12 + p, 64), w7 = __shfl(wL, j + 14 + p, 64);
            unsigned int u0 = xt32[(size_t)s0 * 32 + sl];
            unsigned int u1 = xt32[(size_t)s1 * 32 + sl];
            unsigned int u2 = xt32[(size_t)s2 * 32 + sl];
            unsigned int u3 = xt32[(size_t)s3 * 32 + sl];
            unsigned int u4 = xt32[(size_t)s4 * 32 + sl];
            unsigned int u5 = xt32[(size_t)s5 * 32 + sl];
            unsigned int u6 = xt32[(size_t)s6 * 32 + sl];
            unsigned int u7 = xt32[(size_t)s7 * 32 + sl];
            a0x = fmaf(w0, uplo(u0), a0x); a0y = fmaf(w0, uphi(u0), a0y);
            a1x = fmaf(w1, uplo(u1), a1x); a1y = fmaf(w1, uphi(u1), a1y);
            a2x = fmaf(w2, uplo(u2), a2x); a2y = fmaf(w2, uphi(u2), a2y);
            a3x = fmaf(w3, uplo(u3), a3x); a3y = fmaf(w3, uphi(u3), a3y);
            a0x = fmaf(w4, uplo(u4), a0x); a0y = fmaf(w4, uphi(u4), a0y);
            a1x = fmaf(w5, uplo(u5), a1x); a1y = fmaf(w5, uphi(u5), a1y);
            a2x = fmaf(w6, uplo(u6), a2x); a2y = fmaf(w6, uphi(u6), a2y);
            a3x = fmaf(w7, uplo(u7), a3x); a3y = fmaf(w7, uphi(u7), a3y);
        }
        for (; j + 8 <= cnt; j += 8) {
            int   s0 = __shfl(sL, j     + p, 64), s1 = __shfl(sL, j + 2 + p, 64);
            int   s2 = __shfl(sL, j + 4 + p, 64), s3 = __shfl(sL, j + 6 + p, 64);
            float w0 = __shfl(wL, j     + p, 64), w1 = __shfl(wL, j + 2 + p, 64);
            float w2 = __shfl(wL, j + 4 + p, 64), w3 = __shfl(wL, j + 6 + p, 64);
            unsigned int u0 = xt32[(size_t)s0 * 32 + sl];
            unsigned int u1 = xt32[(size_t)s1 * 32 + sl];
            unsigned int u2 = xt32[(size_t)s2 * 32 + sl];
            unsigned int u3 = xt32[(size_t)s3 * 32 + sl];
            a0x = fmaf(w0, uplo(u0), a0x); a0y = fmaf(w0, uphi(u0), a0y);
            a1x = fmaf(w1, uplo(u1), a1x); a1y = fmaf(w1, uphi(u1), a1y);
            a2x = fmaf(w2, uplo(u2), a2x); a2y = fmaf(w2, uphi(u2), a2y);
            a3x = fmaf(w3, uplo(u3), a3x); a3y = fmaf(w3, uphi(u3), a3y);
        }
        for (; j < cnt; j += 2) {       // tail (odd edge pairs with w=0 pad)
            int   s = __shfl(sL, j + p, 64);
            float w = __shfl(wL, j + p, 64);
            unsigned int u = xt32[(size_t)s * 32 + sl];
            a0x = fmaf(w, uplo(u), a0x); a0y = fmaf(w, uphi(u), a0y);
        }
    }
    float tx = (a0x + a1x) + (a2x + a3x);
    float ty = (a0y + a1y) + (a2y + a3y);
    tx += __shfl_xor(tx, 32, 64);
    ty += __shfl_xor(ty, 32, 64);
    if (p == 0)
        *(float2*)(agg + (size_t)d * 64 + 2 * sl) = make_float2(tx, ty);
}

// ===== layer 2: MFMA (bf16 W2) fused HypAct+matvec+tail; agg -> xtb2 =====
__global__ __launch_bounds__(256) void hgA_layer2_mfma(
    const float* __restrict__ agg,   // [N,64] fp32 (d_out)
    const bfu* __restrict__ w2b,     // [64,64] bf16 row-major
    const float* __restrict__ b2v,   // [64]
    bfu* __restrict__ xtb2, int N)   // [N,64] bf16 (ws)
{
    const int tid = threadIdx.x, lane = tid & 63, wv = tid >> 6;
    const int nodeBase = (blockIdx.x * 4 + wv) * 16;
    if (nodeBase >= N) return;

    float y2;
    float hb = bias_point(b2v, lane, &y2);
    float hbv[4];
#pragma unroll
    for (int t = 0; t < 4; ++t) hbv[t] = __shfl(hb, (lane & 15) + 16 * t);

    const int m = lane & 15, q = lane >> 4;
    const bool rowok = (nodeBase + m) < N;

    float af0[8], af1[8];
    const float* arow = agg + (size_t)(nodeBase + m) * 64 + q * 8;
    if (rowok) {
        *(float4*)(af0)     = *(const float4*)(arow);
        *(float4*)(af0 + 4) = *(const float4*)(arow + 4);
        *(float4*)(af1)     = *(const float4*)(arow + 32);
        *(float4*)(af1 + 4) = *(const float4*)(arow + 36);
    } else {
#pragma unroll
        for (int j = 0; j < 8; ++j) { af0[j] = 0.0f; af1[j] = 0.0f; }
    }
    float asq = 0.0f;
#pragma unroll
    for (int j = 0; j < 8; ++j) {
        asq = fmaf(af0[j], af0[j], asq);
        asq = fmaf(af1[j], af1[j], asq);
    }
    asq += __shfl_xor(asq, 16, 64);
    asq += __shfl_xor(asq, 32, 64);

    float n  = fmaxf(sqrtf(asq), EPSV);
    float th = tanhf(n);
    float g  = th / n;
    float nh = fmaxf(th, EPSV);
    if (nh > MAXN) { g *= MAXN / nh; nh = MAXN; }
    float lamg = (artanh_(nh) / nh) * g;
    float t0[8], t1[8], tsq = 0.0f;
#pragma unroll
    for (int j = 0; j < 8; ++j) {
        t0[j] = fmaxf(lamg * af0[j], 0.0f);
        t1[j] = fmaxf(lamg * af1[j], 0.0f);
        tsq = fmaf(t0[j], t0[j], tsq);
        tsq = fmaf(t1[j], t1[j], tsq);
    }
    tsq += __shfl_xor(tsq, 16, 64);
    tsq += __shfl_xor(tsq, 32, 64);
    float n2  = fmaxf(sqrtf(tsq), EPSV);
    float th2 = tanhf(n2);
    float g2  = th2 / n2;
    float nh2 = fmaxf(th2, EPSV);
    if (nh2 > MAXN) { g2 *= MAXN / nh2; nh2 = MAXN; }
    float xn_m = nh2;
    float x0[8], x1[8];
#pragma unroll
    for (int j = 0; j < 8; ++j) { x0[j] = g2 * t0[j]; x1[j] = g2 * t1[j]; }
    v8s a0 = cvt8(x0), a1 = cvt8(x1);

    v4f acc0 = {0,0,0,0}, acc1 = {0,0,0,0}, acc2 = {0,0,0,0}, acc3 = {0,0,0,0};
    {
        const bfu* wb;
        wb = w2b + (size_t)(m     ) * 64 + q * 8;
        acc0 = __builtin_amdgcn_mfma_f32_16x16x32_bf16(a0, *(const v8s*)(wb),      acc0, 0, 0, 0);
        acc0 = __builtin_amdgcn_mfma_f32_16x16x32_bf16(a1, *(const v8s*)(wb + 32), acc0, 0, 0, 0);
        wb = w2b + (size_t)(m + 16) * 64 + q * 8;
        acc1 = __builtin_amdgcn_mfma_f32_16x16x32_bf16(a0, *(const v8s*)(wb),      acc1, 0, 0, 0);
        acc1 = __builtin_amdgcn_mfma_f32_16x16x32_bf16(a1, *(const v8s*)(wb + 32), acc1, 0, 0, 0);
        wb = w2b + (size_t)(m + 32) * 64 + q * 8;
        acc2 = __builtin_amdgcn_mfma_f32_16x16x32_bf16(a0, *(const v8s*)(wb),      acc2, 0, 0, 0);
        acc2 = __builtin_amdgcn_mfma_f32_16x16x32_bf16(a1, *(const v8s*)(wb + 32), acc2, 0, 0, 0);
        wb = w2b + (size_t)(m + 48) * 64 + q * 8;
        acc3 = __builtin_amdgcn_mfma_f32_16x16x32_bf16(a0, *(const v8s*)(wb),      acc3, 0, 0, 0);
        acc3 = __builtin_amdgcn_mfma_f32_16x16x32_bf16(a1, *(const v8s*)(wb + 32), acc3, 0, 0, 0);
    }

    float P[4], Q[4];
#pragma unroll
    for (int r = 0; r < 4; ++r) {
        float s2 = acc0[r]*acc0[r] + acc1[r]*acc1[r] + acc2[r]*acc2[r] + acc3[r]*acc3[r];
        float sh = acc0[r]*hbv[0] + acc1[r]*hbv[1] + acc2[r]*hbv[2] + acc3[r]*hbv[3];
#pragma unroll
        for (int o = 1; o < 16; o <<= 1) {
            s2 += __shfl_xor(s2, o, 64);
            sh += __shfl_xor(sh, o, 64);
        }
        float xn = __shfl(xn_m, q * 4 + r);
        float mxn = fmaxf(sqrtf(s2), EPSV);
        float rt  = tanhf(mxn / xn * artanh_(xn));
        float k1, x2s, xy;
        if (s2 != 0.0f) {
            k1 = rt / mxn;
            float mvn = fmaxf(fabsf(rt), EPSV);
            if (mvn > MAXN) k1 *= MAXN / mvn;
            float cn = fminf(mvn, MAXN);
            x2s = cn * cn;
            xy  = k1 * sh;
        } else { k1 = 0.0f; x2s = 0.0f; xy = 0.0f; }
        float ca = 1.0f + 2.0f * xy + y2;
        float cb = 1.0f - x2s;
        float den = fmaxf(1.0f + 2.0f * xy + x2s * y2, EPSV);
        float hn2 = ca*ca*x2s + 2.0f*ca*cb*xy + cb*cb*y2;
        float hn = fmaxf(sqrtf(hn2) / den, EPSV);
        float hs = 1.0f;
        if (hn > MAXN) { hs = MAXN / hn; hn = MAXN; }
        float lam = artanh_(hn) / hn;
        P[r] = lam * hs * ca * k1 / den;
        Q[r] = lam * hs * cb / den;
    }
#pragma unroll
    for (int r = 0; r < 4; ++r) {
        int ri = nodeBase + q * 4 + r;
        if (ri < N) {
            bfu* orow = xtb2 + (size_t)ri * 64 + m;
            orow[ 0] = f2b(P[r] * acc0[r] + Q[r] * hbv[0]);
            orow[16] = f2b(P[r] * acc1[r] + Q[r] * hbv[1]);
            orow[32] = f2b(P[r] * acc2[r] + Q[r] * hbv[2]);
            orow[48] = f2b(P[r] * acc3[r] + Q[r] * hbv[3]);
        }
    }
}

// ===== gather #2 + final HypAct fused; paired bf16x2, 16/8/2 ladder =====
__global__ __launch_bounds__(256) void hgA_gather_out(
    const int* __restrict__ row_start, const int2* __restrict__ csr,
    const bfu* __restrict__ xtb2, float* __restrict__ out, int N) {
    const int lane = threadIdx.x & 63, wv = threadIdx.x >> 6;
    const int d = blockIdx.x * 4 + wv;
    if (d >= N) return;
    const int sl = lane & 31, p = lane >> 5;
    const int n0 = row_start[d], n1 = row_start[d + 1];
    const unsigned int* xt32 = (const unsigned int*)xtb2;
    float a0x = 0.f, a0y = 0.f, a1x = 0.f, a1y = 0.f;
    float a2x = 0.f, a2y = 0.f, a3x = 0.f, a3y = 0.f;
    for (int base = n0; base < n1; base += 64) {
        int cnt = n1 - base; if (cnt > 64) cnt = 64;
        int sL = 0; float wL = 0.0f;
        if (lane < cnt) { int2 rec = csr[base + lane]; sL = rec.x; wL = i2f(rec.y); }
        int j = 0;
        for (; j + 16 <= cnt; j += 16) {
            int   s0 = __shfl(sL, j      + p, 64), s1 = __shfl(sL, j +  2 + p, 64);
            int   s2 = __shfl(sL, j +  4 + p, 64), s3 = __shfl(sL, j +  6 + p, 64);
            int   s4 = __shfl(sL, j +  8 + p, 64), s5 = __shfl(sL, j + 10 + p, 64);
            int   s6 = __shfl(sL, j + 12 + p, 64), s7 = __shfl(sL, j + 14 + p, 64);
            float w0 = __shfl(wL, j      + p, 64), w1 = __shfl(wL, j +  2 + p, 64);
            float w2 = __shfl(wL, j +  4 + p, 64), w3 = __shfl(wL, j +  6 + p, 64);
            float w4 = __shfl(wL, j +  8 + p, 64), w5 = __shfl(wL, j + 10 + p, 64);
            float w6 = __shfl(wL, j + 12 + p, 64), w7 = __shfl(wL, j + 14 + p, 64);
            unsigned int u0 = xt32[(size_t)s0 * 32 + sl];
            unsigned int u1 = xt32[(size_t)s1 * 32 + sl];
            unsigned int u2 = xt32[(size_t)s2 * 32 + sl];
            unsigned int u3 = xt32[(size_t)s3 * 32 + sl];
            unsigned int u4 = xt32[(size_t)s4 * 32 + sl];
            unsigned int u5 = xt32[(size_t)s5 * 32 + sl];
            unsigned int u6 = xt32[(size_t)s6 * 32 + sl];
            unsigned int u7 = xt32[(size_t)s7 * 32 + sl];
            a0x = fmaf(w0, uplo(u0), a0x); a0y = fmaf(w0, uphi(u0), a0y);
            a1x = fmaf(w1, uplo(u1), a1x); a1y = fmaf(w1, uphi(u1), a1y);
            a2x = fmaf(w2, uplo(u2), a2x); a2y = fmaf(w2, uphi(u2), a2y);
            a3x = fmaf(w3, uplo(u3), a3x); a3y = fmaf(w3, uphi(u3), a3y);
            a0x = fmaf(w4, uplo(u4), a0x); a0y = fmaf(w4, uphi(u4), a0y);
            a1x = fmaf(w5, uplo(u5), a1x); a1y = fmaf(w5, uphi(u5), a1y);
            a2x = fmaf(w6, uplo(u6), a2x); a2y = fmaf(w6, uphi(u6), a2y);
            a3x = fmaf(w7, uplo(u7), a3x); a3y = fmaf(w7, uphi(u7), a3y);
        }
        for (; j + 8 <= cnt; j += 8) {
            int   s0 = __shfl(sL, j     + p, 64), s1 = __shfl(sL, j + 2 + p, 64);
            int   s2 = __shfl(sL, j + 4 + p, 64), s3 = __shfl(sL, j + 6 + p, 64);
            float w0 = __shfl(wL, j     + p, 64), w1 = __shfl(wL, j + 2 + p, 64);
            float w2 = __shfl(wL, j + 4 + p, 64), w3 = __shfl(wL, j + 6 + p, 64);
            unsigned int u0 = xt32[(size_t)s0 * 32 + sl];
            unsigned int u1 = xt32[(size_t)s1 * 32 + sl];
            unsigned int u2 = xt32[(size_t)s2 * 32 + sl];
            unsigned int u3 = xt32[(size_t)s3 * 32 + sl];
            a0x = fmaf(w0, uplo(u0), a0x); a0y = fmaf(w0, uphi(u0), a0y);
            a1x = fmaf(w1, uplo(u1), a1x); a1y = fmaf(w1, uphi(u1), a1y);
            a2x = fmaf(w2, uplo(u2), a2x); a2y = fmaf(w2, uphi(u2), a2y);
            a3x = fmaf(w3, uplo(u3), a3x); a3y = fmaf(w3, uphi(u3), a3y);
        }
        for (; j < cnt; j += 2) {
            int   s = __shfl(sL, j + p, 64);
            float w = __shfl(wL, j + p, 64);
            unsigned int u = xt32[(size_t)s * 32 + sl];
            a0x = fmaf(w, uplo(u), a0x); a0y = fmaf(w, uphi(u), a0y);
        }
    }
    float tx = (a0x + a1x) + (a2x + a3x);
    float ty = (a0y + a1y) + (a2y + a3y);
    tx += __shfl_xor(tx, 32, 64);
    ty += __shfl_xor(ty, 32, 64);
    // both 32-lane halves now hold all 64 dims -> half-wave reductions exact
    float ssq = hredsum(tx * tx + ty * ty);
    float n  = fmaxf(sqrtf(ssq), EPSV);
    float th = tanhf(n);
    float g  = th / n;
    float nh = fmaxf(th, EPSV);
    if (nh > MAXN) { g *= MAXN / nh; nh = MAXN; }
    float lamg = (artanh_(nh) / nh) * g;
    float t0 = fmaxf(lamg * tx, 0.0f);
    float t1 = fmaxf(lamg * ty, 0.0f);
    float tsq = hredsum(t0 * t0 + t1 * t1);
    float n2  = fmaxf(sqrtf(tsq), EPSV);
    float th2 = tanhf(n2);
    float g2  = th2 / n2;
    float nh2 = fmaxf(th2, EPSV);
    if (nh2 > MAXN) g2 *= MAXN / nh2;
    if (p == 0)
        *(float2*)(out + (size_t)d * 64 + 2 * sl) = make_float2(g2 * t0, g2 * t1);
}

// ===== fallback kernels (round-9 path, fp32 weights, used only if ws tiny) =====
__global__ __launch_bounds__(256) void hgA_layer1_fp32(
    const float* __restrict__ x, const float* __restrict__ W1,
    const float* __restrict__ b1v, float* __restrict__ xt, int N)
{
    const int tid = threadIdx.x, lane = tid & 63, wv = tid >> 6;
    const int nodeBase = (blockIdx.x * 4 + wv) * 16;
    if (nodeBase >= N) return;
    float y2;
    float hb = bias_point(b1v, lane, &y2);
    float hbv[4];
#pragma unroll
    for (int t = 0; t < 4; ++t) hbv[t] = __shfl(hb, (lane & 15) + 16 * t);
    const int m = lane & 15, q = lane >> 4;
    v4f acc0 = {0,0,0,0}, acc1 = {0,0,0,0}, acc2 = {0,0,0,0}, acc3 = {0,0,0,0};
    float usq = 0.0f;
    const float* arow = x + (size_t)(nodeBase + m) * 256 + q * 8;
#pragma unroll
    for (int s = 0; s < 8; ++s) {
        float af[8];
        *(float4*)(af)     = *(const float4*)(arow + s * 32);
        *(float4*)(af + 4) = *(const float4*)(arow + s * 32 + 4);
#pragma unroll
        for (int j = 0; j < 8; ++j) usq = fmaf(af[j], af[j], usq);
        v8s a = cvt8(af);
        const float* wbase = W1 + (size_t)m * 256 + s * 32 + q * 8;
        float wf[8];
        *(float4*)(wf) = *(const float4*)(wbase);  *(float4*)(wf+4) = *(const float4*)(wbase+4);
        acc0 = __builtin_amdgcn_mfma_f32_16x16x32_bf16(a, cvt8(wf), acc0, 0, 0, 0);
        *(float4*)(wf) = *(const float4*)(wbase+16*256); *(float4*)(wf+4) = *(const float4*)(wbase+16*256+4);
        acc1 = __builtin_amdgcn_mfma_f32_16x16x32_bf16(a, cvt8(wf), acc1, 0, 0, 0);
        *(float4*)(wf) = *(const float4*)(wbase+32*256); *(float4*)(wf+4) = *(const float4*)(wbase+32*256+4);
        acc2 = __builtin_amdgcn_mfma_f32_16x16x32_bf16(a, cvt8(wf), acc2, 0, 0, 0);
        *(float4*)(wf) = *(const float4*)(wbase+48*256); *(float4*)(wf+4) = *(const float4*)(wbase+48*256+4);
        acc3 = __builtin_amdgcn_mfma_f32_16x16x32_bf16(a, cvt8(wf), acc3, 0, 0, 0);
    }
    usq += __shfl_xor(usq, 16, 64);
    usq += __shfl_xor(usq, 32, 64);
    float P[4], Q[4];
#pragma unroll
    for (int r = 0; r < 4; ++r) {
        float s2 = acc0[r]*acc0[r] + acc1[r]*acc1[r] + acc2[r]*acc2[r] + acc3[r]*acc3[r];
        float sh = acc0[r]*hbv[0] + acc1[r]*hbv[1] + acc2[r]*hbv[2] + acc3[r]*hbv[3];
#pragma unroll
        for (int o = 1; o < 16; o <<= 1) { s2 += __shfl_xor(s2, o, 64); sh += __shfl_xor(sh, o, 64); }
        float usq_r = __shfl(usq, q * 4 + r);
        float n  = fmaxf(sqrtf(usq_r), EPSV);
        float th = tanhf(n);
        float gamma = th / n;
        float xn = fmaxf(th, EPSV);
        if (xn > MAXN) { gamma *= MAXN / xn; xn = MAXN; }
        float mxn = fmaxf(gamma * sqrtf(s2), EPSV);
        float rt  = tanhf(mxn / xn * artanh_(xn));
        float k1, x2s, xy;
        if (s2 != 0.0f) {
            k1 = (rt / mxn) * gamma;
            float mvn = fmaxf(fabsf(rt), EPSV);
            if (mvn > MAXN) k1 *= MAXN / mvn;
            float cn = fminf(mvn, MAXN);
            x2s = cn * cn; xy = k1 * sh;
        } else { k1 = 0.0f; x2s = 0.0f; xy = 0.0f; }
        float ca = 1.0f + 2.0f * xy + y2;
        float cb = 1.0f - x2s;
        float den = fmaxf(1.0f + 2.0f * xy + x2s * y2, EPSV);
        float hn2 = ca*ca*x2s + 2.0f*ca*cb*xy + cb*cb*y2;
        float hn = fmaxf(sqrtf(hn2) / den, EPSV);
        float hs = 1.0f;
        if (hn > MAXN) { hs = MAXN / hn; hn = MAXN; }
        float lam = artanh_(hn) / hn;
        P[r] = lam * hs * ca * k1 / den;
        Q[r] = lam * hs * cb / den;
    }
#pragma unroll
    for (int r = 0; r < 4; ++r) {
        float* orow = xt + (size_t)(nodeBase + q * 4 + r) * 64 + m;
        orow[ 0] = P[r] * acc0[r] + Q[r] * hbv[0];
        orow[16] = P[r] * acc1[r] + Q[r] * hbv[1];
        orow[32] = P[r] * acc2[r] + Q[r] * hbv[2];
        orow[48] = P[r] * acc3[r] + Q[r] * hbv[3];
    }
}

__global__ __launch_bounds__(256) void hgA_scatter(
    const int* __restrict__ src, const int* __restrict__ dst,
    const float* __restrict__ ew,
    const float* __restrict__ xt, float* __restrict__ agg, int E)
{
    const int lane = threadIdx.x & 63;
    const long long wid = ((long long)blockIdx.x * blockDim.x + threadIdx.x) >> 6;
    const long long nw = ((long long)gridDim.x * blockDim.x) >> 6;
    for (long long e = wid; e < E; e += nw) {
        int s = src[e], d = dst[e];
        atomicAdd(&agg[(size_t)d * 64 + lane], ew[e] * xt[(size_t)s * 64 + lane]);
    }
}

__global__ __launch_bounds__(256) void hgA_layer2_fb(
    const float* __restrict__ agg,
    const float* __restrict__ W2, const float* __restrict__ b2v,
    float* __restrict__ xt2, int N)
{
    const int lane = threadIdx.x & 63, wv = threadIdx.x >> 6;
    float y2;
    float hb = bias_point(b2v, lane, &y2);
    const int nw = gridDim.x * 4;
    for (int i = blockIdx.x * 4 + wv; i < N; i += nw) {
        float a = agg[(size_t)i * 64 + lane];
        float xn;
        float x2 = agg_transform(a, &xn);
        float acc = 0.0f;
        const float* Wrow = W2 + (size_t)lane * 64;
        for (int s = 0; s < 64; ++s)
            acc = fmaf(__shfl(x2, s), Wrow[s], acc);
        float o = mobius_tail(acc, xn, hb, y2);
        xt2[(size_t)i * 64 + lane] = o;
    }
}

__global__ __launch_bounds__(256) void hgA_final_fb(
    const float* __restrict__ agg, float* __restrict__ out, int N)
{
    const int lane = threadIdx.x & 63, wv = threadIdx.x >> 6;
    const int nw = gridDim.x * 4;
    for (int i = blockIdx.x * 4 + wv; i < N; i += nw) {
        float a = agg[(size_t)i * 64 + lane];
        float xn;
        float o = agg_transform(a, &xn);
        out[(size_t)i * 64 + lane] = o;
    }
}

extern "C" void kernel_launch(void* const* d_in, const int* in_sizes, int n_in,
                              void* d_out, int out_size, void* d_ws, size_t ws_size,
                              hipStream_t stream)
{
    const float* x  = (const float*)d_in[0];
    const int* src  = (const int*)d_in[1];
    const int* dst  = (const int*)d_in[2];
    const float* ew = (const float*)d_in[3];
    const float* W1 = (const float*)d_in[4];
    const float* b1 = (const float*)d_in[5];
    const float* W2 = (const float*)d_in[6];
    const float* b2 = (const float*)d_in[7];

    const int Dd = in_sizes[5];            // 64
    const int Ff = in_sizes[4] / Dd;       // 256
    const int N  = in_sizes[0] / Ff;       // 80000
    const int E  = in_sizes[1];            // 1280000
    const int NW1 = Dd * Ff;               // 16384
    const int NW2 = Dd * Dd;               // 4096

    float* out = (float*)d_out;
    float* agg = (float*)d_out;            // CSR path: fp32 agg lives in d_out

    const int NB = (N + 1023) / 1024;      // scan chunks

    // ws layouts:
    // tier A: [xtb][deg N][rowst N+1][cursor N][rank E][bsum NB][w1b][w2b][pad][csr]
    // tier B: [xtb][deg N][rowst N+1][cursor N][w1b][w2b][pad][csr]
    bfu*  xtb    = (bfu*)d_ws;
    size_t xtb_b = (size_t)N * Dd * 2;
    int*  deg    = (int*)((char*)d_ws + xtb_b);
    int*  rowst  = deg + N;
    int*  cursor = rowst + (N + 1);
    int*  rank   = cursor + N;
    int*  bsum   = rank + E;

    size_t wA_off = (xtb_b + ((size_t)(3 * N + 1) + (size_t)E + (size_t)NB) * 4 + 15) & ~(size_t)15;
    bfu* w1bA = (bfu*)((char*)d_ws + wA_off);
    bfu* w2bA = w1bA + NW1;
    size_t csr_offA = (wA_off + (size_t)(NW1 + NW2) * 2 + 7) & ~(size_t)7;
    const size_t needA = csr_offA + (size_t)E * 8;

    size_t wB_off = (xtb_b + (size_t)(3 * N + 1) * 4 + 15) & ~(size_t)15;
    bfu* w1bB = (bfu*)((char*)d_ws + wB_off);
    bfu* w2bB = w1bB + NW1;
    size_t csr_offB = (wB_off + (size_t)(NW1 + NW2) * 2 + 7) & ~(size_t)7;
    const size_t needB = csr_offB + (size_t)E * 8;

    const int blkT = (N + 63) / 64;        // wave per 16 nodes (layer kernels)
    const int blkG = (N + 3) / 4;          // wave per dst node (gathers)
    const int blkE4 = (E + 1023) / 1024;   // 4 edges/thread vblocks
    const int prepG = 128 + (NW1 + 255) / 256 + 1;
    const int n4 = (N * Dd) / 4;

    if (ws_size >= needA) {
        int2* csr = (int2*)((char*)d_ws + csr_offA);
        // layer1 vblock split: count 680 | fill rest
        int L1C = blkT < 680 ? blkT : 680;
        int L1F = blkT - L1C;
        hgA_prep        <<<prepG, 256, 0, stream>>>(deg, N, W1, W2, w1bA, w2bA, NW1, NW2);
        hgA_count_rank_l1<<<blkE4 + L1C, 256, 0, stream>>>(
            dst, deg, rank, E, blkE4, L1C, x, w1bA, b1, xtb, N);
        hgA_scan1       <<<NB, 256, 0, stream>>>(deg, rowst, bsum, N);
        hgA_scan2       <<<1,   64, 0, stream>>>(bsum, rowst + N, NB);
        hgA_scan3       <<<NB, 256, 0, stream>>>(rowst, bsum, N);
        hgA_fillr_layer1<<<blkE4 + L1F, 256, 0, stream>>>(
            src, dst, ew, rank, rowst, csr, E, blkE4, L1F, L1C,
            x, w1bA, b1, xtb, N);
        hgA_gather     <<<blkG, 256, 0, stream>>>(rowst, csr, xtb, agg, N);
        hgA_layer2_mfma<<<blkT, 256, 0, stream>>>(agg, w2bA, b2, xtb, N);
        hgA_gather_out <<<blkG, 256, 0, stream>>>(rowst, csr, xtb, out, N);
    } else if (ws_size >= needB) {
        // atomic-cursor fill path
        int2* csr = (int2*)((char*)d_ws + csr_offB);
        const int fillBlocks = 2048;
        hgA_prep       <<<prepG, 256, 0, stream>>>(deg, N, W1, W2, w1bB, w2bB, NW1, NW2);
        hgA_count      <<<2048, 256, 0, stream>>>(dst, deg, E);
        hgA_scan_l1    <<<1,   1024, 0, stream>>>(
            deg, rowst, cursor, N, x, w1bB, b1, xtb, 0);
        hgA_fill_layer1<<<fillBlocks + blkT, 256, 0, stream>>>(
            src, dst, ew, cursor, csr, E, fillBlocks, x, w1bB, b1, xtb, N);
        hgA_gather     <<<blkG, 256, 0, stream>>>(rowst, csr, xtb, agg, N);
        hgA_layer2_mfma<<<blkT, 256, 0, stream>>>(agg, w2bB, b2, xtb, N);
        hgA_gather_out <<<blkG, 256, 0, stream>>>(rowst, csr, xtb, out, N);
    } else {
        // round-9 fallback: xt fp32 in d_out, agg fp32 in ws
        float* xt_fb  = (float*)d_out;
        float* agg_fb = (float*)d_ws;
        hgA_layer1_fp32<<<blkT, 256, 0, stream>>>(x, W1, b1, xt_fb, N);
        hgA_zero     <<<1024,  256, 0, stream>>>(agg_fb, n4);
        hgA_scatter  <<<16384, 256, 0, stream>>>(src, dst, ew, xt_fb, agg_fb, E);
        hgA_layer2_fb<<<2048,  256, 0, stream>>>(agg_fb, W2, b2, xt_fb, N);
        hgA_zero     <<<1024,  256, 0, stream>>>(agg_fb, n4);
        hgA_scatter  <<<16384, 256, 0, stream>>>(src, dst, ew, xt_fb, agg_fb, E);
        hgA_final_fb <<<2048,  256, 0, stream>>>(agg_fb, out, N);
    }
}

// Round 5
// 334.781 us; speedup vs baseline: 1.4216x; 1.0204x over previous
//
#include <hip/hip_runtime.h>

// HGCN forward (2-layer hyperbolic GCN), Poincare ball c=1. fp32 in/out
// (values bf16-grid). Round 15 = round 14 (342us) with:
//  (a) QUAD-ROW gathers: 16-lane groups read uint2 (8B) -> one load instr
//      fetches 4 full 128B rows (vs 2 with the paired scheme). Per-16-edge
//      cost drops from ~80 to ~44 instructions; shuffles halved, load instrs
//      halved, same 16 rows in flight. Full row per wave, single dispatch,
//      single CSR walk (round-2's quad failed only due to dim-split re-walk).
//  (b) l1 vblock split shifted 780 (count) / 470 (fill) -- count has latency
//      slack (VALUBusy 11%, occ 28%); fill's exposed tail shrinks.
// Tiers: A (rank fill + parallel scan) -> B (atomic fill) -> fallback (fp32).

#define EPSV 1e-15f
#define MAXN 0.996f   // (1 - 4e-3) / sqrt(c), c = 1

typedef unsigned short bfu;
typedef __attribute__((ext_vector_type(8))) short v8s;   // 8 bf16 (4 VGPRs)
typedef __attribute__((ext_vector_type(4))) float v4f;   // MFMA acc

__device__ __forceinline__ bfu f2b(float f) {   // fp32 -> bf16, RNE
    unsigned int u;
    __builtin_memcpy(&u, &f, sizeof(u));
    u += 0x7fffu + ((u >> 16) & 1u);
    return (bfu)(u >> 16);
}

__device__ __forceinline__ float b2f(bfu s) {
    unsigned int u = ((unsigned int)s) << 16;
    float f;
    __builtin_memcpy(&f, &u, sizeof(f));
    return f;
}

// low/high bf16 of a packed u32 -> fp32
__device__ __forceinline__ float uplo(unsigned int u) {
    unsigned int v = u << 16; float f;
    __builtin_memcpy(&f, &v, sizeof(f)); return f;
}
__device__ __forceinline__ float uphi(unsigned int u) {
    unsigned int v = u & 0xffff0000u; float f;
    __builtin_memcpy(&f, &v, sizeof(f)); return f;
}

__device__ __forceinline__ v8s cvt8(const float* f) {
    v8s r;
#pragma unroll
    for (int j = 0; j < 8; ++j) r[j] = (short)f2b(f[j]);
    return r;
}

__device__ __forceinline__ float i2f(int i) {
    float f; __builtin_memcpy(&f, &i, sizeof(f)); return f;
}
__device__ __forceinline__ int f2i(float f) {
    int i; __builtin_memcpy(&i, &f, sizeof(i)); return i;
}

__device__ __forceinline__ float wredsum(float v) {
#pragma unroll
    for (int o = 32; o > 0; o >>= 1) v += __shfl_xor(v, o, 64);
    return v;
}

__device__ __forceinline__ float artanh_(float x) {
    x = fminf(fmaxf(x, -1.0f + 1e-7f), 1.0f - 1e-7f);
    return 0.5f * logf((1.0f + x) / (1.0f - x));
}

__device__ __forceinline__ float mobius_tail(float mx, float xn, float hb, float y2) {
    float mxn2 = wredsum(mx * mx);
    unsigned long long nz = __ballot(mx != 0.0f);
    float mxn = fmaxf(sqrtf(mxn2), EPSV);
    float rt = tanhf(mxn / xn * artanh_(xn));
    float mv, x2s;
    if (nz != 0ull) {
        mv = (rt / mxn) * mx;
        float mvn = fmaxf(fabsf(rt), EPSV);
        if (mvn > MAXN) mv *= MAXN / mvn;
        float cn = fminf(mvn, MAXN);
        x2s = cn * cn;
    } else { mv = 0.0f; x2s = 0.0f; }
    float xy = wredsum(mv * hb);
    float ca = 1.0f + 2.0f * xy + y2;
    float cb = 1.0f - x2s;
    float den = fmaxf(1.0f + 2.0f * xy + x2s * y2, EPSV);
    float hj = (ca * mv + cb * hb) / den;
    float hn = fmaxf(sqrtf(wredsum(hj * hj)), EPSV);
    if (hn > MAXN) { hj *= MAXN / hn; hn = MAXN; }
    return (artanh_(hn) / hn) * hj;
}

__device__ __forceinline__ float agg_transform(float a, float* xn_out) {
    float n = fmaxf(sqrtf(wredsum(a * a)), EPSV);
    float th = tanhf(n);
    float g = th / n;
    float nh = fmaxf(th, EPSV);
    if (nh > MAXN) { g *= MAXN / nh; nh = MAXN; }
    float h = g * a;
    float t = fmaxf((artanh_(nh) / nh) * h, 0.0f);
    float n2 = fmaxf(sqrtf(wredsum(t * t)), EPSV);
    float th2 = tanhf(n2);
    float g2 = th2 / n2;
    float nh2 = fmaxf(th2, EPSV);
    if (nh2 > MAXN) { g2 *= MAXN / nh2; nh2 = MAXN; }
    *xn_out = nh2;
    return g2 * t;
}

__device__ __forceinline__ float bias_point(const float* bv, int lane, float* y2) {
    float b = bv[lane];
    float bn = fmaxf(sqrtf(wredsum(b * b)), EPSV);
    float gs = tanhf(bn) / bn;
    float hbn = fmaxf(tanhf(bn), EPSV);
    if (hbn > MAXN) gs *= MAXN / hbn;
    float hb = gs * b;
    *y2 = wredsum(hb * hb);
    return hb;
}

__global__ __launch_bounds__(256) void hgA_zero(float* __restrict__ p, int n4) {
    const float4 z = make_float4(0.f, 0.f, 0.f, 0.f);
    int stride = gridDim.x * blockDim.x;
    for (int i = blockIdx.x * blockDim.x + threadIdx.x; i < n4; i += stride)
        ((float4*)p)[i] = z;
}

// ===== prep: zero deg (blocks 0..127) + convert W1/W2 to bf16 =====
__global__ __launch_bounds__(256) void hgA_prep(
    int* __restrict__ deg, int N,
    const float* __restrict__ W1, const float* __restrict__ W2,
    bfu* __restrict__ w1b, bfu* __restrict__ w2b, int NW1, int NW2)
{
    const int b = blockIdx.x, tid = threadIdx.x;
    if (b < 128) {
        for (int i = b * 256 + tid; i < N; i += 128 * 256) deg[i] = 0;
    } else if (b < 128 + (NW1 + 255) / 256) {
        int i = (b - 128) * 256 + tid;
        if (i < NW1) w1b[i] = f2b(W1[i]);
    } else {
        for (int i = tid; i < NW2; i += 256) w2b[i] = f2b(W2[i]);
    }
}

// ===== layer1 body (MFMA; bf16 weights) -- writes bf16 xt =====
__device__ __forceinline__ void layer1_body(
    int bid, int tid, const float* __restrict__ x, const bfu* __restrict__ w1b,
    const float* __restrict__ b1v, bfu* __restrict__ xtb, int N)
{
    const int lane = tid & 63, wv = tid >> 6;
    const int nodeBase = (bid * 4 + wv) * 16;
    if (nodeBase >= N) return;

    float y2;
    float hb = bias_point(b1v, lane, &y2);
    float hbv[4];
#pragma unroll
    for (int t = 0; t < 4; ++t) hbv[t] = __shfl(hb, (lane & 15) + 16 * t);

    const int m = lane & 15, q = lane >> 4;
    v4f acc0 = {0,0,0,0}, acc1 = {0,0,0,0}, acc2 = {0,0,0,0}, acc3 = {0,0,0,0};
    float usq = 0.0f;

    const float* arow = x + (size_t)(nodeBase + m) * 256 + q * 8;
    const bfu* wrow = w1b + (size_t)m * 256 + q * 8;
#pragma unroll
    for (int s = 0; s < 8; ++s) {
        float af[8];
        *(float4*)(af)     = *(const float4*)(arow + s * 32);
        *(float4*)(af + 4) = *(const float4*)(arow + s * 32 + 4);
#pragma unroll
        for (int j = 0; j < 8; ++j) usq = fmaf(af[j], af[j], usq);
        v8s a = cvt8(af);
        const bfu* wb = wrow + s * 32;
        acc0 = __builtin_amdgcn_mfma_f32_16x16x32_bf16(a, *(const v8s*)(wb), acc0, 0, 0, 0);
        acc1 = __builtin_amdgcn_mfma_f32_16x16x32_bf16(a, *(const v8s*)(wb + 16 * 256), acc1, 0, 0, 0);
        acc2 = __builtin_amdgcn_mfma_f32_16x16x32_bf16(a, *(const v8s*)(wb + 32 * 256), acc2, 0, 0, 0);
        acc3 = __builtin_amdgcn_mfma_f32_16x16x32_bf16(a, *(const v8s*)(wb + 48 * 256), acc3, 0, 0, 0);
    }
    usq += __shfl_xor(usq, 16, 64);
    usq += __shfl_xor(usq, 32, 64);

    float P[4], Q[4];
#pragma unroll
    for (int r = 0; r < 4; ++r) {
        float s2 = acc0[r]*acc0[r] + acc1[r]*acc1[r] + acc2[r]*acc2[r] + acc3[r]*acc3[r];
        float sh = acc0[r]*hbv[0] + acc1[r]*hbv[1] + acc2[r]*hbv[2] + acc3[r]*hbv[3];
#pragma unroll
        for (int o = 1; o < 16; o <<= 1) {
            s2 += __shfl_xor(s2, o, 64);
            sh += __shfl_xor(sh, o, 64);
        }
        float usq_r = __shfl(usq, q * 4 + r);
        float n  = fmaxf(sqrtf(usq_r), EPSV);
        float th = tanhf(n);
        float gamma = th / n;
        float xn = fmaxf(th, EPSV);
        if (xn > MAXN) { gamma *= MAXN / xn; xn = MAXN; }
        float mxn = fmaxf(gamma * sqrtf(s2), EPSV);
        float rt  = tanhf(mxn / xn * artanh_(xn));
        float k1, x2s, xy;
        if (s2 != 0.0f) {
            k1 = (rt / mxn) * gamma;
            float mvn = fmaxf(fabsf(rt), EPSV);
            if (mvn > MAXN) k1 *= MAXN / mvn;
            float cn = fminf(mvn, MAXN);
            x2s = cn * cn;
            xy  = k1 * sh;
        } else { k1 = 0.0f; x2s = 0.0f; xy = 0.0f; }
        float ca = 1.0f + 2.0f * xy + y2;
        float cb = 1.0f - x2s;
        float den = fmaxf(1.0f + 2.0f * xy + x2s * y2, EPSV);
        float hn2 = ca*ca*x2s + 2.0f*ca*cb*xy + cb*cb*y2;
        float hn = fmaxf(sqrtf(hn2) / den, EPSV);
        float hs = 1.0f;
        if (hn > MAXN) { hs = MAXN / hn; hn = MAXN; }
        float lam = artanh_(hn) / hn;
        P[r] = lam * hs * ca * k1 / den;
        Q[r] = lam * hs * cb / den;
    }
#pragma unroll
    for (int r = 0; r < 4; ++r) {
        bfu* orow = xtb + (size_t)(nodeBase + q * 4 + r) * 64 + m;
        orow[ 0] = f2b(P[r] * acc0[r] + Q[r] * hbv[0]);
        orow[16] = f2b(P[r] * acc1[r] + Q[r] * hbv[1]);
        orow[32] = f2b(P[r] * acc2[r] + Q[r] * hbv[2]);
        orow[48] = f2b(P[r] * acc3[r] + Q[r] * hbv[3]);
    }
}

// ===== CSR build =====
__global__ __launch_bounds__(256) void hgA_zero_i32(int* __restrict__ p, int n) {
    int stride = gridDim.x * blockDim.x;
    for (int i = blockIdx.x * blockDim.x + threadIdx.x; i < n; i += stride) p[i] = 0;
}

// tier B count (no rank)
__global__ __launch_bounds__(256) void hgA_count(
    const int* __restrict__ dst, int* __restrict__ deg, int E) {
    int stride = gridDim.x * blockDim.x;
    for (int e = blockIdx.x * blockDim.x + threadIdx.x; e < E; e += stride)
        atomicAdd(&deg[dst[e]], 1);
}

// tier A count_rank + layer1 share (parity-interleaved). count side:
// int4-vectorized, 4 edges/thread, exact grid (nf = ceil(E/1024)).
__global__ __launch_bounds__(256) void hgA_count_rank_l1(
    const int* __restrict__ dst, int* __restrict__ deg, int* __restrict__ rank,
    int E, int nf, int nl,
    const float* __restrict__ x, const bfu* __restrict__ w1b,
    const float* __restrict__ b1v, bfu* __restrict__ xtb, int N)
{
    const int b = blockIdx.x;
    const int mn = nf < nl ? nf : nl;
    bool isC; int idx;
    if (b < 2 * mn) { isC = !(b & 1); idx = b >> 1; }
    else            { isC = (nf > nl); idx = mn + (b - 2 * mn); }
    if (isC) {
        int e0 = (idx * 256 + threadIdx.x) * 4;
        if (e0 + 4 <= E) {
            int4 d4 = *(const int4*)(dst + e0);
            int4 r4;
            r4.x = atomicAdd(&deg[d4.x], 1);
            r4.y = atomicAdd(&deg[d4.y], 1);
            r4.z = atomicAdd(&deg[d4.z], 1);
            r4.w = atomicAdd(&deg[d4.w], 1);
            *(int4*)(rank + e0) = r4;
        } else if (e0 < E) {
            for (int e = e0; e < E; ++e) rank[e] = atomicAdd(&deg[dst[e]], 1);
        }
    } else {
        layer1_body(idx, threadIdx.x, x, w1b, b1v, xtb, N);   // l1off = 0
    }
}

// ===== parallel scan, phase 1: per-1024-chunk exclusive scan + block sums =====
__global__ __launch_bounds__(256) void hgA_scan1(
    const int* __restrict__ deg, int* __restrict__ rowst,
    int* __restrict__ bsum, int N)
{
    __shared__ int wsum[4];
    const int tid = threadIdx.x, lane = tid & 63, wv = tid >> 6;
    const int base = blockIdx.x * 1024 + tid * 4;
    int v0 = 0, v1 = 0, v2 = 0, v3 = 0;
    if (base + 4 <= N) {
        int4 d4 = *(const int4*)(deg + base);
        v0 = d4.x; v1 = d4.y; v2 = d4.z; v3 = d4.w;
    } else {
        if (base + 0 < N) v0 = deg[base + 0];
        if (base + 1 < N) v1 = deg[base + 1];
        if (base + 2 < N) v2 = deg[base + 2];
        if (base + 3 < N) v3 = deg[base + 3];
    }
    const int tsum = v0 + v1 + v2 + v3;
    int incl = tsum;
#pragma unroll
    for (int o = 1; o < 64; o <<= 1) {
        int nb = __shfl_up(incl, o, 64);
        if (lane >= o) incl += nb;
    }
    if (lane == 63) wsum[wv] = incl;
    __syncthreads();
    int add = 0;
#pragma unroll
    for (int w = 0; w < 4; ++w) { int s = wsum[w]; if (w < wv) add += s; }
    const int excl = add + incl - tsum;
    const int e0 = excl, e1 = e0 + v0, e2 = e1 + v1, e3 = e2 + v2;
    if (base + 4 <= N) {
        *(int4*)(rowst + base) = make_int4(e0, e1, e2, e3);
    } else {
        if (base + 0 < N) rowst[base + 0] = e0;
        if (base + 1 < N) rowst[base + 1] = e1;
        if (base + 2 < N) rowst[base + 2] = e2;
        if (base + 3 < N) rowst[base + 3] = e3;
    }
    if (tid == 255) bsum[blockIdx.x] = add + incl;
}

// phase 2: single wave, exclusive-scan the NB block sums in place; total -> *tot
__global__ __launch_bounds__(64) void hgA_scan2(
    int* __restrict__ bsum, int* __restrict__ tot, int NB)
{
    const int lane = threadIdx.x;
    int run = 0;
    for (int b = 0; b < NB; b += 64) {
        int i = b + lane;
        int v = (i < NB) ? bsum[i] : 0;
        int incl = v;
#pragma unroll
        for (int o = 1; o < 64; o <<= 1) {
            int nb = __shfl_up(incl, o, 64);
            if (lane >= o) incl += nb;
        }
        if (i < NB) bsum[i] = run + incl - v;
        run += __shfl(incl, 63);
    }
    if (lane == 0) *tot = run;
}

// phase 3: add per-chunk offsets
__global__ __launch_bounds__(256) void hgA_scan3(
    int* __restrict__ rowst, const int* __restrict__ bsum, int N)
{
    const int base = blockIdx.x * 1024 + threadIdx.x * 4;
    const int off = bsum[blockIdx.x];
    if (base + 4 <= N) {
        int4 r = *(int4*)(rowst + base);
        r.x += off; r.y += off; r.z += off; r.w += off;
        *(int4*)(rowst + base) = r;
    } else {
        for (int i = base; i < N; ++i) rowst[i] += off;
    }
}

// tier B: serial scan (block 0) -- retained as safety net
__global__ __launch_bounds__(1024) void hgA_scan_l1(
    const int* __restrict__ deg, int* __restrict__ row_start,
    int* __restrict__ cursor, int N,
    const float* __restrict__ x, const bfu* __restrict__ w1b,
    const float* __restrict__ b1v, bfu* __restrict__ xtb, int NL)
{
    if (blockIdx.x != 0) {
        int vb = (blockIdx.x - 1) * 4 + (threadIdx.x >> 8);
        if (vb < NL) layer1_body(vb, threadIdx.x & 255, x, w1b, b1v, xtb, N);
        return;
    }
    __shared__ int wsum[16];
    __shared__ int srun;
    const int tid = threadIdx.x, lane = tid & 63, wv = tid >> 6;
    if (tid == 0) srun = 0;
    __syncthreads();
    for (int base = 0; base < N; base += 1024) {
        int i = base + tid;
        int v = (i < N) ? deg[i] : 0;
        int incl = v;
#pragma unroll
        for (int o = 1; o < 64; o <<= 1) {
            int nbr = __shfl_up(incl, o, 64);
            if (lane >= o) incl += nbr;
        }
        if (lane == 63) wsum[wv] = incl;
        __syncthreads();
        int add = 0;
#pragma unroll
        for (int w = 0; w < 16; ++w) { int s = wsum[w]; if (w < wv) add += s; }
        int excl = srun + add + incl - v;
        if (i < N) { row_start[i] = excl; cursor[i] = excl; }
        __syncthreads();
        if (tid == 1023) srun += add + incl;
        __syncthreads();
    }
    if (tid == 0) row_start[N] = srun;
}

// ===== tier B fused: fill (atomic cursor) || layer1 =====
__global__ __launch_bounds__(256) void hgA_fill_layer1(
    const int* __restrict__ src, const int* __restrict__ dst,
    const float* __restrict__ ew, int* __restrict__ cursor,
    int2* __restrict__ csr, int E, int fillBlocks,
    const float* __restrict__ x, const bfu* __restrict__ w1b,
    const float* __restrict__ b1v, bfu* __restrict__ xtb, int N)
{
    const int b = blockIdx.x;
    if (b < fillBlocks) {
        int stride = fillBlocks * blockDim.x;
        for (int e = b * blockDim.x + threadIdx.x; e < E; e += stride) {
            int d = dst[e];
            int slot = atomicAdd(&cursor[d], 1);
            csr[slot] = make_int2(src[e], f2i(ew[e]));
        }
    } else {
        layer1_body(b - fillBlocks, threadIdx.x, x, w1b, b1v, xtb, N);
    }
}

// ===== tier A fused: atomic-free fill (int4 loads) || layer1, interleaved =====
__global__ __launch_bounds__(256) void hgA_fillr_layer1(
    const int* __restrict__ src, const int* __restrict__ dst,
    const float* __restrict__ ew, const int* __restrict__ rank,
    const int* __restrict__ row_start, int2* __restrict__ csr,
    int E, int nf, int nl, int l1off,
    const float* __restrict__ x, const bfu* __restrict__ w1b,
    const float* __restrict__ b1v, bfu* __restrict__ xtb, int N)
{
    const int b = blockIdx.x;
    const int mn = nf < nl ? nf : nl;
    bool isFill; int idx;
    if (b < 2 * mn) { isFill = !(b & 1); idx = b >> 1; }
    else            { isFill = (nf > nl); idx = mn + (b - 2 * mn); }
    if (isFill) {
        int e0 = (idx * 256 + threadIdx.x) * 4;
        if (e0 + 4 <= E) {
            int4  d4 = *(const int4*)(dst + e0);
            int4  s4 = *(const int4*)(src + e0);
            int4  r4 = *(const int4*)(rank + e0);
            float4 w4 = *(const float4*)(ew + e0);
            csr[row_start[d4.x] + r4.x] = make_int2(s4.x, f2i(w4.x));
            csr[row_start[d4.y] + r4.y] = make_int2(s4.y, f2i(w4.y));
            csr[row_start[d4.z] + r4.z] = make_int2(s4.z, f2i(w4.z));
            csr[row_start[d4.w] + r4.w] = make_int2(s4.w, f2i(w4.w));
        } else if (e0 < E) {
            for (int e = e0; e < E; ++e)
                csr[row_start[dst[e]] + rank[e]] = make_int2(src[e], f2i(ew[e]));
        }
    } else {
        layer1_body(l1off + idx, threadIdx.x, x, w1b, b1v, xtb, N);
    }
}

// ===== quad-row gather core: 16-lane groups, uint2/lane -> 4 rows per load =====
// lane = p*16 + sl (p in [0,4)); after fold, EVERY lane holds dims
// [4*sl, 4*sl+4) of the weighted row sum in t0..t3.
#define GACC_QUAD(T64, CSR, N0, N1, LANE, T0, T1, T2, T3)                      \
    {                                                                          \
        const int sl_ = (LANE) & 15, p_ = (LANE) >> 4;                         \
        float a0x=0.f,a0y=0.f,a0z=0.f,a0w=0.f;                                 \
        float a1x=0.f,a1y=0.f,a1z=0.f,a1w=0.f;                                 \
        float a2x=0.f,a2y=0.f,a2z=0.f,a2w=0.f;                                 \
        float a3x=0.f,a3y=0.f,a3z=0.f,a3w=0.f;                                 \
        for (int base = (N0); base < (N1); base += 64) {                       \
            int cnt = (N1) - base; if (cnt > 64) cnt = 64;                     \
            int sL = 0; float wL = 0.0f;                                       \
            if ((LANE) < cnt) { int2 rec = (CSR)[base + (LANE)];               \
                                sL = rec.x; wL = i2f(rec.y); }                 \
            int j = 0;                                                         \
            for (; j + 16 <= cnt; j += 16) {                                   \
                int   s0 = __shfl(sL, j      + p_, 64);                        \
                int   s1 = __shfl(sL, j +  4 + p_, 64);                        \
                int   s2 = __shfl(sL, j +  8 + p_, 64);                        \
                int   s3 = __shfl(sL, j + 12 + p_, 64);                        \
                float w0 = __shfl(wL, j      + p_, 64);                        \
                float w1 = __shfl(wL, j +  4 + p_, 64);                        \
                float w2 = __shfl(wL, j +  8 + p_, 64);                        \
                float w3 = __shfl(wL, j + 12 + p_, 64);                        \
                uint2 u0 = (T64)[(size_t)s0 * 16 + sl_];                       \
                uint2 u1 = (T64)[(size_t)s1 * 16 + sl_];                       \
                uint2 u2 = (T64)[(size_t)s2 * 16 + sl_];                       \
                uint2 u3 = (T64)[(size_t)s3 * 16 + sl_];                       \
                a0x = fmaf(w0, uplo(u0.x), a0x); a0y = fmaf(w0, uphi(u0.x), a0y); \
                a0z = fmaf(w0, uplo(u0.y), a0z); a0w = fmaf(w0, uphi(u0.y), a0w); \
                a1x = fmaf(w1, uplo(u1.x), a1x); a1y = fmaf(w1, uphi(u1.x), a1y); \
                a1z = fmaf(w1, uplo(u1.y), a1z); a1w = fmaf(w1, uphi(u1.y), a1w); \
                a2x = fmaf(w2, uplo(u2.x), a2x); a2y = fmaf(w2, uphi(u2.x), a2y); \
                a2z = fmaf(w2, uplo(u2.y), a2z); a2w = fmaf(w2, uphi(u2.y), a2w); \
                a3x = fmaf(w3, uplo(u3.x), a3x); a3y = fmaf(w3, uphi(u3.x), a3y); \
                a3z = fmaf(w3, uplo(u3.y), a3z); a3w = fmaf(w3, uphi(u3.y), a3w); \
            }                                                                  \
            for (; j + 8 <= cnt; j += 8) {                                     \
                int   s0 = __shfl(sL, j     + p_, 64);                         \
                int   s1 = __shfl(sL, j + 4 + p_, 64);                         \
                float w0 = __shfl(wL, j     + p_, 64);                         \
                float w1 = __shfl(wL, j + 4 + p_, 64);                         \
                uint2 u0 = (T64)[(size_t)s0 * 16 + sl_];                       \
                uint2 u1 = (T64)[(size_t)s1 * 16 + sl_];                       \
                a0x = fmaf(w0, uplo(u0.x), a0x); a0y = fmaf(w0, uphi(u0.x), a0y); \
                a0z = fmaf(w0, uplo(u0.y), a0z); a0w = fmaf(w0, uphi(u0.y), a0w); \
                a1x = fmaf(w1, uplo(u1.x), a1x); a1y = fmaf(w1, uphi(u1.x), a1y); \
                a1z = fmaf(w1, uplo(u1.y), a1z); a1w = fmaf(w1, uphi(u1.y), a1w); \
            }                                                                  \
            for (; j < cnt; j += 4) {   /* 4 edges/step, w=0 pads safe */      \
                int   s = __shfl(sL, j + p_, 64);                              \
                float w = __shfl(wL, j + p_, 64);                              \
                uint2 u = (T64)[(size_t)s * 16 + sl_];                         \
                a0x = fmaf(w, uplo(u.x), a0x); a0y = fmaf(w, uphi(u.x), a0y);  \
                a0z = fmaf(w, uplo(u.y), a0z); a0w = fmaf(w, uphi(u.y), a0w);  \
            }                                                                  \
        }                                                                      \
        T0 = (a0x + a1x) + (a2x + a3x);                                        \
        T1 = (a0y + a1y) + (a2y + a3y);                                        \
        T2 = (a0z + a1z) + (a2z + a3z);                                        \
        T3 = (a0w + a1w) + (a2w + a3w);                                        \
        T0 += __shfl_xor(T0, 16, 64); T0 += __shfl_xor(T0, 32, 64);            \
        T1 += __shfl_xor(T1, 16, 64); T1 += __shfl_xor(T1, 32, 64);            \
        T2 += __shfl_xor(T2, 16, 64); T2 += __shfl_xor(T2, 32, 64);            \
        T3 += __shfl_xor(T3, 16, 64); T3 += __shfl_xor(T3, 32, 64);            \
    }

// gather #1: agg[d] = sum w*xtb[src]
__global__ __launch_bounds__(256) void hgA_gather(
    const int* __restrict__ row_start, const int2* __restrict__ csr,
    const bfu* __restrict__ xtb, float* __restrict__ agg, int N) {
    const int lane = threadIdx.x & 63, wv = threadIdx.x >> 6;
    const int d = blockIdx.x * 4 + wv;
    if (d >= N) return;
    const uint2* t64 = (const uint2*)xtb;
    const int n0 = row_start[d], n1 = row_start[d + 1];
    float t0, t1, t2, t3;
    GACC_QUAD(t64, csr, n0, n1, lane, t0, t1, t2, t3);
    if ((lane >> 4) == 0)
        *(float4*)(agg + (size_t)d * 64 + 4 * (lane & 15)) =
            make_float4(t0, t1, t2, t3);
}

// gather #2 + final HypAct fused
__global__ __launch_bounds__(256) void hgA_gather_out(
    const int* __restrict__ row_start, const int2* __restrict__ csr,
    const bfu* __restrict__ xtb2, float* __restrict__ out, int N) {
    const int lane = threadIdx.x & 63, wv = threadIdx.x >> 6;
    const int d = blockIdx.x * 4 + wv;
    if (d >= N) return;
    const uint2* t64 = (const uint2*)xtb2;
    const int n0 = row_start[d], n1 = row_start[d + 1];
    float t0, t1, t2, t3;
    GACC_QUAD(t64, csr, n0, n1, lane, t0, t1, t2, t3);
    // every 16-lane group holds the full row (4 dims/lane) -> group reduce
    float ssq = t0*t0 + t1*t1 + t2*t2 + t3*t3;
#pragma unroll
    for (int o = 1; o < 16; o <<= 1) ssq += __shfl_xor(ssq, o, 64);
    float n  = fmaxf(sqrtf(ssq), EPSV);
    float th = tanhf(n);
    float g  = th / n;
    float nh = fmaxf(th, EPSV);
    if (nh > MAXN) { g *= MAXN / nh; nh = MAXN; }
    float lamg = (artanh_(nh) / nh) * g;
    float r0 = fmaxf(lamg * t0, 0.0f);
    float r1 = fmaxf(lamg * t1, 0.0f);
    float r2 = fmaxf(lamg * t2, 0.0f);
    float r3 = fmaxf(lamg * t3, 0.0f);
    float tsq = r0*r0 + r1*r1 + r2*r2 + r3*r3;
#pragma unroll
    for (int o = 1; o < 16; o <<= 1) tsq += __shfl_xor(tsq, o, 64);
    float n2  = fmaxf(sqrtf(tsq), EPSV);
    float th2 = tanhf(n2);
    float g2  = th2 / n2;
    float nh2 = fmaxf(th2, EPSV);
    if (nh2 > MAXN) g2 *= MAXN / nh2;
    if ((lane >> 4) == 0)
        *(float4*)(out + (size_t)d * 64 + 4 * (lane & 15)) =
            make_float4(g2 * r0, g2 * r1, g2 * r2, g2 * r3);
}

// ===== layer 2: MFMA (bf16 W2) fused HypAct+matvec+tail; agg -> xtb2 =====
__global__ __launch_bounds__(256) void hgA_layer2_mfma(
    const float* __restrict__ agg,   // [N,64] fp32 (d_out)
    const bfu* __restrict__ w2b,     // [64,64] bf16 row-major
    const float* __restrict__ b2v,   // [64]
    bfu* __restrict__ xtb2, int N)   // [N,64] bf16 (ws)
{
    const int tid = threadIdx.x, lane = tid & 63, wv = tid >> 6;
    const int nodeBase = (blockIdx.x * 4 + wv) * 16;
    if (nodeBase >= N) return;

    float y2;
    float hb = bias_point(b2v, lane, &y2);
    float hbv[4];
#pragma unroll
    for (int t = 0; t < 4; ++t) hbv[t] = __shfl(hb, (lane & 15) + 16 * t);

    const int m = lane & 15, q = lane >> 4;
    const bool rowok = (nodeBase + m) < N;

    float af0[8], af1[8];
    const float* arow = agg + (size_t)(nodeBase + m) * 64 + q * 8;
    if (rowok) {
        *(float4*)(af0)     = *(const float4*)(arow);
        *(float4*)(af0 + 4) = *(const float4*)(arow + 4);
        *(float4*)(af1)     = *(const float4*)(arow + 32);
        *(float4*)(af1 + 4) = *(const float4*)(arow + 36);
    } else {
#pragma unroll
        for (int j = 0; j < 8; ++j) { af0[j] = 0.0f; af1[j] = 0.0f; }
    }
    float asq = 0.0f;
#pragma unroll
    for (int j = 0; j < 8; ++j) {
        asq = fmaf(af0[j], af0[j], asq);
        asq = fmaf(af1[j], af1[j], asq);
    }
    asq += __shfl_xor(asq, 16, 64);
    asq += __shfl_xor(asq, 32, 64);

    float n  = fmaxf(sqrtf(asq), EPSV);
    float th = tanhf(n);
    float g  = th / n;
    float nh = fmaxf(th, EPSV);
    if (nh > MAXN) { g *= MAXN / nh; nh = MAXN; }
    float lamg = (artanh_(nh) / nh) * g;
    float t0[8], t1[8], tsq = 0.0f;
#pragma unroll
    for (int j = 0; j < 8; ++j) {
        t0[j] = fmaxf(lamg * af0[j], 0.0f);
        t1[j] = fmaxf(lamg * af1[j], 0.0f);
        tsq = fmaf(t0[j], t0[j], tsq);
        tsq = fmaf(t1[j], t1[j], tsq);
    }
    tsq += __shfl_xor(tsq, 16, 64);
    tsq += __shfl_xor(tsq, 32, 64);
    float n2  = fmaxf(sqrtf(tsq), EPSV);
    float th2 = tanhf(n2);
    float g2  = th2 / n2;
    float nh2 = fmaxf(th2, EPSV);
    if (nh2 > MAXN) { g2 *= MAXN / nh2; nh2 = MAXN; }
    float xn_m = nh2;
    float x0[8], x1[8];
#pragma unroll
    for (int j = 0; j < 8; ++j) { x0[j] = g2 * t0[j]; x1[j] = g2 * t1[j]; }
    v8s a0 = cvt8(x0), a1 = cvt8(x1);

    v4f acc0 = {0,0,0,0}, acc1 = {0,0,0,0}, acc2 = {0,0,0,0}, acc3 = {0,0,0,0};
    {
        const bfu* wb;
        wb = w2b + (size_t)(m     ) * 64 + q * 8;
        acc0 = __builtin_amdgcn_mfma_f32_16x16x32_bf16(a0, *(const v8s*)(wb),      acc0, 0, 0, 0);
        acc0 = __builtin_amdgcn_mfma_f32_16x16x32_bf16(a1, *(const v8s*)(wb + 32), acc0, 0, 0, 0);
        wb = w2b + (size_t)(m + 16) * 64 + q * 8;
        acc1 = __builtin_amdgcn_mfma_f32_16x16x32_bf16(a0, *(const v8s*)(wb),      acc1, 0, 0, 0);
        acc1 = __builtin_amdgcn_mfma_f32_16x16x32_bf16(a1, *(const v8s*)(wb + 32), acc1, 0, 0, 0);
        wb = w2b + (size_t)(m + 32) * 64 + q * 8;
        acc2 = __builtin_amdgcn_mfma_f32_16x16x32_bf16(a0, *(const v8s*)(wb),      acc2, 0, 0, 0);
        acc2 = __builtin_amdgcn_mfma_f32_16x16x32_bf16(a1, *(const v8s*)(wb + 32), acc2, 0, 0, 0);
        wb = w2b + (size_t)(m + 48) * 64 + q * 8;
        acc3 = __builtin_amdgcn_mfma_f32_16x16x32_bf16(a0, *(const v8s*)(wb),      acc3, 0, 0, 0);
        acc3 = __builtin_amdgcn_mfma_f32_16x16x32_bf16(a1, *(const v8s*)(wb + 32), acc3, 0, 0, 0);
    }

    float P[4], Q[4];
#pragma unroll
    for (int r = 0; r < 4; ++r) {
        float s2 = acc0[r]*acc0[r] + acc1[r]*acc1[r] + acc2[r]*acc2[r] + acc3[r]*acc3[r];
        float sh = acc0[r]*hbv[0] + acc1[r]*hbv[1] + acc2[r]*hbv[2] + acc3[r]*hbv[3];
#pragma unroll
        for (int o = 1; o < 16; o <<= 1) {
            s2 += __shfl_xor(s2, o, 64);
            sh += __shfl_xor(sh, o, 64);
        }
        float xn = __shfl(xn_m, q * 4 + r);
        float mxn = fmaxf(sqrtf(s2), EPSV);
        float rt  = tanhf(mxn / xn * artanh_(xn));
        float k1, x2s, xy;
        if (s2 != 0.0f) {
            k1 = rt / mxn;
            float mvn = fmaxf(fabsf(rt), EPSV);
            if (mvn > MAXN) k1 *= MAXN / mvn;
            float cn = fminf(mvn, MAXN);
            x2s = cn * cn;
            xy  = k1 * sh;
        } else { k1 = 0.0f; x2s = 0.0f; xy = 0.0f; }
        float ca = 1.0f + 2.0f * xy + y2;
        float cb = 1.0f - x2s;
        float den = fmaxf(1.0f + 2.0f * xy + x2s * y2, EPSV);
        float hn2 = ca*ca*x2s + 2.0f*ca*cb*xy + cb*cb*y2;
        float hn = fmaxf(sqrtf(hn2) / den, EPSV);
        float hs = 1.0f;
        if (hn > MAXN) { hs = MAXN / hn; hn = MAXN; }
        float lam = artanh_(hn) / hn;
        P[r] = lam * hs * ca * k1 / den;
        Q[r] = lam * hs * cb / den;
    }
#pragma unroll
    for (int r = 0; r < 4; ++r) {
        int ri = nodeBase + q * 4 + r;
        if (ri < N) {
            bfu* orow = xtb2 + (size_t)ri * 64 + m;
            orow[ 0] = f2b(P[r] * acc0[r] + Q[r] * hbv[0]);
            orow[16] = f2b(P[r] * acc1[r] + Q[r] * hbv[1]);
            orow[32] = f2b(P[r] * acc2[r] + Q[r] * hbv[2]);
            orow[48] = f2b(P[r] * acc3[r] + Q[r] * hbv[3]);
        }
    }
}

// ===== fallback kernels (round-9 path, fp32 weights, used only if ws tiny) =====
__global__ __launch_bounds__(256) void hgA_layer1_fp32(
    const float* __restrict__ x, const float* __restrict__ W1,
    const float* __restrict__ b1v, float* __restrict__ xt, int N)
{
    const int tid = threadIdx.x, lane = tid & 63, wv = tid >> 6;
    const int nodeBase = (blockIdx.x * 4 + wv) * 16;
    if (nodeBase >= N) return;
    float y2;
    float hb = bias_point(b1v, lane, &y2);
    float hbv[4];
#pragma unroll
    for (int t = 0; t < 4; ++t) hbv[t] = __shfl(hb, (lane & 15) + 16 * t);
    const int m = lane & 15, q = lane >> 4;
    v4f acc0 = {0,0,0,0}, acc1 = {0,0,0,0}, acc2 = {0,0,0,0}, acc3 = {0,0,0,0};
    float usq = 0.0f;
    const float* arow = x + (size_t)(nodeBase + m) * 256 + q * 8;
#pragma unroll
    for (int s = 0; s < 8; ++s) {
        float af[8];
        *(float4*)(af)     = *(const float4*)(arow + s * 32);
        *(float4*)(af + 4) = *(const float4*)(arow + s * 32 + 4);
#pragma unroll
        for (int j = 0; j < 8; ++j) usq = fmaf(af[j], af[j], usq);
        v8s a = cvt8(af);
        const float* wbase = W1 + (size_t)m * 256 + s * 32 + q * 8;
        float wf[8];
        *(float4*)(wf) = *(const float4*)(wbase);  *(float4*)(wf+4) = *(const float4*)(wbase+4);
        acc0 = __builtin_amdgcn_mfma_f32_16x16x32_bf16(a, cvt8(wf), acc0, 0, 0, 0);
        *(float4*)(wf) = *(const float4*)(wbase+16*256); *(float4*)(wf+4) = *(const float4*)(wbase+16*256+4);
        acc1 = __builtin_amdgcn_mfma_f32_16x16x32_bf16(a, cvt8(wf), acc1, 0, 0, 0);
        *(float4*)(wf) = *(const float4*)(wbase+32*256); *(float4*)(wf+4) = *(const float4*)(wbase+32*256+4);
        acc2 = __builtin_amdgcn_mfma_f32_16x16x32_bf16(a, cvt8(wf), acc2, 0, 0, 0);
        *(float4*)(wf) = *(const float4*)(wbase+48*256); *(float4*)(wf+4) = *(const float4*)(wbase+48*256+4);
        acc3 = __builtin_amdgcn_mfma_f32_16x16x32_bf16(a, cvt8(wf), acc3, 0, 0, 0);
    }
    usq += __shfl_xor(usq, 16, 64);
    usq += __shfl_xor(usq, 32, 64);
    float P[4], Q[4];
#pragma unroll
    for (int r = 0; r < 4; ++r) {
        float s2 = acc0[r]*acc0[r] + acc1[r]*acc1[r] + acc2[r]*acc2[r] + acc3[r]*acc3[r];
        float sh = acc0[r]*hbv[0] + acc1[r]*hbv[1] + acc2[r]*hbv[2] + acc3[r]*hbv[3];
#pragma unroll
        for (int o = 1; o < 16; o <<= 1) { s2 += __shfl_xor(s2, o, 64); sh += __shfl_xor(sh, o, 64); }
        float usq_r = __shfl(usq, q * 4 + r);
        float n  = fmaxf(sqrtf(usq_r), EPSV);
        float th = tanhf(n);
        float gamma = th / n;
        float xn = fmaxf(th, EPSV);
        if (xn > MAXN) { gamma *= MAXN / xn; xn = MAXN; }
        float mxn = fmaxf(gamma * sqrtf(s2), EPSV);
        float rt  = tanhf(mxn / xn * artanh_(xn));
        float k1, x2s, xy;
        if (s2 != 0.0f) {
            k1 = (rt / mxn) * gamma;
            float mvn = fmaxf(fabsf(rt), EPSV);
            if (mvn > MAXN) k1 *= MAXN / mvn;
            float cn = fminf(mvn, MAXN);
            x2s = cn * cn; xy = k1 * sh;
        } else { k1 = 0.0f; x2s = 0.0f; xy = 0.0f; }
        float ca = 1.0f + 2.0f * xy + y2;
        float cb = 1.0f - x2s;
        float den = fmaxf(1.0f + 2.0f * xy + x2s * y2, EPSV);
        float hn2 = ca*ca*x2s + 2.0f*ca*cb*xy + cb*cb*y2;
        float hn = fmaxf(sqrtf(hn2) / den, EPSV);
        float hs = 1.0f;
        if (hn > MAXN) { hs = MAXN / hn; hn = MAXN; }
        float lam = artanh_(hn) / hn;
        P[r] = lam * hs * ca * k1 / den;
        Q[r] = lam * hs * cb / den;
    }
#pragma unroll
    for (int r = 0; r < 4; ++r) {
        float* orow = xt + (size_t)(nodeBase + q * 4 + r) * 64 + m;
        orow[ 0] = P[r] * acc0[r] + Q[r] * hbv[0];
        orow[16] = P[r] * acc1[r] + Q[r] * hbv[1];
        orow[32] = P[r] * acc2[r] + Q[r] * hbv[2];
        orow[48] = P[r] * acc3[r] + Q[r] * hbv[3];
    }
}

__global__ __launch_bounds__(256) void hgA_scatter(
    const int* __restrict__ src, const int* __restrict__ dst,
    const float* __restrict__ ew,
    const float* __restrict__ xt, float* __restrict__ agg, int E)
{
    const int lane = threadIdx.x & 63;
    const long long wid = ((long long)blockIdx.x * blockDim.x + threadIdx.x) >> 6;
    const long long nw = ((long long)gridDim.x * blockDim.x) >> 6;
    for (long long e = wid; e < E; e += nw) {
        int s = src[e], d = dst[e];
        atomicAdd(&agg[(size_t)d * 64 + lane], ew[e] * xt[(size_t)s * 64 + lane]);
    }
}

__global__ __launch_bounds__(256) void hgA_layer2_fb(
    const float* __restrict__ agg,
    const float* __restrict__ W2, const float* __restrict__ b2v,
    float* __restrict__ xt2, int N)
{
    const int lane = threadIdx.x & 63, wv = threadIdx.x >> 6;
    float y2;
    float hb = bias_point(b2v, lane, &y2);
    const int nw = gridDim.x * 4;
    for (int i = blockIdx.x * 4 + wv; i < N; i += nw) {
        float a = agg[(size_t)i * 64 + lane];
        float xn;
        float x2 = agg_transform(a, &xn);
        float acc = 0.0f;
        const float* Wrow = W2 + (size_t)lane * 64;
        for (int s = 0; s < 64; ++s)
            acc = fmaf(__shfl(x2, s), Wrow[s], acc);
        float o = mobius_tail(acc, xn, hb, y2);
        xt2[(size_t)i * 64 + lane] = o;
    }
}

__global__ __launch_bounds__(256) void hgA_final_fb(
    const float* __restrict__ agg, float* __restrict__ out, int N)
{
    const int lane = threadIdx.x & 63, wv = threadIdx.x >> 6;
    const int nw = gridDim.x * 4;
    for (int i = blockIdx.x * 4 + wv; i < N; i += nw) {
        float a = agg[(size_t)i * 64 + lane];
        float xn;
        float o = agg_transform(a, &xn);
        out[(size_t)i * 64 + lane] = o;
    }
}

extern "C" void kernel_launch(void* const* d_in, const int* in_sizes, int n_in,
                              void* d_out, int out_size, void* d_ws, size_t ws_size,
                              hipStream_t stream)
{
    const float* x  = (const float*)d_in[0];
    const int* src  = (const int*)d_in[1];
    const int* dst  = (const int*)d_in[2];
    const float* ew = (const float*)d_in[3];
    const float* W1 = (const float*)d_in[4];
    const float* b1 = (const float*)d_in[5];
    const float* W2 = (const float*)d_in[6];
    const float* b2 = (const float*)d_in[7];

    const int Dd = in_sizes[5];            // 64
    const int Ff = in_sizes[4] / Dd;       // 256
    const int N  = in_sizes[0] / Ff;       // 80000
    const int E  = in_sizes[1];            // 1280000
    const int NW1 = Dd * Ff;               // 16384
    const int NW2 = Dd * Dd;               // 4096

    float* out = (float*)d_out;
    float* agg = (float*)d_out;            // CSR path: fp32 agg lives in d_out

    const int NB = (N + 1023) / 1024;      // scan chunks

    // ws layouts:
    // tier A: [xtb][deg N][rowst N+1][cursor N][rank E][bsum NB][w1b][w2b][pad][csr]
    // tier B: [xtb][deg N][rowst N+1][cursor N][w1b][w2b][pad][csr]
    bfu*  xtb    = (bfu*)d_ws;
    size_t xtb_b = (size_t)N * Dd * 2;
    int*  deg    = (int*)((char*)d_ws + xtb_b);
    int*  rowst  = deg + N;
    int*  cursor = rowst + (N + 1);
    int*  rank   = cursor + N;
    int*  bsum   = rank + E;

    size_t wA_off = (xtb_b + ((size_t)(3 * N + 1) + (size_t)E + (size_t)NB) * 4 + 15) & ~(size_t)15;
    bfu* w1bA = (bfu*)((char*)d_ws + wA_off);
    bfu* w2bA = w1bA + NW1;
    size_t csr_offA = (wA_off + (size_t)(NW1 + NW2) * 2 + 7) & ~(size_t)7;
    const size_t needA = csr_offA + (size_t)E * 8;

    size_t wB_off = (xtb_b + (size_t)(3 * N + 1) * 4 + 15) & ~(size_t)15;
    bfu* w1bB = (bfu*)((char*)d_ws + wB_off);
    bfu* w2bB = w1bB + NW1;
    size_t csr_offB = (wB_off + (size_t)(NW1 + NW2) * 2 + 7) & ~(size_t)7;
    const size_t needB = csr_offB + (size_t)E * 8;

    const int blkT = (N + 63) / 64;        // wave per 16 nodes (layer kernels)
    const int blkG = (N + 3) / 4;          // wave per dst node (gathers)
    const int blkE4 = (E + 1023) / 1024;   // 4 edges/thread vblocks
    const int prepG = 128 + (NW1 + 255) / 256 + 1;
    const int n4 = (N * Dd) / 4;

    if (ws_size >= needA) {
        int2* csr = (int2*)((char*)d_ws + csr_offA);
        // layer1 vblock split: count 780 | fill rest
        int L1C = blkT < 780 ? blkT : 780;
        int L1F = blkT - L1C;
        hgA_prep        <<<prepG, 256, 0, stream>>>(deg, N, W1, W2, w1bA, w2bA, NW1, NW2);
        hgA_count_rank_l1<<<blkE4 + L1C, 256, 0, stream>>>(
            dst, deg, rank, E, blkE4, L1C, x, w1bA, b1, xtb, N);
        hgA_scan1       <<<NB, 256, 0, stream>>>(deg, rowst, bsum, N);
        hgA_scan2       <<<1,   64, 0, stream>>>(bsum, rowst + N, NB);
        hgA_scan3       <<<NB, 256, 0, stream>>>(rowst, bsum, N);
        hgA_fillr_layer1<<<blkE4 + L1F, 256, 0, stream>>>(
            src, dst, ew, rank, rowst, csr, E, blkE4, L1F, L1C,
            x, w1bA, b1, xtb, N);
        hgA_gather     <<<blkG, 256, 0, stream>>>(rowst, csr, xtb, agg, N);
        hgA_layer2_mfma<<<blkT, 256, 0, stream>>>(agg, w2bA, b2, xtb, N);
        hgA_gather_out <<<blkG, 256, 0, stream>>>(rowst, csr, xtb, out, N);
    } else if (ws_size >= needB) {
        // atomic-cursor fill path
        int2* csr = (int2*)((char*)d_ws + csr_offB);
        const int fillBlocks = 2048;
        hgA_prep       <<<prepG, 256, 0, stream>>>(deg, N, W1, W2, w1bB, w2bB, NW1, NW2);
        hgA_count      <<<2048, 256, 0, stream>>>(dst, deg, E);
        hgA_scan_l1    <<<1,   1024, 0, stream>>>(
            deg, rowst, cursor, N, x, w1bB, b1, xtb, 0);
        hgA_fill_layer1<<<fillBlocks + blkT, 256, 0, stream>>>(
            src, dst, ew, cursor, csr, E, fillBlocks, x, w1bB, b1, xtb, N);
        hgA_gather     <<<blkG, 256, 0, stream>>>(rowst, csr, xtb, agg, N);
        hgA_layer2_mfma<<<blkT, 256, 0, stream>>>(agg, w2bB, b2, xtb, N);
        hgA_gather_out <<<blkG, 256, 0, stream>>>(rowst, csr, xtb, out, N);
    } else {
        // round-9 fallback: xt fp32 in d_out, agg fp32 in ws
        float* xt_fb  = (float*)d_out;
        float* agg_fb = (float*)d_ws;
        hgA_layer1_fp32<<<blkT, 256, 0, stream>>>(x, W1, b1, xt_fb, N);
        hgA_zero     <<<1024,  256, 0, stream>>>(agg_fb, n4);
        hgA_scatter  <<<16384, 256, 0, stream>>>(src, dst, ew, xt_fb, agg_fb, E);
        hgA_layer2_fb<<<2048,  256, 0, stream>>>(agg_fb, W2, b2, xt_fb, N);
        hgA_zero     <<<1024,  256, 0, stream>>>(agg_fb, n4);
        hgA_scatter  <<<16384, 256, 0, stream>>>(src, dst, ew, xt_fb, agg_fb, E);
        hgA_final_fb <<<2048,  256, 0, stream>>>(agg_fb, out, N);
    }
}

// Round 6
// 333.388 us; speedup vs baseline: 1.4275x; 1.0042x over previous
//
#include <hip/hip_runtime.h>

// HGCN forward (2-layer hyperbolic GCN), Poincare ball c=1. fp32 in/out
// (values bf16-grid). Round 16 = round 15 (335us) with:
//  (a) x PRE-CONVERTED to bf16 (xb, 41MB) + per-node usq precomputed in fp32
//      with the IDENTICAL fmaf chain + xor16/32 fold layer1 used -- layer1b
//      becomes nearly pure MFMA+loads (no cvt8, no usq chain), BIT-IDENTICAL
//      outputs. Conversion fused into the count kernel (atomic-latency count
//      interleaved with BW-bound xcvt, 1250:1250 parity).
//  (b) all 1250 l1 vblocks now bf16-path: 192 hosted in scan1 (its 79-block
//      grid leaves GPU idle), 1058 in fillr.
//  (c) tier ladder: A1 (xb path) -> A2 (exact round-15 path) -> B -> fallback,
//      gated by ws_size; cannot regress if ws too small for xb.

#define EPSV 1e-15f
#define MAXN 0.996f   // (1 - 4e-3) / sqrt(c), c = 1

typedef unsigned short bfu;
typedef __attribute__((ext_vector_type(8))) short v8s;   // 8 bf16 (4 VGPRs)
typedef __attribute__((ext_vector_type(4))) float v4f;   // MFMA acc

__device__ __forceinline__ bfu f2b(float f) {   // fp32 -> bf16, RNE
    unsigned int u;
    __builtin_memcpy(&u, &f, sizeof(u));
    u += 0x7fffu + ((u >> 16) & 1u);
    return (bfu)(u >> 16);
}

__device__ __forceinline__ float b2f(bfu s) {
    unsigned int u = ((unsigned int)s) << 16;
    float f;
    __builtin_memcpy(&f, &u, sizeof(f));
    return f;
}

// low/high bf16 of a packed u32 -> fp32
__device__ __forceinline__ float uplo(unsigned int u) {
    unsigned int v = u << 16; float f;
    __builtin_memcpy(&f, &v, sizeof(f)); return f;
}
__device__ __forceinline__ float uphi(unsigned int u) {
    unsigned int v = u & 0xffff0000u; float f;
    __builtin_memcpy(&f, &v, sizeof(f)); return f;
}

__device__ __forceinline__ v8s cvt8(const float* f) {
    v8s r;
#pragma unroll
    for (int j = 0; j < 8; ++j) r[j] = (short)f2b(f[j]);
    return r;
}

__device__ __forceinline__ float i2f(int i) {
    float f; __builtin_memcpy(&f, &i, sizeof(f)); return f;
}
__device__ __forceinline__ int f2i(float f) {
    int i; __builtin_memcpy(&i, &f, sizeof(i)); return i;
}

__device__ __forceinline__ float wredsum(float v) {
#pragma unroll
    for (int o = 32; o > 0; o >>= 1) v += __shfl_xor(v, o, 64);
    return v;
}

__device__ __forceinline__ float artanh_(float x) {
    x = fminf(fmaxf(x, -1.0f + 1e-7f), 1.0f - 1e-7f);
    return 0.5f * logf((1.0f + x) / (1.0f - x));
}

__device__ __forceinline__ float mobius_tail(float mx, float xn, float hb, float y2) {
    float mxn2 = wredsum(mx * mx);
    unsigned long long nz = __ballot(mx != 0.0f);
    float mxn = fmaxf(sqrtf(mxn2), EPSV);
    float rt = tanhf(mxn / xn * artanh_(xn));
    float mv, x2s;
    if (nz != 0ull) {
        mv = (rt / mxn) * mx;
        float mvn = fmaxf(fabsf(rt), EPSV);
        if (mvn > MAXN) mv *= MAXN / mvn;
        float cn = fminf(mvn, MAXN);
        x2s = cn * cn;
    } else { mv = 0.0f; x2s = 0.0f; }
    float xy = wredsum(mv * hb);
    float ca = 1.0f + 2.0f * xy + y2;
    float cb = 1.0f - x2s;
    float den = fmaxf(1.0f + 2.0f * xy + x2s * y2, EPSV);
    float hj = (ca * mv + cb * hb) / den;
    float hn = fmaxf(sqrtf(wredsum(hj * hj)), EPSV);
    if (hn > MAXN) { hj *= MAXN / hn; hn = MAXN; }
    return (artanh_(hn) / hn) * hj;
}

__device__ __forceinline__ float agg_transform(float a, float* xn_out) {
    float n = fmaxf(sqrtf(wredsum(a * a)), EPSV);
    float th = tanhf(n);
    float g = th / n;
    float nh = fmaxf(th, EPSV);
    if (nh > MAXN) { g *= MAXN / nh; nh = MAXN; }
    float h = g * a;
    float t = fmaxf((artanh_(nh) / nh) * h, 0.0f);
    float n2 = fmaxf(sqrtf(wredsum(t * t)), EPSV);
    float th2 = tanhf(n2);
    float g2 = th2 / n2;
    float nh2 = fmaxf(th2, EPSV);
    if (nh2 > MAXN) { g2 *= MAXN / nh2; nh2 = MAXN; }
    *xn_out = nh2;
    return g2 * t;
}

__device__ __forceinline__ float bias_point(const float* bv, int lane, float* y2) {
    float b = bv[lane];
    float bn = fmaxf(sqrtf(wredsum(b * b)), EPSV);
    float gs = tanhf(bn) / bn;
    float hbn = fmaxf(tanhf(bn), EPSV);
    if (hbn > MAXN) gs *= MAXN / hbn;
    float hb = gs * b;
    *y2 = wredsum(hb * hb);
    return hb;
}

__global__ __launch_bounds__(256) void hgA_zero(float* __restrict__ p, int n4) {
    const float4 z = make_float4(0.f, 0.f, 0.f, 0.f);
    int stride = gridDim.x * blockDim.x;
    for (int i = blockIdx.x * blockDim.x + threadIdx.x; i < n4; i += stride)
        ((float4*)p)[i] = z;
}

// ===== prep: zero deg (blocks 0..127) + convert W1/W2 to bf16 =====
__global__ __launch_bounds__(256) void hgA_prep(
    int* __restrict__ deg, int N,
    const float* __restrict__ W1, const float* __restrict__ W2,
    bfu* __restrict__ w1b, bfu* __restrict__ w2b, int NW1, int NW2)
{
    const int b = blockIdx.x, tid = threadIdx.x;
    if (b < 128) {
        for (int i = b * 256 + tid; i < N; i += 128 * 256) deg[i] = 0;
    } else if (b < 128 + (NW1 + 255) / 256) {
        int i = (b - 128) * 256 + tid;
        if (i < NW1) w1b[i] = f2b(W1[i]);
    } else {
        for (int i = tid; i < NW2; i += 256) w2b[i] = f2b(W2[i]);
    }
}

// shared tail of layer1: from accs + usq to xtb writes (bit-identical both paths)
__device__ __forceinline__ void layer1_tail(
    int nodeBase, int m, int q, float usq, const float* hbv, float y2,
    v4f acc0, v4f acc1, v4f acc2, v4f acc3, bfu* __restrict__ xtb)
{
    float P[4], Q[4];
#pragma unroll
    for (int r = 0; r < 4; ++r) {
        float s2 = acc0[r]*acc0[r] + acc1[r]*acc1[r] + acc2[r]*acc2[r] + acc3[r]*acc3[r];
        float sh = acc0[r]*hbv[0] + acc1[r]*hbv[1] + acc2[r]*hbv[2] + acc3[r]*hbv[3];
#pragma unroll
        for (int o = 1; o < 16; o <<= 1) {
            s2 += __shfl_xor(s2, o, 64);
            sh += __shfl_xor(sh, o, 64);
        }
        float usq_r = __shfl(usq, q * 4 + r);
        float n  = fmaxf(sqrtf(usq_r), EPSV);
        float th = tanhf(n);
        float gamma = th / n;
        float xn = fmaxf(th, EPSV);
        if (xn > MAXN) { gamma *= MAXN / xn; xn = MAXN; }
        float mxn = fmaxf(gamma * sqrtf(s2), EPSV);
        float rt  = tanhf(mxn / xn * artanh_(xn));
        float k1, x2s, xy;
        if (s2 != 0.0f) {
            k1 = (rt / mxn) * gamma;
            float mvn = fmaxf(fabsf(rt), EPSV);
            if (mvn > MAXN) k1 *= MAXN / mvn;
            float cn = fminf(mvn, MAXN);
            x2s = cn * cn;
            xy  = k1 * sh;
        } else { k1 = 0.0f; x2s = 0.0f; xy = 0.0f; }
        float ca = 1.0f + 2.0f * xy + y2;
        float cb = 1.0f - x2s;
        float den = fmaxf(1.0f + 2.0f * xy + x2s * y2, EPSV);
        float hn2 = ca*ca*x2s + 2.0f*ca*cb*xy + cb*cb*y2;
        float hn = fmaxf(sqrtf(hn2) / den, EPSV);
        float hs = 1.0f;
        if (hn > MAXN) { hs = MAXN / hn; hn = MAXN; }
        float lam = artanh_(hn) / hn;
        P[r] = lam * hs * ca * k1 / den;
        Q[r] = lam * hs * cb / den;
    }
#pragma unroll
    for (int r = 0; r < 4; ++r) {
        bfu* orow = xtb + (size_t)(nodeBase + q * 4 + r) * 64 + m;
        orow[ 0] = f2b(P[r] * acc0[r] + Q[r] * hbv[0]);
        orow[16] = f2b(P[r] * acc1[r] + Q[r] * hbv[1]);
        orow[32] = f2b(P[r] * acc2[r] + Q[r] * hbv[2]);
        orow[48] = f2b(P[r] * acc3[r] + Q[r] * hbv[3]);
    }
}

// ===== layer1 body, fp32-x path (tiers A2/B) =====
__device__ __forceinline__ void layer1_body(
    int bid, int tid, const float* __restrict__ x, const bfu* __restrict__ w1b,
    const float* __restrict__ b1v, bfu* __restrict__ xtb, int N)
{
    const int lane = tid & 63, wv = tid >> 6;
    const int nodeBase = (bid * 4 + wv) * 16;
    if (nodeBase >= N) return;

    float y2;
    float hb = bias_point(b1v, lane, &y2);
    float hbv[4];
#pragma unroll
    for (int t = 0; t < 4; ++t) hbv[t] = __shfl(hb, (lane & 15) + 16 * t);

    const int m = lane & 15, q = lane >> 4;
    v4f acc0 = {0,0,0,0}, acc1 = {0,0,0,0}, acc2 = {0,0,0,0}, acc3 = {0,0,0,0};
    float usq = 0.0f;

    const float* arow = x + (size_t)(nodeBase + m) * 256 + q * 8;
    const bfu* wrow = w1b + (size_t)m * 256 + q * 8;
#pragma unroll
    for (int s = 0; s < 8; ++s) {
        float af[8];
        *(float4*)(af)     = *(const float4*)(arow + s * 32);
        *(float4*)(af + 4) = *(const float4*)(arow + s * 32 + 4);
#pragma unroll
        for (int j = 0; j < 8; ++j) usq = fmaf(af[j], af[j], usq);
        v8s a = cvt8(af);
        const bfu* wb = wrow + s * 32;
        acc0 = __builtin_amdgcn_mfma_f32_16x16x32_bf16(a, *(const v8s*)(wb), acc0, 0, 0, 0);
        acc1 = __builtin_amdgcn_mfma_f32_16x16x32_bf16(a, *(const v8s*)(wb + 16 * 256), acc1, 0, 0, 0);
        acc2 = __builtin_amdgcn_mfma_f32_16x16x32_bf16(a, *(const v8s*)(wb + 32 * 256), acc2, 0, 0, 0);
        acc3 = __builtin_amdgcn_mfma_f32_16x16x32_bf16(a, *(const v8s*)(wb + 48 * 256), acc3, 0, 0, 0);
    }
    usq += __shfl_xor(usq, 16, 64);
    usq += __shfl_xor(usq, 32, 64);
    layer1_tail(nodeBase, m, q, usq, hbv, y2, acc0, acc1, acc2, acc3, xtb);
}

// ===== layer1 body, bf16-x path (tier A1): pure loads+MFMA =====
__device__ __forceinline__ void layer1b_body(
    int bid, int tid, const bfu* __restrict__ xb, const float* __restrict__ usqt,
    const bfu* __restrict__ w1b, const float* __restrict__ b1v,
    bfu* __restrict__ xtb, int N)
{
    const int lane = tid & 63, wv = tid >> 6;
    const int nodeBase = (bid * 4 + wv) * 16;
    if (nodeBase >= N) return;

    float y2;
    float hb = bias_point(b1v, lane, &y2);
    float hbv[4];
#pragma unroll
    for (int t = 0; t < 4; ++t) hbv[t] = __shfl(hb, (lane & 15) + 16 * t);

    const int m = lane & 15, q = lane >> 4;
    v4f acc0 = {0,0,0,0}, acc1 = {0,0,0,0}, acc2 = {0,0,0,0}, acc3 = {0,0,0,0};
    const float usq = usqt[nodeBase + m];   // precomputed, bit-identical chain

    const bfu* arow = xb + (size_t)(nodeBase + m) * 256 + q * 8;
    const bfu* wrow = w1b + (size_t)m * 256 + q * 8;
#pragma unroll
    for (int s = 0; s < 8; ++s) {
        v8s a = *(const v8s*)(arow + s * 32);
        const bfu* wb = wrow + s * 32;
        acc0 = __builtin_amdgcn_mfma_f32_16x16x32_bf16(a, *(const v8s*)(wb), acc0, 0, 0, 0);
        acc1 = __builtin_amdgcn_mfma_f32_16x16x32_bf16(a, *(const v8s*)(wb + 16 * 256), acc1, 0, 0, 0);
        acc2 = __builtin_amdgcn_mfma_f32_16x16x32_bf16(a, *(const v8s*)(wb + 32 * 256), acc2, 0, 0, 0);
        acc3 = __builtin_amdgcn_mfma_f32_16x16x32_bf16(a, *(const v8s*)(wb + 48 * 256), acc3, 0, 0, 0);
    }
    layer1_tail(nodeBase, m, q, usq, hbv, y2, acc0, acc1, acc2, acc3, xtb);
}

// ===== CSR build =====
__global__ __launch_bounds__(256) void hgA_zero_i32(int* __restrict__ p, int n) {
    int stride = gridDim.x * blockDim.x;
    for (int i = blockIdx.x * blockDim.x + threadIdx.x; i < n; i += stride) p[i] = 0;
}

// tier B count (no rank)
__global__ __launch_bounds__(256) void hgA_count(
    const int* __restrict__ dst, int* __restrict__ deg, int E) {
    int stride = gridDim.x * blockDim.x;
    for (int e = blockIdx.x * blockDim.x + threadIdx.x; e < E; e += stride)
        atomicAdd(&deg[dst[e]], 1);
}

// tier A2 count_rank + fp32 layer1 share (parity-interleaved)
__global__ __launch_bounds__(256) void hgA_count_rank_l1(
    const int* __restrict__ dst, int* __restrict__ deg, int* __restrict__ rank,
    int E, int nf, int nl,
    const float* __restrict__ x, const bfu* __restrict__ w1b,
    const float* __restrict__ b1v, bfu* __restrict__ xtb, int N)
{
    const int b = blockIdx.x;
    const int mn = nf < nl ? nf : nl;
    bool isC; int idx;
    if (b < 2 * mn) { isC = !(b & 1); idx = b >> 1; }
    else            { isC = (nf > nl); idx = mn + (b - 2 * mn); }
    if (isC) {
        int e0 = (idx * 256 + threadIdx.x) * 4;
        if (e0 + 4 <= E) {
            int4 d4 = *(const int4*)(dst + e0);
            int4 r4;
            r4.x = atomicAdd(&deg[d4.x], 1);
            r4.y = atomicAdd(&deg[d4.y], 1);
            r4.z = atomicAdd(&deg[d4.z], 1);
            r4.w = atomicAdd(&deg[d4.w], 1);
            *(int4*)(rank + e0) = r4;
        } else if (e0 < E) {
            for (int e = e0; e < E; ++e) rank[e] = atomicAdd(&deg[dst[e]], 1);
        }
    } else {
        layer1_body(idx, threadIdx.x, x, w1b, b1v, xtb, N);
    }
}

// tier A1: count_rank || x->bf16 convert + usq precompute (parity-interleaved)
__global__ __launch_bounds__(256) void hgA_count_xcvt(
    const int* __restrict__ dst, int* __restrict__ deg, int* __restrict__ rank,
    int E, int nf,
    const float* __restrict__ x, bfu* __restrict__ xb, float* __restrict__ usqt,
    int nc, int N)
{
    const int b = blockIdx.x;
    const int mn = nf < nc ? nf : nc;
    bool isC; int idx;
    if (b < 2 * mn) { isC = !(b & 1); idx = b >> 1; }
    else            { isC = (nf > nc); idx = mn + (b - 2 * mn); }
    if (isC) {
        int e0 = (idx * 256 + threadIdx.x) * 4;
        if (e0 + 4 <= E) {
            int4 d4 = *(const int4*)(dst + e0);
            int4 r4;
            r4.x = atomicAdd(&deg[d4.x], 1);
            r4.y = atomicAdd(&deg[d4.y], 1);
            r4.z = atomicAdd(&deg[d4.z], 1);
            r4.w = atomicAdd(&deg[d4.w], 1);
            *(int4*)(rank + e0) = r4;
        } else if (e0 < E) {
            for (int e = e0; e < E; ++e) rank[e] = atomicAdd(&deg[dst[e]], 1);
        }
    } else {
        // xcvt role: mirror layer1's exact load pattern + usq chain
        const int lane = threadIdx.x & 63, wv = threadIdx.x >> 6;
        const int nodeBase = (idx * 4 + wv) * 16;
        if (nodeBase >= N) return;
        const int m = lane & 15, q = lane >> 4;
        const float* arow = x + (size_t)(nodeBase + m) * 256 + q * 8;
        bfu* orow = xb + (size_t)(nodeBase + m) * 256 + q * 8;
        float usq = 0.0f;
#pragma unroll
        for (int s = 0; s < 8; ++s) {
            float af[8];
            *(float4*)(af)     = *(const float4*)(arow + s * 32);
            *(float4*)(af + 4) = *(const float4*)(arow + s * 32 + 4);
#pragma unroll
            for (int j = 0; j < 8; ++j) usq = fmaf(af[j], af[j], usq);
            *(v8s*)(orow + s * 32) = cvt8(af);
        }
        usq += __shfl_xor(usq, 16, 64);
        usq += __shfl_xor(usq, 32, 64);
        if (lane < 16 && nodeBase + lane < N) usqt[nodeBase + lane] = usq;
    }
}

// ===== parallel scan, phase 1 (+optional bf16 l1 tail blocks) =====
__global__ __launch_bounds__(256) void hgA_scan1(
    const int* __restrict__ deg, int* __restrict__ rowst,
    int* __restrict__ bsum, int N, int NBr,
    const bfu* __restrict__ xb, const float* __restrict__ usqt,
    const bfu* __restrict__ w1b, const float* __restrict__ b1v,
    bfu* __restrict__ xtb, int NL)
{
    if (blockIdx.x >= NBr) {
        int vb = blockIdx.x - NBr;
        if (vb < NL) layer1b_body(vb, threadIdx.x, xb, usqt, w1b, b1v, xtb, N);
        return;
    }
    __shared__ int wsum[4];
    const int tid = threadIdx.x, lane = tid & 63, wv = tid >> 6;
    const int base = blockIdx.x * 1024 + tid * 4;
    int v0 = 0, v1 = 0, v2 = 0, v3 = 0;
    if (base + 4 <= N) {
        int4 d4 = *(const int4*)(deg + base);
        v0 = d4.x; v1 = d4.y; v2 = d4.z; v3 = d4.w;
    } else {
        if (base + 0 < N) v0 = deg[base + 0];
        if (base + 1 < N) v1 = deg[base + 1];
        if (base + 2 < N) v2 = deg[base + 2];
        if (base + 3 < N) v3 = deg[base + 3];
    }
    const int tsum = v0 + v1 + v2 + v3;
    int incl = tsum;
#pragma unroll
    for (int o = 1; o < 64; o <<= 1) {
        int nb = __shfl_up(incl, o, 64);
        if (lane >= o) incl += nb;
    }
    if (lane == 63) wsum[wv] = incl;
    __syncthreads();
    int add = 0;
#pragma unroll
    for (int w = 0; w < 4; ++w) { int s = wsum[w]; if (w < wv) add += s; }
    const int excl = add + incl - tsum;
    const int e0 = excl, e1 = e0 + v0, e2 = e1 + v1, e3 = e2 + v2;
    if (base + 4 <= N) {
        *(int4*)(rowst + base) = make_int4(e0, e1, e2, e3);
    } else {
        if (base + 0 < N) rowst[base + 0] = e0;
        if (base + 1 < N) rowst[base + 1] = e1;
        if (base + 2 < N) rowst[base + 2] = e2;
        if (base + 3 < N) rowst[base + 3] = e3;
    }
    if (tid == 255) bsum[blockIdx.x] = add + incl;
}

// phase 2: single wave, exclusive-scan the NB block sums in place; total -> *tot
__global__ __launch_bounds__(64) void hgA_scan2(
    int* __restrict__ bsum, int* __restrict__ tot, int NB)
{
    const int lane = threadIdx.x;
    int run = 0;
    for (int b = 0; b < NB; b += 64) {
        int i = b + lane;
        int v = (i < NB) ? bsum[i] : 0;
        int incl = v;
#pragma unroll
        for (int o = 1; o < 64; o <<= 1) {
            int nb = __shfl_up(incl, o, 64);
            if (lane >= o) incl += nb;
        }
        if (i < NB) bsum[i] = run + incl - v;
        run += __shfl(incl, 63);
    }
    if (lane == 0) *tot = run;
}

// phase 3: add per-chunk offsets
__global__ __launch_bounds__(256) void hgA_scan3(
    int* __restrict__ rowst, const int* __restrict__ bsum, int N)
{
    const int base = blockIdx.x * 1024 + threadIdx.x * 4;
    const int off = bsum[blockIdx.x];
    if (base + 4 <= N) {
        int4 r = *(int4*)(rowst + base);
        r.x += off; r.y += off; r.z += off; r.w += off;
        *(int4*)(rowst + base) = r;
    } else {
        for (int i = base; i < N; ++i) rowst[i] += off;
    }
}

// tier B: serial scan (block 0) -- retained as safety net
__global__ __launch_bounds__(1024) void hgA_scan_l1(
    const int* __restrict__ deg, int* __restrict__ row_start,
    int* __restrict__ cursor, int N,
    const float* __restrict__ x, const bfu* __restrict__ w1b,
    const float* __restrict__ b1v, bfu* __restrict__ xtb, int NL)
{
    if (blockIdx.x != 0) {
        int vb = (blockIdx.x - 1) * 4 + (threadIdx.x >> 8);
        if (vb < NL) layer1_body(vb, threadIdx.x & 255, x, w1b, b1v, xtb, N);
        return;
    }
    __shared__ int wsum[16];
    __shared__ int srun;
    const int tid = threadIdx.x, lane = tid & 63, wv = tid >> 6;
    if (tid == 0) srun = 0;
    __syncthreads();
    for (int base = 0; base < N; base += 1024) {
        int i = base + tid;
        int v = (i < N) ? deg[i] : 0;
        int incl = v;
#pragma unroll
        for (int o = 1; o < 64; o <<= 1) {
            int nbr = __shfl_up(incl, o, 64);
            if (lane >= o) incl += nbr;
        }
        if (lane == 63) wsum[wv] = incl;
        __syncthreads();
        int add = 0;
#pragma unroll
        for (int w = 0; w < 16; ++w) { int s = wsum[w]; if (w < wv) add += s; }
        int excl = srun + add + incl - v;
        if (i < N) { row_start[i] = excl; cursor[i] = excl; }
        __syncthreads();
        if (tid == 1023) srun += add + incl;
        __syncthreads();
    }
    if (tid == 0) row_start[N] = srun;
}

// ===== tier B fused: fill (atomic cursor) || fp32 layer1 =====
__global__ __launch_bounds__(256) void hgA_fill_layer1(
    const int* __restrict__ src, const int* __restrict__ dst,
    const float* __restrict__ ew, int* __restrict__ cursor,
    int2* __restrict__ csr, int E, int fillBlocks,
    const float* __restrict__ x, const bfu* __restrict__ w1b,
    const float* __restrict__ b1v, bfu* __restrict__ xtb, int N)
{
    const int b = blockIdx.x;
    if (b < fillBlocks) {
        int stride = fillBlocks * blockDim.x;
        for (int e = b * blockDim.x + threadIdx.x; e < E; e += stride) {
            int d = dst[e];
            int slot = atomicAdd(&cursor[d], 1);
            csr[slot] = make_int2(src[e], f2i(ew[e]));
        }
    } else {
        layer1_body(b - fillBlocks, threadIdx.x, x, w1b, b1v, xtb, N);
    }
}

// ===== tier A2 fused: atomic-free fill || fp32 layer1, interleaved =====
__global__ __launch_bounds__(256) void hgA_fillr_layer1(
    const int* __restrict__ src, const int* __restrict__ dst,
    const float* __restrict__ ew, const int* __restrict__ rank,
    const int* __restrict__ row_start, int2* __restrict__ csr,
    int E, int nf, int nl, int l1off,
    const float* __restrict__ x, const bfu* __restrict__ w1b,
    const float* __restrict__ b1v, bfu* __restrict__ xtb, int N)
{
    const int b = blockIdx.x;
    const int mn = nf < nl ? nf : nl;
    bool isFill; int idx;
    if (b < 2 * mn) { isFill = !(b & 1); idx = b >> 1; }
    else            { isFill = (nf > nl); idx = mn + (b - 2 * mn); }
    if (isFill) {
        int e0 = (idx * 256 + threadIdx.x) * 4;
        if (e0 + 4 <= E) {
            int4  d4 = *(const int4*)(dst + e0);
            int4  s4 = *(const int4*)(src + e0);
            int4  r4 = *(const int4*)(rank + e0);
            float4 w4 = *(const float4*)(ew + e0);
            csr[row_start[d4.x] + r4.x] = make_int2(s4.x, f2i(w4.x));
            csr[row_start[d4.y] + r4.y] = make_int2(s4.y, f2i(w4.y));
            csr[row_start[d4.z] + r4.z] = make_int2(s4.z, f2i(w4.z));
            csr[row_start[d4.w] + r4.w] = make_int2(s4.w, f2i(w4.w));
        } else if (e0 < E) {
            for (int e = e0; e < E; ++e)
                csr[row_start[dst[e]] + rank[e]] = make_int2(src[e], f2i(ew[e]));
        }
    } else {
        layer1_body(l1off + idx, threadIdx.x, x, w1b, b1v, xtb, N);
    }
}

// ===== tier A1 fused: atomic-free fill || bf16 layer1, interleaved =====
__global__ __launch_bounds__(256) void hgA_fillr_l1b(
    const int* __restrict__ src, const int* __restrict__ dst,
    const float* __restrict__ ew, const int* __restrict__ rank,
    const int* __restrict__ row_start, int2* __restrict__ csr,
    int E, int nf, int nl, int l1off,
    const bfu* __restrict__ xb, const float* __restrict__ usqt,
    const bfu* __restrict__ w1b, const float* __restrict__ b1v,
    bfu* __restrict__ xtb, int N)
{
    const int b = blockIdx.x;
    const int mn = nf < nl ? nf : nl;
    bool isFill; int idx;
    if (b < 2 * mn) { isFill = !(b & 1); idx = b >> 1; }
    else            { isFill = (nf > nl); idx = mn + (b - 2 * mn); }
    if (isFill) {
        int e0 = (idx * 256 + threadIdx.x) * 4;
        if (e0 + 4 <= E) {
            int4  d4 = *(const int4*)(dst + e0);
            int4  s4 = *(const int4*)(src + e0);
            int4  r4 = *(const int4*)(rank + e0);
            float4 w4 = *(const float4*)(ew + e0);
            csr[row_start[d4.x] + r4.x] = make_int2(s4.x, f2i(w4.x));
            csr[row_start[d4.y] + r4.y] = make_int2(s4.y, f2i(w4.y));
            csr[row_start[d4.z] + r4.z] = make_int2(s4.z, f2i(w4.z));
            csr[row_start[d4.w] + r4.w] = make_int2(s4.w, f2i(w4.w));
        } else if (e0 < E) {
            for (int e = e0; e < E; ++e)
                csr[row_start[dst[e]] + rank[e]] = make_int2(src[e], f2i(ew[e]));
        }
    } else {
        layer1b_body(l1off + idx, threadIdx.x, xb, usqt, w1b, b1v, xtb, N);
    }
}

// ===== quad-row gather core: 16-lane groups, uint2/lane -> 4 rows per load =====
#define GACC_QUAD(T64, CSR, N0, N1, LANE, T0, T1, T2, T3)                      \
    {                                                                          \
        const int sl_ = (LANE) & 15, p_ = (LANE) >> 4;                         \
        float a0x=0.f,a0y=0.f,a0z=0.f,a0w=0.f;                                 \
        float a1x=0.f,a1y=0.f,a1z=0.f,a1w=0.f;                                 \
        float a2x=0.f,a2y=0.f,a2z=0.f,a2w=0.f;                                 \
        float a3x=0.f,a3y=0.f,a3z=0.f,a3w=0.f;                                 \
        for (int base = (N0); base < (N1); base += 64) {                       \
            int cnt = (N1) - base; if (cnt > 64) cnt = 64;                     \
            int sL = 0; float wL = 0.0f;                                       \
            if ((LANE) < cnt) { int2 rec = (CSR)[base + (LANE)];               \
                                sL = rec.x; wL = i2f(rec.y); }                 \
            int j = 0;                                                         \
            for (; j + 16 <= cnt; j += 16) {                                   \
                int   s0 = __shfl(sL, j      + p_, 64);                        \
                int   s1 = __shfl(sL, j +  4 + p_, 64);                        \
                int   s2 = __shfl(sL, j +  8 + p_, 64);                        \
                int   s3 = __shfl(sL, j + 12 + p_, 64);                        \
                float w0 = __shfl(wL, j      + p_, 64);                        \
                float w1 = __shfl(wL, j +  4 + p_, 64);                        \
                float w2 = __shfl(wL, j +  8 + p_, 64);                        \
                float w3 = __shfl(wL, j + 12 + p_, 64);                        \
                uint2 u0 = (T64)[(size_t)s0 * 16 + sl_];                       \
                uint2 u1 = (T64)[(size_t)s1 * 16 + sl_];                       \
                uint2 u2 = (T64)[(size_t)s2 * 16 + sl_];                       \
                uint2 u3 = (T64)[(size_t)s3 * 16 + sl_];                       \
                a0x = fmaf(w0, uplo(u0.x), a0x); a0y = fmaf(w0, uphi(u0.x), a0y); \
                a0z = fmaf(w0, uplo(u0.y), a0z); a0w = fmaf(w0, uphi(u0.y), a0w); \
                a1x = fmaf(w1, uplo(u1.x), a1x); a1y = fmaf(w1, uphi(u1.x), a1y); \
                a1z = fmaf(w1, uplo(u1.y), a1z); a1w = fmaf(w1, uphi(u1.y), a1w); \
                a2x = fmaf(w2, uplo(u2.x), a2x); a2y = fmaf(w2, uphi(u2.x), a2y); \
                a2z = fmaf(w2, uplo(u2.y), a2z); a2w = fmaf(w2, uphi(u2.y), a2w); \
                a3x = fmaf(w3, uplo(u3.x), a3x); a3y = fmaf(w3, uphi(u3.x), a3y); \
                a3z = fmaf(w3, uplo(u3.y), a3z); a3w = fmaf(w3, uphi(u3.y), a3w); \
            }                                                                  \
            for (; j + 8 <= cnt; j += 8) {                                     \
                int   s0 = __shfl(sL, j     + p_, 64);                         \
                int   s1 = __shfl(sL, j + 4 + p_, 64);                         \
                float w0 = __shfl(wL, j     + p_, 64);                         \
                float w1 = __shfl(wL, j + 4 + p_, 64);                         \
                uint2 u0 = (T64)[(size_t)s0 * 16 + sl_];                       \
                uint2 u1 = (T64)[(size_t)s1 * 16 + sl_];                       \
                a0x = fmaf(w0, uplo(u0.x), a0x); a0y = fmaf(w0, uphi(u0.x), a0y); \
                a0z = fmaf(w0, uplo(u0.y), a0z); a0w = fmaf(w0, uphi(u0.y), a0w); \
                a1x = fmaf(w1, uplo(u1.x), a1x); a1y = fmaf(w1, uphi(u1.x), a1y); \
                a1z = fmaf(w1, uplo(u1.y), a1z); a1w = fmaf(w1, uphi(u1.y), a1w); \
            }                                                                  \
            for (; j < cnt; j += 4) {   /* 4 edges/step, w=0 pads safe */      \
                int   s = __shfl(sL, j + p_, 64);                              \
                float w = __shfl(wL, j + p_, 64);                              \
                uint2 u = (T64)[(size_t)s * 16 + sl_];                         \
                a0x = fmaf(w, uplo(u.x), a0x); a0y = fmaf(w, uphi(u.x), a0y);  \
                a0z = fmaf(w, uplo(u.y), a0z); a0w = fmaf(w, uphi(u.y), a0w);  \
            }                                                                  \
        }                                                                      \
        T0 = (a0x + a1x) + (a2x + a3x);                                        \
        T1 = (a0y + a1y) + (a2y + a3y);                                        \
        T2 = (a0z + a1z) + (a2z + a3z);                                        \
        T3 = (a0w + a1w) + (a2w + a3w);                                        \
        T0 += __shfl_xor(T0, 16, 64); T0 += __shfl_xor(T0, 32, 64);            \
        T1 += __shfl_xor(T1, 16, 64); T1 += __shfl_xor(T1, 32, 64);            \
        T2 += __shfl_xor(T2, 16, 64); T2 += __shfl_xor(T2, 32, 64);            \
        T3 += __shfl_xor(T3, 16, 64); T3 += __shfl_xor(T3, 32, 64);            \
    }

// gather #1: agg[d] = sum w*xtb[src]
__global__ __launch_bounds__(256) void hgA_gather(
    const int* __restrict__ row_start, const int2* __restrict__ csr,
    const bfu* __restrict__ xtb, float* __restrict__ agg, int N) {
    const int lane = threadIdx.x & 63, wv = threadIdx.x >> 6;
    const int d = blockIdx.x * 4 + wv;
    if (d >= N) return;
    const uint2* t64 = (const uint2*)xtb;
    const int n0 = row_start[d], n1 = row_start[d + 1];
    float t0, t1, t2, t3;
    GACC_QUAD(t64, csr, n0, n1, lane, t0, t1, t2, t3);
    if ((lane >> 4) == 0)
        *(float4*)(agg + (size_t)d * 64 + 4 * (lane & 15)) =
            make_float4(t0, t1, t2, t3);
}

// gather #2 + final HypAct fused
__global__ __launch_bounds__(256) void hgA_gather_out(
    const int* __restrict__ row_start, const int2* __restrict__ csr,
    const bfu* __restrict__ xtb2, float* __restrict__ out, int N) {
    const int lane = threadIdx.x & 63, wv = threadIdx.x >> 6;
    const int d = blockIdx.x * 4 + wv;
    if (d >= N) return;
    const uint2* t64 = (const uint2*)xtb2;
    const int n0 = row_start[d], n1 = row_start[d + 1];
    float t0, t1, t2, t3;
    GACC_QUAD(t64, csr, n0, n1, lane, t0, t1, t2, t3);
    float ssq = t0*t0 + t1*t1 + t2*t2 + t3*t3;
#pragma unroll
    for (int o = 1; o < 16; o <<= 1) ssq += __shfl_xor(ssq, o, 64);
    float n  = fmaxf(sqrtf(ssq), EPSV);
    float th = tanhf(n);
    float g  = th / n;
    float nh = fmaxf(th, EPSV);
    if (nh > MAXN) { g *= MAXN / nh; nh = MAXN; }
    float lamg = (artanh_(nh) / nh) * g;
    float r0 = fmaxf(lamg * t0, 0.0f);
    float r1 = fmaxf(lamg * t1, 0.0f);
    float r2 = fmaxf(lamg * t2, 0.0f);
    float r3 = fmaxf(lamg * t3, 0.0f);
    float tsq = r0*r0 + r1*r1 + r2*r2 + r3*r3;
#pragma unroll
    for (int o = 1; o < 16; o <<= 1) tsq += __shfl_xor(tsq, o, 64);
    float n2  = fmaxf(sqrtf(tsq), EPSV);
    float th2 = tanhf(n2);
    float g2  = th2 / n2;
    float nh2 = fmaxf(th2, EPSV);
    if (nh2 > MAXN) g2 *= MAXN / nh2;
    if ((lane >> 4) == 0)
        *(float4*)(out + (size_t)d * 64 + 4 * (lane & 15)) =
            make_float4(g2 * r0, g2 * r1, g2 * r2, g2 * r3);
}

// ===== layer 2: MFMA (bf16 W2) fused HypAct+matvec+tail; agg -> xtb2 =====
__global__ __launch_bounds__(256) void hgA_layer2_mfma(
    const float* __restrict__ agg,   // [N,64] fp32 (d_out)
    const bfu* __restrict__ w2b,     // [64,64] bf16 row-major
    const float* __restrict__ b2v,   // [64]
    bfu* __restrict__ xtb2, int N)   // [N,64] bf16 (ws)
{
    const int tid = threadIdx.x, lane = tid & 63, wv = tid >> 6;
    const int nodeBase = (blockIdx.x * 4 + wv) * 16;
    if (nodeBase >= N) return;

    float y2;
    float hb = bias_point(b2v, lane, &y2);
    float hbv[4];
#pragma unroll
    for (int t = 0; t < 4; ++t) hbv[t] = __shfl(hb, (lane & 15) + 16 * t);

    const int m = lane & 15, q = lane >> 4;
    const bool rowok = (nodeBase + m) < N;

    float af0[8], af1[8];
    const float* arow = agg + (size_t)(nodeBase + m) * 64 + q * 8;
    if (rowok) {
        *(float4*)(af0)     = *(const float4*)(arow);
        *(float4*)(af0 + 4) = *(const float4*)(arow + 4);
        *(float4*)(af1)     = *(const float4*)(arow + 32);
        *(float4*)(af1 + 4) = *(const float4*)(arow + 36);
    } else {
#pragma unroll
        for (int j = 0; j < 8; ++j) { af0[j] = 0.0f; af1[j] = 0.0f; }
    }
    float asq = 0.0f;
#pragma unroll
    for (int j = 0; j < 8; ++j) {
        asq = fmaf(af0[j], af0[j], asq);
        asq = fmaf(af1[j], af1[j], asq);
    }
    asq += __shfl_xor(asq, 16, 64);
    asq += __shfl_xor(asq, 32, 64);

    float n  = fmaxf(sqrtf(asq), EPSV);
    float th = tanhf(n);
    float g  = th / n;
    float nh = fmaxf(th, EPSV);
    if (nh > MAXN) { g *= MAXN / nh; nh = MAXN; }
    float lamg = (artanh_(nh) / nh) * g;
    float t0[8], t1[8], tsq = 0.0f;
#pragma unroll
    for (int j = 0; j < 8; ++j) {
        t0[j] = fmaxf(lamg * af0[j], 0.0f);
        t1[j] = fmaxf(lamg * af1[j], 0.0f);
        tsq = fmaf(t0[j], t0[j], tsq);
        tsq = fmaf(t1[j], t1[j], tsq);
    }
    tsq += __shfl_xor(tsq, 16, 64);
    tsq += __shfl_xor(tsq, 32, 64);
    float n2  = fmaxf(sqrtf(tsq), EPSV);
    float th2 = tanhf(n2);
    float g2  = th2 / n2;
    float nh2 = fmaxf(th2, EPSV);
    if (nh2 > MAXN) { g2 *= MAXN / nh2; nh2 = MAXN; }
    float xn_m = nh2;
    float x0[8], x1[8];
#pragma unroll
    for (int j = 0; j < 8; ++j) { x0[j] = g2 * t0[j]; x1[j] = g2 * t1[j]; }
    v8s a0 = cvt8(x0), a1 = cvt8(x1);

    v4f acc0 = {0,0,0,0}, acc1 = {0,0,0,0}, acc2 = {0,0,0,0}, acc3 = {0,0,0,0};
    {
        const bfu* wb;
        wb = w2b + (size_t)(m     ) * 64 + q * 8;
        acc0 = __builtin_amdgcn_mfma_f32_16x16x32_bf16(a0, *(const v8s*)(wb),      acc0, 0, 0, 0);
        acc0 = __builtin_amdgcn_mfma_f32_16x16x32_bf16(a1, *(const v8s*)(wb + 32), acc0, 0, 0, 0);
        wb = w2b + (size_t)(m + 16) * 64 + q * 8;
        acc1 = __builtin_amdgcn_mfma_f32_16x16x32_bf16(a0, *(const v8s*)(wb),      acc1, 0, 0, 0);
        acc1 = __builtin_amdgcn_mfma_f32_16x16x32_bf16(a1, *(const v8s*)(wb + 32), acc1, 0, 0, 0);
        wb = w2b + (size_t)(m + 32) * 64 + q * 8;
        acc2 = __builtin_amdgcn_mfma_f32_16x16x32_bf16(a0, *(const v8s*)(wb),      acc2, 0, 0, 0);
        acc2 = __builtin_amdgcn_mfma_f32_16x16x32_bf16(a1, *(const v8s*)(wb + 32), acc2, 0, 0, 0);
        wb = w2b + (size_t)(m + 48) * 64 + q * 8;
        acc3 = __builtin_amdgcn_mfma_f32_16x16x32_bf16(a0, *(const v8s*)(wb),      acc3, 0, 0, 0);
        acc3 = __builtin_amdgcn_mfma_f32_16x16x32_bf16(a1, *(const v8s*)(wb + 32), acc3, 0, 0, 0);
    }

    float P[4], Q[4];
#pragma unroll
    for (int r = 0; r < 4; ++r) {
        float s2 = acc0[r]*acc0[r] + acc1[r]*acc1[r] + acc2[r]*acc2[r] + acc3[r]*acc3[r];
        float sh = acc0[r]*hbv[0] + acc1[r]*hbv[1] + acc2[r]*hbv[2] + acc3[r]*hbv[3];
#pragma unroll
        for (int o = 1; o < 16; o <<= 1) {
            s2 += __shfl_xor(s2, o, 64);
            sh += __shfl_xor(sh, o, 64);
        }
        float xn = __shfl(xn_m, q * 4 + r);
        float mxn = fmaxf(sqrtf(s2), EPSV);
        float rt  = tanhf(mxn / xn * artanh_(xn));
        float k1, x2s, xy;
        if (s2 != 0.0f) {
            k1 = rt / mxn;
            float mvn = fmaxf(fabsf(rt), EPSV);
            if (mvn > MAXN) k1 *= MAXN / mvn;
            float cn = fminf(mvn, MAXN);
            x2s = cn * cn;
            xy  = k1 * sh;
        } else { k1 = 0.0f; x2s = 0.0f; xy = 0.0f; }
        float ca = 1.0f + 2.0f * xy + y2;
        float cb = 1.0f - x2s;
        float den = fmaxf(1.0f + 2.0f * xy + x2s * y2, EPSV);
        float hn2 = ca*ca*x2s + 2.0f*ca*cb*xy + cb*cb*y2;
        float hn = fmaxf(sqrtf(hn2) / den, EPSV);
        float hs = 1.0f;
        if (hn > MAXN) { hs = MAXN / hn; hn = MAXN; }
        float lam = artanh_(hn) / hn;
        P[r] = lam * hs * ca * k1 / den;
        Q[r] = lam * hs * cb / den;
    }
#pragma unroll
    for (int r = 0; r < 4; ++r) {
        int ri = nodeBase + q * 4 + r;
        if (ri < N) {
            bfu* orow = xtb2 + (size_t)ri * 64 + m;
            orow[ 0] = f2b(P[r] * acc0[r] + Q[r] * hbv[0]);
            orow[16] = f2b(P[r] * acc1[r] + Q[r] * hbv[1]);
            orow[32] = f2b(P[r] * acc2[r] + Q[r] * hbv[2]);
            orow[48] = f2b(P[r] * acc3[r] + Q[r] * hbv[3]);
        }
    }
}

// ===== fallback kernels (round-9 path, fp32 weights, used only if ws tiny) =====
__global__ __launch_bounds__(256) void hgA_layer1_fp32(
    const float* __restrict__ x, const float* __restrict__ W1,
    const float* __restrict__ b1v, float* __restrict__ xt, int N)
{
    const int tid = threadIdx.x, lane = tid & 63, wv = tid >> 6;
    const int nodeBase = (blockIdx.x * 4 + wv) * 16;
    if (nodeBase >= N) return;
    float y2;
    float hb = bias_point(b1v, lane, &y2);
    float hbv[4];
#pragma unroll
    for (int t = 0; t < 4; ++t) hbv[t] = __shfl(hb, (lane & 15) + 16 * t);
    const int m = lane & 15, q = lane >> 4;
    v4f acc0 = {0,0,0,0}, acc1 = {0,0,0,0}, acc2 = {0,0,0,0}, acc3 = {0,0,0,0};
    float usq = 0.0f;
    const float* arow = x + (size_t)(nodeBase + m) * 256 + q * 8;
#pragma unroll
    for (int s = 0; s < 8; ++s) {
        float af[8];
        *(float4*)(af)     = *(const float4*)(arow + s * 32);
        *(float4*)(af + 4) = *(const float4*)(arow + s * 32 + 4);
#pragma unroll
        for (int j = 0; j < 8; ++j) usq = fmaf(af[j], af[j], usq);
        v8s a = cvt8(af);
        const float* wbase = W1 + (size_t)m * 256 + s * 32 + q * 8;
        float wf[8];
        *(float4*)(wf) = *(const float4*)(wbase);  *(float4*)(wf+4) = *(const float4*)(wbase+4);
        acc0 = __builtin_amdgcn_mfma_f32_16x16x32_bf16(a, cvt8(wf), acc0, 0, 0, 0);
        *(float4*)(wf) = *(const float4*)(wbase+16*256); *(float4*)(wf+4) = *(const float4*)(wbase+16*256+4);
        acc1 = __builtin_amdgcn_mfma_f32_16x16x32_bf16(a, cvt8(wf), acc1, 0, 0, 0);
        *(float4*)(wf) = *(const float4*)(wbase+32*256); *(float4*)(wf+4) = *(const float4*)(wbase+32*256+4);
        acc2 = __builtin_amdgcn_mfma_f32_16x16x32_bf16(a, cvt8(wf), acc2, 0, 0, 0);
        *(float4*)(wf) = *(const float4*)(wbase+48*256); *(float4*)(wf+4) = *(const float4*)(wbase+48*256+4);
        acc3 = __builtin_amdgcn_mfma_f32_16x16x32_bf16(a, cvt8(wf), acc3, 0, 0, 0);
    }
    usq += __shfl_xor(usq, 16, 64);
    usq += __shfl_xor(usq, 32, 64);
    float P[4], Q[4];
#pragma unroll
    for (int r = 0; r < 4; ++r) {
        float s2 = acc0[r]*acc0[r] + acc1[r]*acc1[r] + acc2[r]*acc2[r] + acc3[r]*acc3[r];
        float sh = acc0[r]*hbv[0] + acc1[r]*hbv[1] + acc2[r]*hbv[2] + acc3[r]*hbv[3];
#pragma unroll
        for (int o = 1; o < 16; o <<= 1) { s2 += __shfl_xor(s2, o, 64); sh += __shfl_xor(sh, o, 64); }
        float usq_r = __shfl(usq, q * 4 + r);
        float n  = fmaxf(sqrtf(usq_r), EPSV);
        float th = tanhf(n);
        float gamma = th / n;
        float xn = fmaxf(th, EPSV);
        if (xn > MAXN) { gamma *= MAXN / xn; xn = MAXN; }
        float mxn = fmaxf(gamma * sqrtf(s2), EPSV);
        float rt  = tanhf(mxn / xn * artanh_(xn));
        float k1, x2s, xy;
        if (s2 != 0.0f) {
            k1 = (rt / mxn) * gamma;
            float mvn = fmaxf(fabsf(rt), EPSV);
            if (mvn > MAXN) k1 *= MAXN / mvn;
            float cn = fminf(mvn, MAXN);
            x2s = cn * cn; xy = k1 * sh;
        } else { k1 = 0.0f; x2s = 0.0f; xy = 0.0f; }
        float ca = 1.0f + 2.0f * xy + y2;
        float cb = 1.0f - x2s;
        float den = fmaxf(1.0f + 2.0f * xy + x2s * y2, EPSV);
        float hn2 = ca*ca*x2s + 2.0f*ca*cb*xy + cb*cb*y2;
        float hn = fmaxf(sqrtf(hn2) / den, EPSV);
        float hs = 1.0f;
        if (hn > MAXN) { hs = MAXN / hn; hn = MAXN; }
        float lam = artanh_(hn) / hn;
        P[r] = lam * hs * ca * k1 / den;
        Q[r] = lam * hs * cb / den;
    }
#pragma unroll
    for (int r = 0; r < 4; ++r) {
        float* orow = xt + (size_t)(nodeBase + q * 4 + r) * 64 + m;
        orow[ 0] = P[r] * acc0[r] + Q[r] * hbv[0];
        orow[16] = P[r] * acc1[r] + Q[r] * hbv[1];
        orow[32] = P[r] * acc2[r] + Q[r] * hbv[2];
        orow[48] = P[r] * acc3[r] + Q[r] * hbv[3];
    }
}

__global__ __launch_bounds__(256) void hgA_scatter(
    const int* __restrict__ src, const int* __restrict__ dst,
    const float* __restrict__ ew,
    const float* __restrict__ xt, float* __restrict__ agg, int E)
{
    const int lane = threadIdx.x & 63;
    const long long wid = ((long long)blockIdx.x * blockDim.x + threadIdx.x) >> 6;
    const long long nw = ((long long)gridDim.x * blockDim.x) >> 6;
    for (long long e = wid; e < E; e += nw) {
        int s = src[e], d = dst[e];
        atomicAdd(&agg[(size_t)d * 64 + lane], ew[e] * xt[(size_t)s * 64 + lane]);
    }
}

__global__ __launch_bounds__(256) void hgA_layer2_fb(
    const float* __restrict__ agg,
    const float* __restrict__ W2, const float* __restrict__ b2v,
    float* __restrict__ xt2, int N)
{
    const int lane = threadIdx.x & 63, wv = threadIdx.x >> 6;
    float y2;
    float hb = bias_point(b2v, lane, &y2);
    const int nw = gridDim.x * 4;
    for (int i = blockIdx.x * 4 + wv; i < N; i += nw) {
        float a = agg[(size_t)i * 64 + lane];
        float xn;
        float x2 = agg_transform(a, &xn);
        float acc = 0.0f;
        const float* Wrow = W2 + (size_t)lane * 64;
        for (int s = 0; s < 64; ++s)
            acc = fmaf(__shfl(x2, s), Wrow[s], acc);
        float o = mobius_tail(acc, xn, hb, y2);
        xt2[(size_t)i * 64 + lane] = o;
    }
}

__global__ __launch_bounds__(256) void hgA_final_fb(
    const float* __restrict__ agg, float* __restrict__ out, int N)
{
    const int lane = threadIdx.x & 63, wv = threadIdx.x >> 6;
    const int nw = gridDim.x * 4;
    for (int i = blockIdx.x * 4 + wv; i < N; i += nw) {
        float a = agg[(size_t)i * 64 + lane];
        float xn;
        float o = agg_transform(a, &xn);
        out[(size_t)i * 64 + lane] = o;
    }
}

extern "C" void kernel_launch(void* const* d_in, const int* in_sizes, int n_in,
                              void* d_out, int out_size, void* d_ws, size_t ws_size,
                              hipStream_t stream)
{
    const float* x  = (const float*)d_in[0];
    const int* src  = (const int*)d_in[1];
    const int* dst  = (const int*)d_in[2];
    const float* ew = (const float*)d_in[3];
    const float* W1 = (const float*)d_in[4];
    const float* b1 = (const float*)d_in[5];
    const float* W2 = (const float*)d_in[6];
    const float* b2 = (const float*)d_in[7];

    const int Dd = in_sizes[5];            // 64
    const int Ff = in_sizes[4] / Dd;       // 256
    const int N  = in_sizes[0] / Ff;       // 80000
    const int E  = in_sizes[1];            // 1280000
    const int NW1 = Dd * Ff;               // 16384
    const int NW2 = Dd * Dd;               // 4096

    float* out = (float*)d_out;
    float* agg = (float*)d_out;            // CSR path: fp32 agg lives in d_out

    const int NB = (N + 1023) / 1024;      // scan chunks

    const int blkT = (N + 63) / 64;        // wave per 16 nodes (layer kernels)
    const int blkG = (N + 3) / 4;          // wave per dst node (gathers)
    const int blkE4 = (E + 1023) / 1024;   // 4 edges/thread vblocks
    const int prepG = 128 + (NW1 + 255) / 256 + 1;
    const int n4 = (N * Dd) / 4;

    // --- tier A1 layout: [xtb][xb][usq][deg][rowst][rank][bsum][w1b][w2b][csr]
    size_t xtb_b = (size_t)N * Dd * 2;
    size_t xb_b  = (size_t)N * Ff * 2;
    bfu*  xtb   = (bfu*)d_ws;
    bfu*  xbA   = (bfu*)((char*)d_ws + xtb_b);
    float* usqt = (float*)((char*)d_ws + xtb_b + xb_b);
    size_t off1 = xtb_b + xb_b + (size_t)N * 4;
    int*  degA1   = (int*)((char*)d_ws + off1);
    int*  rowstA1 = degA1 + N;
    int*  rankA1  = rowstA1 + (N + 1);
    int*  bsumA1  = rankA1 + E;
    size_t w1_offA1 = (off1 + ((size_t)(2 * N + 1) + (size_t)E + (size_t)NB) * 4 + 15) & ~(size_t)15;
    bfu* w1bA1 = (bfu*)((char*)d_ws + w1_offA1);
    bfu* w2bA1 = w1bA1 + NW1;
    size_t csr_offA1 = (w1_offA1 + (size_t)(NW1 + NW2) * 2 + 7) & ~(size_t)7;
    const size_t needA1 = csr_offA1 + (size_t)E * 8;

    // --- tier A2 layout (round-15): [xtb][deg][rowst][cursor][rank][bsum][w][csr]
    int*  deg    = (int*)((char*)d_ws + xtb_b);
    int*  rowst  = deg + N;
    int*  cursor = rowst + (N + 1);
    int*  rank   = cursor + N;
    int*  bsum   = rank + E;
    size_t wA_off = (xtb_b + ((size_t)(3 * N + 1) + (size_t)E + (size_t)NB) * 4 + 15) & ~(size_t)15;
    bfu* w1bA = (bfu*)((char*)d_ws + wA_off);
    bfu* w2bA = w1bA + NW1;
    size_t csr_offA = (wA_off + (size_t)(NW1 + NW2) * 2 + 7) & ~(size_t)7;
    const size_t needA2 = csr_offA + (size_t)E * 8;

    // --- tier B layout
    size_t wB_off = (xtb_b + (size_t)(3 * N + 1) * 4 + 15) & ~(size_t)15;
    bfu* w1bB = (bfu*)((char*)d_ws + wB_off);
    bfu* w2bB = w1bB + NW1;
    size_t csr_offB = (wB_off + (size_t)(NW1 + NW2) * 2 + 7) & ~(size_t)7;
    const size_t needB = csr_offB + (size_t)E * 8;

    if (ws_size >= needA1) {
        int2* csr = (int2*)((char*)d_ws + csr_offA1);
        int L1S = blkT < 192 ? blkT : 192;     // l1 vblocks hosted by scan1
        int L1F = blkT - L1S;                  // rest hosted by fillr
        hgA_prep      <<<prepG, 256, 0, stream>>>(degA1, N, W1, W2, w1bA1, w2bA1, NW1, NW2);
        hgA_count_xcvt<<<blkE4 + blkT, 256, 0, stream>>>(
            dst, degA1, rankA1, E, blkE4, x, xbA, usqt, blkT, N);
        hgA_scan1     <<<NB + L1S, 256, 0, stream>>>(
            degA1, rowstA1, bsumA1, N, NB, xbA, usqt, w1bA1, b1, xtb, L1S);
        hgA_scan2     <<<1, 64, 0, stream>>>(bsumA1, rowstA1 + N, NB);
        hgA_scan3     <<<NB, 256, 0, stream>>>(rowstA1, bsumA1, N);
        hgA_fillr_l1b <<<blkE4 + L1F, 256, 0, stream>>>(
            src, dst, ew, rankA1, rowstA1, csr, E, blkE4, L1F, L1S,
            xbA, usqt, w1bA1, b1, xtb, N);
        hgA_gather     <<<blkG, 256, 0, stream>>>(rowstA1, csr, xtb, agg, N);
        hgA_layer2_mfma<<<blkT, 256, 0, stream>>>(agg, w2bA1, b2, xtb, N);
        hgA_gather_out <<<blkG, 256, 0, stream>>>(rowstA1, csr, xtb, out, N);
    } else if (ws_size >= needA2) {
        int2* csr = (int2*)((char*)d_ws + csr_offA);
        int L1C = blkT < 780 ? blkT : 780;
        int L1F = blkT - L1C;
        hgA_prep        <<<prepG, 256, 0, stream>>>(deg, N, W1, W2, w1bA, w2bA, NW1, NW2);
        hgA_count_rank_l1<<<blkE4 + L1C, 256, 0, stream>>>(
            dst, deg, rank, E, blkE4, L1C, x, w1bA, b1, xtb, N);
        hgA_scan1       <<<NB, 256, 0, stream>>>(deg, rowst, bsum, N, NB,
                                                 (const bfu*)xtb, (const float*)deg,
                                                 w1bA, b1, xtb, 0);
        hgA_scan2       <<<1,   64, 0, stream>>>(bsum, rowst + N, NB);
        hgA_scan3       <<<NB, 256, 0, stream>>>(rowst, bsum, N);
        hgA_fillr_layer1<<<blkE4 + L1F, 256, 0, stream>>>(
            src, dst, ew, rank, rowst, csr, E, blkE4, L1F, L1C,
            x, w1bA, b1, xtb, N);
        hgA_gather     <<<blkG, 256, 0, stream>>>(rowst, csr, xtb, agg, N);
        hgA_layer2_mfma<<<blkT, 256, 0, stream>>>(agg, w2bA, b2, xtb, N);
        hgA_gather_out <<<blkG, 256, 0, stream>>>(rowst, csr, xtb, out, N);
    } else if (ws_size >= needB) {
        int2* csr = (int2*)((char*)d_ws + csr_offB);
        const int fillBlocks = 2048;
        hgA_prep       <<<prepG, 256, 0, stream>>>(deg, N, W1, W2, w1bB, w2bB, NW1, NW2);
        hgA_count      <<<2048, 256, 0, stream>>>(dst, deg, E);
        hgA_scan_l1    <<<1,   1024, 0, stream>>>(
            deg, rowst, cursor, N, x, w1bB, b1, xtb, 0);
        hgA_fill_layer1<<<fillBlocks + blkT, 256, 0, stream>>>(
            src, dst, ew, cursor, csr, E, fillBlocks, x, w1bB, b1, xtb, N);
        hgA_gather     <<<blkG, 256, 0, stream>>>(rowst, csr, xtb, agg, N);
        hgA_layer2_mfma<<<blkT, 256, 0, stream>>>(agg, w2bB, b2, xtb, N);
        hgA_gather_out <<<blkG, 256, 0, stream>>>(rowst, csr, xtb, out, N);
    } else {
        // round-9 fallback: xt fp32 in d_out, agg fp32 in ws
        float* xt_fb  = (float*)d_out;
        float* agg_fb = (float*)d_ws;
        hgA_layer1_fp32<<<blkT, 256, 0, stream>>>(x, W1, b1, xt_fb, N);
        hgA_zero     <<<1024,  256, 0, stream>>>(agg_fb, n4);
        hgA_scatter  <<<16384, 256, 0, stream>>>(src, dst, ew, xt_fb, agg_fb, E);
        hgA_layer2_fb<<<2048,  256, 0, stream>>>(agg_fb, W2, b2, xt_fb, N);
        hgA_zero     <<<1024,  256, 0, stream>>>(agg_fb, n4);
        hgA_scatter  <<<16384, 256, 0, stream>>>(src, dst, ew, xt_fb, agg_fb, E);
        hgA_final_fb <<<2048,  256, 0, stream>>>(agg_fb, out, N);
    }
}

// Round 7
// 315.187 us; speedup vs baseline: 1.5100x; 1.0577x over previous
//
#include <hip/hip_runtime.h>

// HGCN forward (2-layer hyperbolic GCN), Poincare ball c=1. fp32 in/out
// (values bf16-grid). Round 17 = round 16 (333us) with:
//  GATHERS RESTRUCTURED: one 16-lane group per dst (4 dst/wave). A row is
//  128B = 16 lanes x uint2, so each group holds the full row (4 dims/lane):
//  - no cross-group fold (was 8 shuffles/wave),
//  - csr wave-load ~fully used (avg degree 16 = group width),
//  - 8-edge unrolled inner step -> 8 rows in flight per group = 32/wave
//    (was 4/wave) -- the gathers are latency x MLP bound (round-5 quad
//    proved instruction count is not the limit).
//  Grid drops 4x (blkG16 = N/16 blocks). Everything else as round 16.
// Tiers: A1 (xb bf16-x path) -> A2 (fp32-x) -> B (atomic fill) -> fallback.

#define EPSV 1e-15f
#define MAXN 0.996f   // (1 - 4e-3) / sqrt(c), c = 1

typedef unsigned short bfu;
typedef __attribute__((ext_vector_type(8))) short v8s;   // 8 bf16 (4 VGPRs)
typedef __attribute__((ext_vector_type(4))) float v4f;   // MFMA acc

__device__ __forceinline__ bfu f2b(float f) {   // fp32 -> bf16, RNE
    unsigned int u;
    __builtin_memcpy(&u, &f, sizeof(u));
    u += 0x7fffu + ((u >> 16) & 1u);
    return (bfu)(u >> 16);
}

__device__ __forceinline__ float b2f(bfu s) {
    unsigned int u = ((unsigned int)s) << 16;
    float f;
    __builtin_memcpy(&f, &u, sizeof(f));
    return f;
}

// low/high bf16 of a packed u32 -> fp32
__device__ __forceinline__ float uplo(unsigned int u) {
    unsigned int v = u << 16; float f;
    __builtin_memcpy(&f, &v, sizeof(f)); return f;
}
__device__ __forceinline__ float uphi(unsigned int u) {
    unsigned int v = u & 0xffff0000u; float f;
    __builtin_memcpy(&f, &v, sizeof(f)); return f;
}

__device__ __forceinline__ v8s cvt8(const float* f) {
    v8s r;
#pragma unroll
    for (int j = 0; j < 8; ++j) r[j] = (short)f2b(f[j]);
    return r;
}

__device__ __forceinline__ float i2f(int i) {
    float f; __builtin_memcpy(&f, &i, sizeof(f)); return f;
}
__device__ __forceinline__ int f2i(float f) {
    int i; __builtin_memcpy(&i, &f, sizeof(i)); return i;
}

__device__ __forceinline__ float wredsum(float v) {
#pragma unroll
    for (int o = 32; o > 0; o >>= 1) v += __shfl_xor(v, o, 64);
    return v;
}

__device__ __forceinline__ float artanh_(float x) {
    x = fminf(fmaxf(x, -1.0f + 1e-7f), 1.0f - 1e-7f);
    return 0.5f * logf((1.0f + x) / (1.0f - x));
}

__device__ __forceinline__ float mobius_tail(float mx, float xn, float hb, float y2) {
    float mxn2 = wredsum(mx * mx);
    unsigned long long nz = __ballot(mx != 0.0f);
    float mxn = fmaxf(sqrtf(mxn2), EPSV);
    float rt = tanhf(mxn / xn * artanh_(xn));
    float mv, x2s;
    if (nz != 0ull) {
        mv = (rt / mxn) * mx;
        float mvn = fmaxf(fabsf(rt), EPSV);
        if (mvn > MAXN) mv *= MAXN / mvn;
        float cn = fminf(mvn, MAXN);
        x2s = cn * cn;
    } else { mv = 0.0f; x2s = 0.0f; }
    float xy = wredsum(mv * hb);
    float ca = 1.0f + 2.0f * xy + y2;
    float cb = 1.0f - x2s;
    float den = fmaxf(1.0f + 2.0f * xy + x2s * y2, EPSV);
    float hj = (ca * mv + cb * hb) / den;
    float hn = fmaxf(sqrtf(wredsum(hj * hj)), EPSV);
    if (hn > MAXN) { hj *= MAXN / hn; hn = MAXN; }
    return (artanh_(hn) / hn) * hj;
}

__device__ __forceinline__ float agg_transform(float a, float* xn_out) {
    float n = fmaxf(sqrtf(wredsum(a * a)), EPSV);
    float th = tanhf(n);
    float g = th / n;
    float nh = fmaxf(th, EPSV);
    if (nh > MAXN) { g *= MAXN / nh; nh = MAXN; }
    float h = g * a;
    float t = fmaxf((artanh_(nh) / nh) * h, 0.0f);
    float n2 = fmaxf(sqrtf(wredsum(t * t)), EPSV);
    float th2 = tanhf(n2);
    float g2 = th2 / n2;
    float nh2 = fmaxf(th2, EPSV);
    if (nh2 > MAXN) { g2 *= MAXN / nh2; nh2 = MAXN; }
    *xn_out = nh2;
    return g2 * t;
}

__device__ __forceinline__ float bias_point(const float* bv, int lane, float* y2) {
    float b = bv[lane];
    float bn = fmaxf(sqrtf(wredsum(b * b)), EPSV);
    float gs = tanhf(bn) / bn;
    float hbn = fmaxf(tanhf(bn), EPSV);
    if (hbn > MAXN) gs *= MAXN / hbn;
    float hb = gs * b;
    *y2 = wredsum(hb * hb);
    return hb;
}

__global__ __launch_bounds__(256) void hgA_zero(float* __restrict__ p, int n4) {
    const float4 z = make_float4(0.f, 0.f, 0.f, 0.f);
    int stride = gridDim.x * blockDim.x;
    for (int i = blockIdx.x * blockDim.x + threadIdx.x; i < n4; i += stride)
        ((float4*)p)[i] = z;
}

// ===== prep: zero deg (blocks 0..127) + convert W1/W2 to bf16 =====
__global__ __launch_bounds__(256) void hgA_prep(
    int* __restrict__ deg, int N,
    const float* __restrict__ W1, const float* __restrict__ W2,
    bfu* __restrict__ w1b, bfu* __restrict__ w2b, int NW1, int NW2)
{
    const int b = blockIdx.x, tid = threadIdx.x;
    if (b < 128) {
        for (int i = b * 256 + tid; i < N; i += 128 * 256) deg[i] = 0;
    } else if (b < 128 + (NW1 + 255) / 256) {
        int i = (b - 128) * 256 + tid;
        if (i < NW1) w1b[i] = f2b(W1[i]);
    } else {
        for (int i = tid; i < NW2; i += 256) w2b[i] = f2b(W2[i]);
    }
}

// shared tail of layer1: from accs + usq to xtb writes (bit-identical both paths)
__device__ __forceinline__ void layer1_tail(
    int nodeBase, int m, int q, float usq, const float* hbv, float y2,
    v4f acc0, v4f acc1, v4f acc2, v4f acc3, bfu* __restrict__ xtb)
{
    float P[4], Q[4];
#pragma unroll
    for (int r = 0; r < 4; ++r) {
        float s2 = acc0[r]*acc0[r] + acc1[r]*acc1[r] + acc2[r]*acc2[r] + acc3[r]*acc3[r];
        float sh = acc0[r]*hbv[0] + acc1[r]*hbv[1] + acc2[r]*hbv[2] + acc3[r]*hbv[3];
#pragma unroll
        for (int o = 1; o < 16; o <<= 1) {
            s2 += __shfl_xor(s2, o, 64);
            sh += __shfl_xor(sh, o, 64);
        }
        float usq_r = __shfl(usq, q * 4 + r);
        float n  = fmaxf(sqrtf(usq_r), EPSV);
        float th = tanhf(n);
        float gamma = th / n;
        float xn = fmaxf(th, EPSV);
        if (xn > MAXN) { gamma *= MAXN / xn; xn = MAXN; }
        float mxn = fmaxf(gamma * sqrtf(s2), EPSV);
        float rt  = tanhf(mxn / xn * artanh_(xn));
        float k1, x2s, xy;
        if (s2 != 0.0f) {
            k1 = (rt / mxn) * gamma;
            float mvn = fmaxf(fabsf(rt), EPSV);
            if (mvn > MAXN) k1 *= MAXN / mvn;
            float cn = fminf(mvn, MAXN);
            x2s = cn * cn;
            xy  = k1 * sh;
        } else { k1 = 0.0f; x2s = 0.0f; xy = 0.0f; }
        float ca = 1.0f + 2.0f * xy + y2;
        float cb = 1.0f - x2s;
        float den = fmaxf(1.0f + 2.0f * xy + x2s * y2, EPSV);
        float hn2 = ca*ca*x2s + 2.0f*ca*cb*xy + cb*cb*y2;
        float hn = fmaxf(sqrtf(hn2) / den, EPSV);
        float hs = 1.0f;
        if (hn > MAXN) { hs = MAXN / hn; hn = MAXN; }
        float lam = artanh_(hn) / hn;
        P[r] = lam * hs * ca * k1 / den;
        Q[r] = lam * hs * cb / den;
    }
#pragma unroll
    for (int r = 0; r < 4; ++r) {
        bfu* orow = xtb + (size_t)(nodeBase + q * 4 + r) * 64 + m;
        orow[ 0] = f2b(P[r] * acc0[r] + Q[r] * hbv[0]);
        orow[16] = f2b(P[r] * acc1[r] + Q[r] * hbv[1]);
        orow[32] = f2b(P[r] * acc2[r] + Q[r] * hbv[2]);
        orow[48] = f2b(P[r] * acc3[r] + Q[r] * hbv[3]);
    }
}

// ===== layer1 body, fp32-x path (tiers A2/B) =====
__device__ __forceinline__ void layer1_body(
    int bid, int tid, const float* __restrict__ x, const bfu* __restrict__ w1b,
    const float* __restrict__ b1v, bfu* __restrict__ xtb, int N)
{
    const int lane = tid & 63, wv = tid >> 6;
    const int nodeBase = (bid * 4 + wv) * 16;
    if (nodeBase >= N) return;

    float y2;
    float hb = bias_point(b1v, lane, &y2);
    float hbv[4];
#pragma unroll
    for (int t = 0; t < 4; ++t) hbv[t] = __shfl(hb, (lane & 15) + 16 * t);

    const int m = lane & 15, q = lane >> 4;
    v4f acc0 = {0,0,0,0}, acc1 = {0,0,0,0}, acc2 = {0,0,0,0}, acc3 = {0,0,0,0};
    float usq = 0.0f;

    const float* arow = x + (size_t)(nodeBase + m) * 256 + q * 8;
    const bfu* wrow = w1b + (size_t)m * 256 + q * 8;
#pragma unroll
    for (int s = 0; s < 8; ++s) {
        float af[8];
        *(float4*)(af)     = *(const float4*)(arow + s * 32);
        *(float4*)(af + 4) = *(const float4*)(arow + s * 32 + 4);
#pragma unroll
        for (int j = 0; j < 8; ++j) usq = fmaf(af[j], af[j], usq);
        v8s a = cvt8(af);
        const bfu* wb = wrow + s * 32;
        acc0 = __builtin_amdgcn_mfma_f32_16x16x32_bf16(a, *(const v8s*)(wb), acc0, 0, 0, 0);
        acc1 = __builtin_amdgcn_mfma_f32_16x16x32_bf16(a, *(const v8s*)(wb + 16 * 256), acc1, 0, 0, 0);
        acc2 = __builtin_amdgcn_mfma_f32_16x16x32_bf16(a, *(const v8s*)(wb + 32 * 256), acc2, 0, 0, 0);
        acc3 = __builtin_amdgcn_mfma_f32_16x16x32_bf16(a, *(const v8s*)(wb + 48 * 256), acc3, 0, 0, 0);
    }
    usq += __shfl_xor(usq, 16, 64);
    usq += __shfl_xor(usq, 32, 64);
    layer1_tail(nodeBase, m, q, usq, hbv, y2, acc0, acc1, acc2, acc3, xtb);
}

// ===== layer1 body, bf16-x path (tier A1): pure loads+MFMA =====
__device__ __forceinline__ void layer1b_body(
    int bid, int tid, const bfu* __restrict__ xb, const float* __restrict__ usqt,
    const bfu* __restrict__ w1b, const float* __restrict__ b1v,
    bfu* __restrict__ xtb, int N)
{
    const int lane = tid & 63, wv = tid >> 6;
    const int nodeBase = (bid * 4 + wv) * 16;
    if (nodeBase >= N) return;

    float y2;
    float hb = bias_point(b1v, lane, &y2);
    float hbv[4];
#pragma unroll
    for (int t = 0; t < 4; ++t) hbv[t] = __shfl(hb, (lane & 15) + 16 * t);

    const int m = lane & 15, q = lane >> 4;
    v4f acc0 = {0,0,0,0}, acc1 = {0,0,0,0}, acc2 = {0,0,0,0}, acc3 = {0,0,0,0};
    const float usq = usqt[nodeBase + m];   // precomputed, bit-identical chain

    const bfu* arow = xb + (size_t)(nodeBase + m) * 256 + q * 8;
    const bfu* wrow = w1b + (size_t)m * 256 + q * 8;
#pragma unroll
    for (int s = 0; s < 8; ++s) {
        v8s a = *(const v8s*)(arow + s * 32);
        const bfu* wb = wrow + s * 32;
        acc0 = __builtin_amdgcn_mfma_f32_16x16x32_bf16(a, *(const v8s*)(wb), acc0, 0, 0, 0);
        acc1 = __builtin_amdgcn_mfma_f32_16x16x32_bf16(a, *(const v8s*)(wb + 16 * 256), acc1, 0, 0, 0);
        acc2 = __builtin_amdgcn_mfma_f32_16x16x32_bf16(a, *(const v8s*)(wb + 32 * 256), acc2, 0, 0, 0);
        acc3 = __builtin_amdgcn_mfma_f32_16x16x32_bf16(a, *(const v8s*)(wb + 48 * 256), acc3, 0, 0, 0);
    }
    layer1_tail(nodeBase, m, q, usq, hbv, y2, acc0, acc1, acc2, acc3, xtb);
}

// ===== CSR build =====
__global__ __launch_bounds__(256) void hgA_zero_i32(int* __restrict__ p, int n) {
    int stride = gridDim.x * blockDim.x;
    for (int i = blockIdx.x * blockDim.x + threadIdx.x; i < n; i += stride) p[i] = 0;
}

// tier B count (no rank)
__global__ __launch_bounds__(256) void hgA_count(
    const int* __restrict__ dst, int* __restrict__ deg, int E) {
    int stride = gridDim.x * blockDim.x;
    for (int e = blockIdx.x * blockDim.x + threadIdx.x; e < E; e += stride)
        atomicAdd(&deg[dst[e]], 1);
}

// tier A2 count_rank + fp32 layer1 share (parity-interleaved)
__global__ __launch_bounds__(256) void hgA_count_rank_l1(
    const int* __restrict__ dst, int* __restrict__ deg, int* __restrict__ rank,
    int E, int nf, int nl,
    const float* __restrict__ x, const bfu* __restrict__ w1b,
    const float* __restrict__ b1v, bfu* __restrict__ xtb, int N)
{
    const int b = blockIdx.x;
    const int mn = nf < nl ? nf : nl;
    bool isC; int idx;
    if (b < 2 * mn) { isC = !(b & 1); idx = b >> 1; }
    else            { isC = (nf > nl); idx = mn + (b - 2 * mn); }
    if (isC) {
        int e0 = (idx * 256 + threadIdx.x) * 4;
        if (e0 + 4 <= E) {
            int4 d4 = *(const int4*)(dst + e0);
            int4 r4;
            r4.x = atomicAdd(&deg[d4.x], 1);
            r4.y = atomicAdd(&deg[d4.y], 1);
            r4.z = atomicAdd(&deg[d4.z], 1);
            r4.w = atomicAdd(&deg[d4.w], 1);
            *(int4*)(rank + e0) = r4;
        } else if (e0 < E) {
            for (int e = e0; e < E; ++e) rank[e] = atomicAdd(&deg[dst[e]], 1);
        }
    } else {
        layer1_body(idx, threadIdx.x, x, w1b, b1v, xtb, N);
    }
}

// tier A1: count_rank || x->bf16 convert + usq precompute (parity-interleaved)
__global__ __launch_bounds__(256) void hgA_count_xcvt(
    const int* __restrict__ dst, int* __restrict__ deg, int* __restrict__ rank,
    int E, int nf,
    const float* __restrict__ x, bfu* __restrict__ xb, float* __restrict__ usqt,
    int nc, int N)
{
    const int b = blockIdx.x;
    const int mn = nf < nc ? nf : nc;
    bool isC; int idx;
    if (b < 2 * mn) { isC = !(b & 1); idx = b >> 1; }
    else            { isC = (nf > nc); idx = mn + (b - 2 * mn); }
    if (isC) {
        int e0 = (idx * 256 + threadIdx.x) * 4;
        if (e0 + 4 <= E) {
            int4 d4 = *(const int4*)(dst + e0);
            int4 r4;
            r4.x = atomicAdd(&deg[d4.x], 1);
            r4.y = atomicAdd(&deg[d4.y], 1);
            r4.z = atomicAdd(&deg[d4.z], 1);
            r4.w = atomicAdd(&deg[d4.w], 1);
            *(int4*)(rank + e0) = r4;
        } else if (e0 < E) {
            for (int e = e0; e < E; ++e) rank[e] = atomicAdd(&deg[dst[e]], 1);
        }
    } else {
        // xcvt role: mirror layer1's exact load pattern + usq chain
        const int lane = threadIdx.x & 63, wv = threadIdx.x >> 6;
        const int nodeBase = (idx * 4 + wv) * 16;
        if (nodeBase >= N) return;
        const int m = lane & 15, q = lane >> 4;
        const float* arow = x + (size_t)(nodeBase + m) * 256 + q * 8;
        bfu* orow = xb + (size_t)(nodeBase + m) * 256 + q * 8;
        float usq = 0.0f;
#pragma unroll
        for (int s = 0; s < 8; ++s) {
            float af[8];
            *(float4*)(af)     = *(const float4*)(arow + s * 32);
            *(float4*)(af + 4) = *(const float4*)(arow + s * 32 + 4);
#pragma unroll
            for (int j = 0; j < 8; ++j) usq = fmaf(af[j], af[j], usq);
            *(v8s*)(orow + s * 32) = cvt8(af);
        }
        usq += __shfl_xor(usq, 16, 64);
        usq += __shfl_xor(usq, 32, 64);
        if (lane < 16 && nodeBase + lane < N) usqt[nodeBase + lane] = usq;
    }
}

// ===== parallel scan, phase 1 (+optional bf16 l1 tail blocks) =====
__global__ __launch_bounds__(256) void hgA_scan1(
    const int* __restrict__ deg, int* __restrict__ rowst,
    int* __restrict__ bsum, int N, int NBr,
    const bfu* __restrict__ xb, const float* __restrict__ usqt,
    const bfu* __restrict__ w1b, const float* __restrict__ b1v,
    bfu* __restrict__ xtb, int NL)
{
    if (blockIdx.x >= NBr) {
        int vb = blockIdx.x - NBr;
        if (vb < NL) layer1b_body(vb, threadIdx.x, xb, usqt, w1b, b1v, xtb, N);
        return;
    }
    __shared__ int wsum[4];
    const int tid = threadIdx.x, lane = tid & 63, wv = tid >> 6;
    const int base = blockIdx.x * 1024 + tid * 4;
    int v0 = 0, v1 = 0, v2 = 0, v3 = 0;
    if (base + 4 <= N) {
        int4 d4 = *(const int4*)(deg + base);
        v0 = d4.x; v1 = d4.y; v2 = d4.z; v3 = d4.w;
    } else {
        if (base + 0 < N) v0 = deg[base + 0];
        if (base + 1 < N) v1 = deg[base + 1];
        if (base + 2 < N) v2 = deg[base + 2];
        if (base + 3 < N) v3 = deg[base + 3];
    }
    const int tsum = v0 + v1 + v2 + v3;
    int incl = tsum;
#pragma unroll
    for (int o = 1; o < 64; o <<= 1) {
        int nb = __shfl_up(incl, o, 64);
        if (lane >= o) incl += nb;
    }
    if (lane == 63) wsum[wv] = incl;
    __syncthreads();
    int add = 0;
#pragma unroll
    for (int w = 0; w < 4; ++w) { int s = wsum[w]; if (w < wv) add += s; }
    const int excl = add + incl - tsum;
    const int e0 = excl, e1 = e0 + v0, e2 = e1 + v1, e3 = e2 + v2;
    if (base + 4 <= N) {
        *(int4*)(rowst + base) = make_int4(e0, e1, e2, e3);
    } else {
        if (base + 0 < N) rowst[base + 0] = e0;
        if (base + 1 < N) rowst[base + 1] = e1;
        if (base + 2 < N) rowst[base + 2] = e2;
        if (base + 3 < N) rowst[base + 3] = e3;
    }
    if (tid == 255) bsum[blockIdx.x] = add + incl;
}

// phase 2: single wave, exclusive-scan the NB block sums in place; total -> *tot
__global__ __launch_bounds__(64) void hgA_scan2(
    int* __restrict__ bsum, int* __restrict__ tot, int NB)
{
    const int lane = threadIdx.x;
    int run = 0;
    for (int b = 0; b < NB; b += 64) {
        int i = b + lane;
        int v = (i < NB) ? bsum[i] : 0;
        int incl = v;
#pragma unroll
        for (int o = 1; o < 64; o <<= 1) {
            int nb = __shfl_up(incl, o, 64);
            if (lane >= o) incl += nb;
        }
        if (i < NB) bsum[i] = run + incl - v;
        run += __shfl(incl, 63);
    }
    if (lane == 0) *tot = run;
}

// phase 3: add per-chunk offsets
__global__ __launch_bounds__(256) void hgA_scan3(
    int* __restrict__ rowst, const int* __restrict__ bsum, int N)
{
    const int base = blockIdx.x * 1024 + threadIdx.x * 4;
    const int off = bsum[blockIdx.x];
    if (base + 4 <= N) {
        int4 r = *(int4*)(rowst + base);
        r.x += off; r.y += off; r.z += off; r.w += off;
        *(int4*)(rowst + base) = r;
    } else {
        for (int i = base; i < N; ++i) rowst[i] += off;
    }
}

// tier B: serial scan (block 0) -- retained as safety net
__global__ __launch_bounds__(1024) void hgA_scan_l1(
    const int* __restrict__ deg, int* __restrict__ row_start,
    int* __restrict__ cursor, int N,
    const float* __restrict__ x, const bfu* __restrict__ w1b,
    const float* __restrict__ b1v, bfu* __restrict__ xtb, int NL)
{
    if (blockIdx.x != 0) {
        int vb = (blockIdx.x - 1) * 4 + (threadIdx.x >> 8);
        if (vb < NL) layer1_body(vb, threadIdx.x & 255, x, w1b, b1v, xtb, N);
        return;
    }
    __shared__ int wsum[16];
    __shared__ int srun;
    const int tid = threadIdx.x, lane = tid & 63, wv = tid >> 6;
    if (tid == 0) srun = 0;
    __syncthreads();
    for (int base = 0; base < N; base += 1024) {
        int i = base + tid;
        int v = (i < N) ? deg[i] : 0;
        int incl = v;
#pragma unroll
        for (int o = 1; o < 64; o <<= 1) {
            int nbr = __shfl_up(incl, o, 64);
            if (lane >= o) incl += nbr;
        }
        if (lane == 63) wsum[wv] = incl;
        __syncthreads();
        int add = 0;
#pragma unroll
        for (int w = 0; w < 16; ++w) { int s = wsum[w]; if (w < wv) add += s; }
        int excl = srun + add + incl - v;
        if (i < N) { row_start[i] = excl; cursor[i] = excl; }
        __syncthreads();
        if (tid == 1023) srun += add + incl;
        __syncthreads();
    }
    if (tid == 0) row_start[N] = srun;
}

// ===== tier B fused: fill (atomic cursor) || fp32 layer1 =====
__global__ __launch_bounds__(256) void hgA_fill_layer1(
    const int* __restrict__ src, const int* __restrict__ dst,
    const float* __restrict__ ew, int* __restrict__ cursor,
    int2* __restrict__ csr, int E, int fillBlocks,
    const float* __restrict__ x, const bfu* __restrict__ w1b,
    const float* __restrict__ b1v, bfu* __restrict__ xtb, int N)
{
    const int b = blockIdx.x;
    if (b < fillBlocks) {
        int stride = fillBlocks * blockDim.x;
        for (int e = b * blockDim.x + threadIdx.x; e < E; e += stride) {
            int d = dst[e];
            int slot = atomicAdd(&cursor[d], 1);
            csr[slot] = make_int2(src[e], f2i(ew[e]));
        }
    } else {
        layer1_body(b - fillBlocks, threadIdx.x, x, w1b, b1v, xtb, N);
    }
}

// ===== tier A2 fused: atomic-free fill || fp32 layer1, interleaved =====
__global__ __launch_bounds__(256) void hgA_fillr_layer1(
    const int* __restrict__ src, const int* __restrict__ dst,
    const float* __restrict__ ew, const int* __restrict__ rank,
    const int* __restrict__ row_start, int2* __restrict__ csr,
    int E, int nf, int nl, int l1off,
    const float* __restrict__ x, const bfu* __restrict__ w1b,
    const float* __restrict__ b1v, bfu* __restrict__ xtb, int N)
{
    const int b = blockIdx.x;
    const int mn = nf < nl ? nf : nl;
    bool isFill; int idx;
    if (b < 2 * mn) { isFill = !(b & 1); idx = b >> 1; }
    else            { isFill = (nf > nl); idx = mn + (b - 2 * mn); }
    if (isFill) {
        int e0 = (idx * 256 + threadIdx.x) * 4;
        if (e0 + 4 <= E) {
            int4  d4 = *(const int4*)(dst + e0);
            int4  s4 = *(const int4*)(src + e0);
            int4  r4 = *(const int4*)(rank + e0);
            float4 w4 = *(const float4*)(ew + e0);
            csr[row_start[d4.x] + r4.x] = make_int2(s4.x, f2i(w4.x));
            csr[row_start[d4.y] + r4.y] = make_int2(s4.y, f2i(w4.y));
            csr[row_start[d4.z] + r4.z] = make_int2(s4.z, f2i(w4.z));
            csr[row_start[d4.w] + r4.w] = make_int2(s4.w, f2i(w4.w));
        } else if (e0 < E) {
            for (int e = e0; e < E; ++e)
                csr[row_start[dst[e]] + rank[e]] = make_int2(src[e], f2i(ew[e]));
        }
    } else {
        layer1_body(l1off + idx, threadIdx.x, x, w1b, b1v, xtb, N);
    }
}

// ===== tier A1 fused: atomic-free fill || bf16 layer1, interleaved =====
__global__ __launch_bounds__(256) void hgA_fillr_l1b(
    const int* __restrict__ src, const int* __restrict__ dst,
    const float* __restrict__ ew, const int* __restrict__ rank,
    const int* __restrict__ row_start, int2* __restrict__ csr,
    int E, int nf, int nl, int l1off,
    const bfu* __restrict__ xb, const float* __restrict__ usqt,
    const bfu* __restrict__ w1b, const float* __restrict__ b1v,
    bfu* __restrict__ xtb, int N)
{
    const int b = blockIdx.x;
    const int mn = nf < nl ? nf : nl;
    bool isFill; int idx;
    if (b < 2 * mn) { isFill = !(b & 1); idx = b >> 1; }
    else            { isFill = (nf > nl); idx = mn + (b - 2 * mn); }
    if (isFill) {
        int e0 = (idx * 256 + threadIdx.x) * 4;
        if (e0 + 4 <= E) {
            int4  d4 = *(const int4*)(dst + e0);
            int4  s4 = *(const int4*)(src + e0);
            int4  r4 = *(const int4*)(rank + e0);
            float4 w4 = *(const float4*)(ew + e0);
            csr[row_start[d4.x] + r4.x] = make_int2(s4.x, f2i(w4.x));
            csr[row_start[d4.y] + r4.y] = make_int2(s4.y, f2i(w4.y));
            csr[row_start[d4.z] + r4.z] = make_int2(s4.z, f2i(w4.z));
            csr[row_start[d4.w] + r4.w] = make_int2(s4.w, f2i(w4.w));
        } else if (e0 < E) {
            for (int e = e0; e < E; ++e)
                csr[row_start[dst[e]] + rank[e]] = make_int2(src[e], f2i(ew[e]));
        }
    } else {
        layer1b_body(l1off + idx, threadIdx.x, xb, usqt, w1b, b1v, xtb, N);
    }
}

// ===== 16-lane-group gather core: one dst per group, 4 dst per wave =====
// Lane sl covers dims [4*sl, 4*sl+4) of its group's dst row (uint2 = 4 bf16).
// 8-edge main step keeps 8 rows in flight per group (32 per wave). No
// cross-group fold needed (group exclusively owns its dst). Shuffles only
// read within the own group -> safe under inter-group loop divergence.
#define GACC_G16(T64, CSR, N0, N1, SL, GBASE, AX, AY, AZ, AW)                  \
    {                                                                          \
        float bx=0.f,by=0.f,bz=0.f,bw=0.f;                                     \
        for (int base = (N0); base < (N1); base += 16) {                       \
            int cnt = (N1) - base; if (cnt > 16) cnt = 16;                     \
            int sL = 0; float wL = 0.0f;                                       \
            if ((SL) < cnt) { int2 rec = (CSR)[base + (SL)];                   \
                              sL = rec.x; wL = i2f(rec.y); }                   \
            int j = 0;                                                         \
            for (; j + 8 <= cnt; j += 8) {                                     \
                int   s0 = __shfl(sL, (GBASE)+j  , 64), s1 = __shfl(sL, (GBASE)+j+1, 64); \
                int   s2 = __shfl(sL, (GBASE)+j+2, 64), s3 = __shfl(sL, (GBASE)+j+3, 64); \
                int   s4 = __shfl(sL, (GBASE)+j+4, 64), s5 = __shfl(sL, (GBASE)+j+5, 64); \
                int   s6 = __shfl(sL, (GBASE)+j+6, 64), s7 = __shfl(sL, (GBASE)+j+7, 64); \
                float w0 = __shfl(wL, (GBASE)+j  , 64), w1 = __shfl(wL, (GBASE)+j+1, 64); \
                float w2 = __shfl(wL, (GBASE)+j+2, 64), w3 = __shfl(wL, (GBASE)+j+3, 64); \
                float w4 = __shfl(wL, (GBASE)+j+4, 64), w5 = __shfl(wL, (GBASE)+j+5, 64); \
                float w6 = __shfl(wL, (GBASE)+j+6, 64), w7 = __shfl(wL, (GBASE)+j+7, 64); \
                uint2 u0 = (T64)[(size_t)s0 * 16 + (SL)];                      \
                uint2 u1 = (T64)[(size_t)s1 * 16 + (SL)];                      \
                uint2 u2 = (T64)[(size_t)s2 * 16 + (SL)];                      \
                uint2 u3 = (T64)[(size_t)s3 * 16 + (SL)];                      \
                uint2 u4 = (T64)[(size_t)s4 * 16 + (SL)];                      \
                uint2 u5 = (T64)[(size_t)s5 * 16 + (SL)];                      \
                uint2 u6 = (T64)[(size_t)s6 * 16 + (SL)];                      \
                uint2 u7 = (T64)[(size_t)s7 * 16 + (SL)];                      \
                AX = fmaf(w0, uplo(u0.x), AX); AY = fmaf(w0, uphi(u0.x), AY);  \
                AZ = fmaf(w0, uplo(u0.y), AZ); AW = fmaf(w0, uphi(u0.y), AW);  \
                bx = fmaf(w1, uplo(u1.x), bx); by = fmaf(w1, uphi(u1.x), by);  \
                bz = fmaf(w1, uplo(u1.y), bz); bw = fmaf(w1, uphi(u1.y), bw);  \
                AX = fmaf(w2, uplo(u2.x), AX); AY = fmaf(w2, uphi(u2.x), AY);  \
                AZ = fmaf(w2, uplo(u2.y), AZ); AW = fmaf(w2, uphi(u2.y), AW);  \
                bx = fmaf(w3, uplo(u3.x), bx); by = fmaf(w3, uphi(u3.x), by);  \
                bz = fmaf(w3, uplo(u3.y), bz); bw = fmaf(w3, uphi(u3.y), bw);  \
                AX = fmaf(w4, uplo(u4.x), AX); AY = fmaf(w4, uphi(u4.x), AY);  \
                AZ = fmaf(w4, uplo(u4.y), AZ); AW = fmaf(w4, uphi(u4.y), AW);  \
                bx = fmaf(w5, uplo(u5.x), bx); by = fmaf(w5, uphi(u5.x), by);  \
                bz = fmaf(w5, uplo(u5.y), bz); bw = fmaf(w5, uphi(u5.y), bw);  \
                AX = fmaf(w6, uplo(u6.x), AX); AY = fmaf(w6, uphi(u6.x), AY);  \
                AZ = fmaf(w6, uplo(u6.y), AZ); AW = fmaf(w6, uphi(u6.y), AW);  \
                bx = fmaf(w7, uplo(u7.x), bx); by = fmaf(w7, uphi(u7.x), by);  \
                bz = fmaf(w7, uplo(u7.y), bz); bw = fmaf(w7, uphi(u7.y), bw);  \
            }                                                                  \
            for (; j < cnt; j += 4) {   /* pads (w=0, s=0) are safe */         \
                int   s0 = __shfl(sL, (GBASE)+j  , 64), s1 = __shfl(sL, (GBASE)+j+1, 64); \
                int   s2 = __shfl(sL, (GBASE)+j+2, 64), s3 = __shfl(sL, (GBASE)+j+3, 64); \
                float w0 = __shfl(wL, (GBASE)+j  , 64), w1 = __shfl(wL, (GBASE)+j+1, 64); \
                float w2 = __shfl(wL, (GBASE)+j+2, 64), w3 = __shfl(wL, (GBASE)+j+3, 64); \
                uint2 u0 = (T64)[(size_t)s0 * 16 + (SL)];                      \
                uint2 u1 = (T64)[(size_t)s1 * 16 + (SL)];                      \
                uint2 u2 = (T64)[(size_t)s2 * 16 + (SL)];                      \
                uint2 u3 = (T64)[(size_t)s3 * 16 + (SL)];                      \
                AX = fmaf(w0, uplo(u0.x), AX); AY = fmaf(w0, uphi(u0.x), AY);  \
                AZ = fmaf(w0, uplo(u0.y), AZ); AW = fmaf(w0, uphi(u0.y), AW);  \
                bx = fmaf(w1, uplo(u1.x), bx); by = fmaf(w1, uphi(u1.x), by);  \
                bz = fmaf(w1, uplo(u1.y), bz); bw = fmaf(w1, uphi(u1.y), bw);  \
                AX = fmaf(w2, uplo(u2.x), AX); AY = fmaf(w2, uphi(u2.x), AY);  \
                AZ = fmaf(w2, uplo(u2.y), AZ); AW = fmaf(w2, uphi(u2.y), AW);  \
                bx = fmaf(w3, uplo(u3.x), bx); by = fmaf(w3, uphi(u3.x), by);  \
                bz = fmaf(w3, uplo(u3.y), bz); bw = fmaf(w3, uphi(u3.y), bw);  \
            }                                                                  \
        }                                                                      \
        AX += bx; AY += by; AZ += bz; AW += bw;                                \
    }

// gather #1: agg[d] = sum w*xtb[src]; 16 dst per block
__global__ __launch_bounds__(256) void hgA_gather(
    const int* __restrict__ row_start, const int2* __restrict__ csr,
    const bfu* __restrict__ xtb, float* __restrict__ agg, int N) {
    const int lane = threadIdx.x & 63, wv = threadIdx.x >> 6;
    const int g = lane >> 4, sl = lane & 15, gbase = g << 4;
    const int d = (blockIdx.x * 4 + wv) * 4 + g;
    if (d >= N) return;
    const uint2* t64 = (const uint2*)xtb;
    const int n0 = row_start[d], n1 = row_start[d + 1];
    float ax = 0.f, ay = 0.f, az = 0.f, aw = 0.f;
    GACC_G16(t64, csr, n0, n1, sl, gbase, ax, ay, az, aw);
    *(float4*)(agg + (size_t)d * 64 + 4 * sl) = make_float4(ax, ay, az, aw);
}

// gather #2 + final HypAct fused; group-local (16-lane) reductions
__global__ __launch_bounds__(256) void hgA_gather_out(
    const int* __restrict__ row_start, const int2* __restrict__ csr,
    const bfu* __restrict__ xtb2, float* __restrict__ out, int N) {
    const int lane = threadIdx.x & 63, wv = threadIdx.x >> 6;
    const int g = lane >> 4, sl = lane & 15, gbase = g << 4;
    const int d = (blockIdx.x * 4 + wv) * 4 + g;
    if (d >= N) return;
    const uint2* t64 = (const uint2*)xtb2;
    const int n0 = row_start[d], n1 = row_start[d + 1];
    float t0 = 0.f, t1 = 0.f, t2 = 0.f, t3 = 0.f;
    GACC_G16(t64, csr, n0, n1, sl, gbase, t0, t1, t2, t3);
    float ssq = t0*t0 + t1*t1 + t2*t2 + t3*t3;
#pragma unroll
    for (int o = 1; o < 16; o <<= 1) ssq += __shfl_xor(ssq, o, 64);
    float n  = fmaxf(sqrtf(ssq), EPSV);
    float th = tanhf(n);
    float gg = th / n;
    float nh = fmaxf(th, EPSV);
    if (nh > MAXN) { gg *= MAXN / nh; nh = MAXN; }
    float lamg = (artanh_(nh) / nh) * gg;
    float r0 = fmaxf(lamg * t0, 0.0f);
    float r1 = fmaxf(lamg * t1, 0.0f);
    float r2 = fmaxf(lamg * t2, 0.0f);
    float r3 = fmaxf(lamg * t3, 0.0f);
    float tsq = r0*r0 + r1*r1 + r2*r2 + r3*r3;
#pragma unroll
    for (int o = 1; o < 16; o <<= 1) tsq += __shfl_xor(tsq, o, 64);
    float n2  = fmaxf(sqrtf(tsq), EPSV);
    float th2 = tanhf(n2);
    float g2  = th2 / n2;
    float nh2 = fmaxf(th2, EPSV);
    if (nh2 > MAXN) g2 *= MAXN / nh2;
    *(float4*)(out + (size_t)d * 64 + 4 * sl) =
        make_float4(g2 * r0, g2 * r1, g2 * r2, g2 * r3);
}

// ===== layer 2: MFMA (bf16 W2) fused HypAct+matvec+tail; agg -> xtb2 =====
__global__ __launch_bounds__(256) void hgA_layer2_mfma(
    const float* __restrict__ agg,   // [N,64] fp32 (d_out)
    const bfu* __restrict__ w2b,     // [64,64] bf16 row-major
    const float* __restrict__ b2v,   // [64]
    bfu* __restrict__ xtb2, int N)   // [N,64] bf16 (ws)
{
    const int tid = threadIdx.x, lane = tid & 63, wv = tid >> 6;
    const int nodeBase = (blockIdx.x * 4 + wv) * 16;
    if (nodeBase >= N) return;

    float y2;
    float hb = bias_point(b2v, lane, &y2);
    float hbv[4];
#pragma unroll
    for (int t = 0; t < 4; ++t) hbv[t] = __shfl(hb, (lane & 15) + 16 * t);

    const int m = lane & 15, q = lane >> 4;
    const bool rowok = (nodeBase + m) < N;

    float af0[8], af1[8];
    const float* arow = agg + (size_t)(nodeBase + m) * 64 + q * 8;
    if (rowok) {
        *(float4*)(af0)     = *(const float4*)(arow);
        *(float4*)(af0 + 4) = *(const float4*)(arow + 4);
        *(float4*)(af1)     = *(const float4*)(arow + 32);
        *(float4*)(af1 + 4) = *(const float4*)(arow + 36);
    } else {
#pragma unroll
        for (int j = 0; j < 8; ++j) { af0[j] = 0.0f; af1[j] = 0.0f; }
    }
    float asq = 0.0f;
#pragma unroll
    for (int j = 0; j < 8; ++j) {
        asq = fmaf(af0[j], af0[j], asq);
        asq = fmaf(af1[j], af1[j], asq);
    }
    asq += __shfl_xor(asq, 16, 64);
    asq += __shfl_xor(asq, 32, 64);

    float n  = fmaxf(sqrtf(asq), EPSV);
    float th = tanhf(n);
    float g  = th / n;
    float nh = fmaxf(th, EPSV);
    if (nh > MAXN) { g *= MAXN / nh; nh = MAXN; }
    float lamg = (artanh_(nh) / nh) * g;
    float t0[8], t1[8], tsq = 0.0f;
#pragma unroll
    for (int j = 0; j < 8; ++j) {
        t0[j] = fmaxf(lamg * af0[j], 0.0f);
        t1[j] = fmaxf(lamg * af1[j], 0.0f);
        tsq = fmaf(t0[j], t0[j], tsq);
        tsq = fmaf(t1[j], t1[j], tsq);
    }
    tsq += __shfl_xor(tsq, 16, 64);
    tsq += __shfl_xor(tsq, 32, 64);
    float n2  = fmaxf(sqrtf(tsq), EPSV);
    float th2 = tanhf(n2);
    float g2  = th2 / n2;
    float nh2 = fmaxf(th2, EPSV);
    if (nh2 > MAXN) { g2 *= MAXN / nh2; nh2 = MAXN; }
    float xn_m = nh2;
    float x0[8], x1[8];
#pragma unroll
    for (int j = 0; j < 8; ++j) { x0[j] = g2 * t0[j]; x1[j] = g2 * t1[j]; }
    v8s a0 = cvt8(x0), a1 = cvt8(x1);

    v4f acc0 = {0,0,0,0}, acc1 = {0,0,0,0}, acc2 = {0,0,0,0}, acc3 = {0,0,0,0};
    {
        const bfu* wb;
        wb = w2b + (size_t)(m     ) * 64 + q * 8;
        acc0 = __builtin_amdgcn_mfma_f32_16x16x32_bf16(a0, *(const v8s*)(wb),      acc0, 0, 0, 0);
        acc0 = __builtin_amdgcn_mfma_f32_16x16x32_bf16(a1, *(const v8s*)(wb + 32), acc0, 0, 0, 0);
        wb = w2b + (size_t)(m + 16) * 64 + q * 8;
        acc1 = __builtin_amdgcn_mfma_f32_16x16x32_bf16(a0, *(const v8s*)(wb),      acc1, 0, 0, 0);
        acc1 = __builtin_amdgcn_mfma_f32_16x16x32_bf16(a1, *(const v8s*)(wb + 32), acc1, 0, 0, 0);
        wb = w2b + (size_t)(m + 32) * 64 + q * 8;
        acc2 = __builtin_amdgcn_mfma_f32_16x16x32_bf16(a0, *(const v8s*)(wb),      acc2, 0, 0, 0);
        acc2 = __builtin_amdgcn_mfma_f32_16x16x32_bf16(a1, *(const v8s*)(wb + 32), acc2, 0, 0, 0);
        wb = w2b + (size_t)(m + 48) * 64 + q * 8;
        acc3 = __builtin_amdgcn_mfma_f32_16x16x32_bf16(a0, *(const v8s*)(wb),      acc3, 0, 0, 0);
        acc3 = __builtin_amdgcn_mfma_f32_16x16x32_bf16(a1, *(const v8s*)(wb + 32), acc3, 0, 0, 0);
    }

    float P[4], Q[4];
#pragma unroll
    for (int r = 0; r < 4; ++r) {
        float s2 = acc0[r]*acc0[r] + acc1[r]*acc1[r] + acc2[r]*acc2[r] + acc3[r]*acc3[r];
        float sh = acc0[r]*hbv[0] + acc1[r]*hbv[1] + acc2[r]*hbv[2] + acc3[r]*hbv[3];
#pragma unroll
        for (int o = 1; o < 16; o <<= 1) {
            s2 += __shfl_xor(s2, o, 64);
            sh += __shfl_xor(sh, o, 64);
        }
        float xn = __shfl(xn_m, q * 4 + r);
        float mxn = fmaxf(sqrtf(s2), EPSV);
        float rt  = tanhf(mxn / xn * artanh_(xn));
        float k1, x2s, xy;
        if (s2 != 0.0f) {
            k1 = rt / mxn;
            float mvn = fmaxf(fabsf(rt), EPSV);
            if (mvn > MAXN) k1 *= MAXN / mvn;
            float cn = fminf(mvn, MAXN);
            x2s = cn * cn;
            xy  = k1 * sh;
        } else { k1 = 0.0f; x2s = 0.0f; xy = 0.0f; }
        float ca = 1.0f + 2.0f * xy + y2;
        float cb = 1.0f - x2s;
        float den = fmaxf(1.0f + 2.0f * xy + x2s * y2, EPSV);
        float hn2 = ca*ca*x2s + 2.0f*ca*cb*xy + cb*cb*y2;
        float hn = fmaxf(sqrtf(hn2) / den, EPSV);
        float hs = 1.0f;
        if (hn > MAXN) { hs = MAXN / hn; hn = MAXN; }
        float lam = artanh_(hn) / hn;
        P[r] = lam * hs * ca * k1 / den;
        Q[r] = lam * hs * cb / den;
    }
#pragma unroll
    for (int r = 0; r < 4; ++r) {
        int ri = nodeBase + q * 4 + r;
        if (ri < N) {
            bfu* orow = xtb2 + (size_t)ri * 64 + m;
            orow[ 0] = f2b(P[r] * acc0[r] + Q[r] * hbv[0]);
            orow[16] = f2b(P[r] * acc1[r] + Q[r] * hbv[1]);
            orow[32] = f2b(P[r] * acc2[r] + Q[r] * hbv[2]);
            orow[48] = f2b(P[r] * acc3[r] + Q[r] * hbv[3]);
        }
    }
}

// ===== fallback kernels (round-9 path, fp32 weights, used only if ws tiny) =====
__global__ __launch_bounds__(256) void hgA_layer1_fp32(
    const float* __restrict__ x, const float* __restrict__ W1,
    const float* __restrict__ b1v, float* __restrict__ xt, int N)
{
    const int tid = threadIdx.x, lane = tid & 63, wv = tid >> 6;
    const int nodeBase = (blockIdx.x * 4 + wv) * 16;
    if (nodeBase >= N) return;
    float y2;
    float hb = bias_point(b1v, lane, &y2);
    float hbv[4];
#pragma unroll
    for (int t = 0; t < 4; ++t) hbv[t] = __shfl(hb, (lane & 15) + 16 * t);
    const int m = lane & 15, q = lane >> 4;
    v4f acc0 = {0,0,0,0}, acc1 = {0,0,0,0}, acc2 = {0,0,0,0}, acc3 = {0,0,0,0};
    float usq = 0.0f;
    const float* arow = x + (size_t)(nodeBase + m) * 256 + q * 8;
#pragma unroll
    for (int s = 0; s < 8; ++s) {
        float af[8];
        *(float4*)(af)     = *(const float4*)(arow + s * 32);
        *(float4*)(af + 4) = *(const float4*)(arow + s * 32 + 4);
#pragma unroll
        for (int j = 0; j < 8; ++j) usq = fmaf(af[j], af[j], usq);
        v8s a = cvt8(af);
        const float* wbase = W1 + (size_t)m * 256 + s * 32 + q * 8;
        float wf[8];
        *(float4*)(wf) = *(const float4*)(wbase);  *(float4*)(wf+4) = *(const float4*)(wbase+4);
        acc0 = __builtin_amdgcn_mfma_f32_16x16x32_bf16(a, cvt8(wf), acc0, 0, 0, 0);
        *(float4*)(wf) = *(const float4*)(wbase+16*256); *(float4*)(wf+4) = *(const float4*)(wbase+16*256+4);
        acc1 = __builtin_amdgcn_mfma_f32_16x16x32_bf16(a, cvt8(wf), acc1, 0, 0, 0);
        *(float4*)(wf) = *(const float4*)(wbase+32*256); *(float4*)(wf+4) = *(const float4*)(wbase+32*256+4);
        acc2 = __builtin_amdgcn_mfma_f32_16x16x32_bf16(a, cvt8(wf), acc2, 0, 0, 0);
        *(float4*)(wf) = *(const float4*)(wbase+48*256); *(float4*)(wf+4) = *(const float4*)(wbase+48*256+4);
        acc3 = __builtin_amdgcn_mfma_f32_16x16x32_bf16(a, cvt8(wf), acc3, 0, 0, 0);
    }
    usq += __shfl_xor(usq, 16, 64);
    usq += __shfl_xor(usq, 32, 64);
    float P[4], Q[4];
#pragma unroll
    for (int r = 0; r < 4; ++r) {
        float s2 = acc0[r]*acc0[r] + acc1[r]*acc1[r] + acc2[r]*acc2[r] + acc3[r]*acc3[r];
        float sh = acc0[r]*hbv[0] + acc1[r]*hbv[1] + acc2[r]*hbv[2] + acc3[r]*hbv[3];
#pragma unroll
        for (int o = 1; o < 16; o <<= 1) { s2 += __shfl_xor(s2, o, 64); sh += __shfl_xor(sh, o, 64); }
        float usq_r = __shfl(usq, q * 4 + r);
        float n  = fmaxf(sqrtf(usq_r), EPSV);
        float th = tanhf(n);
        float gamma = th / n;
        float xn = fmaxf(th, EPSV);
        if (xn > MAXN) { gamma *= MAXN / xn; xn = MAXN; }
        float mxn = fmaxf(gamma * sqrtf(s2), EPSV);
        float rt  = tanhf(mxn / xn * artanh_(xn));
        float k1, x2s, xy;
        if (s2 != 0.0f) {
            k1 = (rt / mxn) * gamma;
            float mvn = fmaxf(fabsf(rt), EPSV);
            if (mvn > MAXN) k1 *= MAXN / mvn;
            float cn = fminf(mvn, MAXN);
            x2s = cn * cn; xy = k1 * sh;
        } else { k1 = 0.0f; x2s = 0.0f; xy = 0.0f; }
        float ca = 1.0f + 2.0f * xy + y2;
        float cb = 1.0f - x2s;
        float den = fmaxf(1.0f + 2.0f * xy + x2s * y2, EPSV);
        float hn2 = ca*ca*x2s + 2.0f*ca*cb*xy + cb*cb*y2;
        float hn = fmaxf(sqrtf(hn2) / den, EPSV);
        float hs = 1.0f;
        if (hn > MAXN) { hs = MAXN / hn; hn = MAXN; }
        float lam = artanh_(hn) / hn;
        P[r] = lam * hs * ca * k1 / den;
        Q[r] = lam * hs * cb / den;
    }
#pragma unroll
    for (int r = 0; r < 4; ++r) {
        float* orow = xt + (size_t)(nodeBase + q * 4 + r) * 64 + m;
        orow[ 0] = P[r] * acc0[r] + Q[r] * hbv[0];
        orow[16] = P[r] * acc1[r] + Q[r] * hbv[1];
        orow[32] = P[r] * acc2[r] + Q[r] * hbv[2];
        orow[48] = P[r] * acc3[r] + Q[r] * hbv[3];
    }
}

__global__ __launch_bounds__(256) void hgA_scatter(
    const int* __restrict__ src, const int* __restrict__ dst,
    const float* __restrict__ ew,
    const float* __restrict__ xt, float* __restrict__ agg, int E)
{
    const int lane = threadIdx.x & 63;
    const long long wid = ((long long)blockIdx.x * blockDim.x + threadIdx.x) >> 6;
    const long long nw = ((long long)gridDim.x * blockDim.x) >> 6;
    for (long long e = wid; e < E; e += nw) {
        int s = src[e], d = dst[e];
        atomicAdd(&agg[(size_t)d * 64 + lane], ew[e] * xt[(size_t)s * 64 + lane]);
    }
}

__global__ __launch_bounds__(256) void hgA_layer2_fb(
    const float* __restrict__ agg,
    const float* __restrict__ W2, const float* __restrict__ b2v,
    float* __restrict__ xt2, int N)
{
    const int lane = threadIdx.x & 63, wv = threadIdx.x >> 6;
    float y2;
    float hb = bias_point(b2v, lane, &y2);
    const int nw = gridDim.x * 4;
    for (int i = blockIdx.x * 4 + wv; i < N; i += nw) {
        float a = agg[(size_t)i * 64 + lane];
        float xn;
        float x2 = agg_transform(a, &xn);
        float acc = 0.0f;
        const float* Wrow = W2 + (size_t)lane * 64;
        for (int s = 0; s < 64; ++s)
            acc = fmaf(__shfl(x2, s), Wrow[s], acc);
        float o = mobius_tail(acc, xn, hb, y2);
        xt2[(size_t)i * 64 + lane] = o;
    }
}

__global__ __launch_bounds__(256) void hgA_final_fb(
    const float* __restrict__ agg, float* __restrict__ out, int N)
{
    const int lane = threadIdx.x & 63, wv = threadIdx.x >> 6;
    const int nw = gridDim.x * 4;
    for (int i = blockIdx.x * 4 + wv; i < N; i += nw) {
        float a = agg[(size_t)i * 64 + lane];
        float xn;
        float o = agg_transform(a, &xn);
        out[(size_t)i * 64 + lane] = o;
    }
}

extern "C" void kernel_launch(void* const* d_in, const int* in_sizes, int n_in,
                              void* d_out, int out_size, void* d_ws, size_t ws_size,
                              hipStream_t stream)
{
    const float* x  = (const float*)d_in[0];
    const int* src  = (const int*)d_in[1];
    const int* dst  = (const int*)d_in[2];
    const float* ew = (const float*)d_in[3];
    const float* W1 = (const float*)d_in[4];
    const float* b1 = (const float*)d_in[5];
    const float* W2 = (const float*)d_in[6];
    const float* b2 = (const float*)d_in[7];

    const int Dd = in_sizes[5];            // 64
    const int Ff = in_sizes[4] / Dd;       // 256
    const int N  = in_sizes[0] / Ff;       // 80000
    const int E  = in_sizes[1];            // 1280000
    const int NW1 = Dd * Ff;               // 16384
    const int NW2 = Dd * Dd;               // 4096

    float* out = (float*)d_out;
    float* agg = (float*)d_out;            // CSR path: fp32 agg lives in d_out

    const int NB = (N + 1023) / 1024;      // scan chunks

    const int blkT = (N + 63) / 64;        // wave per 16 nodes (layer kernels)
    const int blkG16 = (N + 15) / 16;      // 16 dst per block (gathers)
    const int blkE4 = (E + 1023) / 1024;   // 4 edges/thread vblocks
    const int prepG = 128 + (NW1 + 255) / 256 + 1;
    const int n4 = (N * Dd) / 4;

    // --- tier A1 layout: [xtb][xb][usq][deg][rowst][rank][bsum][w1b][w2b][csr]
    size_t xtb_b = (size_t)N * Dd * 2;
    size_t xb_b  = (size_t)N * Ff * 2;
    bfu*  xtb   = (bfu*)d_ws;
    bfu*  xbA   = (bfu*)((char*)d_ws + xtb_b);
    float* usqt = (float*)((char*)d_ws + xtb_b + xb_b);
    size_t off1 = xtb_b + xb_b + (size_t)N * 4;
    int*  degA1   = (int*)((char*)d_ws + off1);
    int*  rowstA1 = degA1 + N;
    int*  rankA1  = rowstA1 + (N + 1);
    int*  bsumA1  = rankA1 + E;
    size_t w1_offA1 = (off1 + ((size_t)(2 * N + 1) + (size_t)E + (size_t)NB) * 4 + 15) & ~(size_t)15;
    bfu* w1bA1 = (bfu*)((char*)d_ws + w1_offA1);
    bfu* w2bA1 = w1bA1 + NW1;
    size_t csr_offA1 = (w1_offA1 + (size_t)(NW1 + NW2) * 2 + 7) & ~(size_t)7;
    const size_t needA1 = csr_offA1 + (size_t)E * 8;

    // --- tier A2 layout (round-15): [xtb][deg][rowst][cursor][rank][bsum][w][csr]
    int*  deg    = (int*)((char*)d_ws + xtb_b);
    int*  rowst  = deg + N;
    int*  cursor = rowst + (N + 1);
    int*  rank   = cursor + N;
    int*  bsum   = rank + E;
    size_t wA_off = (xtb_b + ((size_t)(3 * N + 1) + (size_t)E + (size_t)NB) * 4 + 15) & ~(size_t)15;
    bfu* w1bA = (bfu*)((char*)d_ws + wA_off);
    bfu* w2bA = w1bA + NW1;
    size_t csr_offA = (wA_off + (size_t)(NW1 + NW2) * 2 + 7) & ~(size_t)7;
    const size_t needA2 = csr_offA + (size_t)E * 8;

    // --- tier B layout
    size_t wB_off = (xtb_b + (size_t)(3 * N + 1) * 4 + 15) & ~(size_t)15;
    bfu* w1bB = (bfu*)((char*)d_ws + wB_off);
    bfu* w2bB = w1bB + NW1;
    size_t csr_offB = (wB_off + (size_t)(NW1 + NW2) * 2 + 7) & ~(size_t)7;
    const size_t needB = csr_offB + (size_t)E * 8;

    if (ws_size >= needA1) {
        int2* csr = (int2*)((char*)d_ws + csr_offA1);
        int L1S = blkT < 192 ? blkT : 192;     // l1 vblocks hosted by scan1
        int L1F = blkT - L1S;                  // rest hosted by fillr
        hgA_prep      <<<prepG, 256, 0, stream>>>(degA1, N, W1, W2, w1bA1, w2bA1, NW1, NW2);
        hgA_count_xcvt<<<blkE4 + blkT, 256, 0, stream>>>(
            dst, degA1, rankA1, E, blkE4, x, xbA, usqt, blkT, N);
        hgA_scan1     <<<NB + L1S, 256, 0, stream>>>(
            degA1, rowstA1, bsumA1, N, NB, xbA, usqt, w1bA1, b1, xtb, L1S);
        hgA_scan2     <<<1, 64, 0, stream>>>(bsumA1, rowstA1 + N, NB);
        hgA_scan3     <<<NB, 256, 0, stream>>>(rowstA1, bsumA1, N);
        hgA_fillr_l1b <<<blkE4 + L1F, 256, 0, stream>>>(
            src, dst, ew, rankA1, rowstA1, csr, E, blkE4, L1F, L1S,
            xbA, usqt, w1bA1, b1, xtb, N);
        hgA_gather     <<<blkG16, 256, 0, stream>>>(rowstA1, csr, xtb, agg, N);
        hgA_layer2_mfma<<<blkT, 256, 0, stream>>>(agg, w2bA1, b2, xtb, N);
        hgA_gather_out <<<blkG16, 256, 0, stream>>>(rowstA1, csr, xtb, out, N);
    } else if (ws_size >= needA2) {
        int2* csr = (int2*)((char*)d_ws + csr_offA);
        int L1C = blkT < 780 ? blkT : 780;
        int L1F = blkT - L1C;
        hgA_prep        <<<prepG, 256, 0, stream>>>(deg, N, W1, W2, w1bA, w2bA, NW1, NW2);
        hgA_count_rank_l1<<<blkE4 + L1C, 256, 0, stream>>>(
            dst, deg, rank, E, blkE4, L1C, x, w1bA, b1, xtb, N);
        hgA_scan1       <<<NB, 256, 0, stream>>>(deg, rowst, bsum, N, NB,
                                                 (const bfu*)xtb, (const float*)deg,
                                                 w1bA, b1, xtb, 0);
        hgA_scan2       <<<1,   64, 0, stream>>>(bsum, rowst + N, NB);
        hgA_scan3       <<<NB, 256, 0, stream>>>(rowst, bsum, N);
        hgA_fillr_layer1<<<blkE4 + L1F, 256, 0, stream>>>(
            src, dst, ew, rank, rowst, csr, E, blkE4, L1F, L1C,
            x, w1bA, b1, xtb, N);
        hgA_gather     <<<blkG16, 256, 0, stream>>>(rowst, csr, xtb, agg, N);
        hgA_layer2_mfma<<<blkT, 256, 0, stream>>>(agg, w2bA, b2, xtb, N);
        hgA_gather_out <<<blkG16, 256, 0, stream>>>(rowst, csr, xtb, out, N);
    } else if (ws_size >= needB) {
        int2* csr = (int2*)((char*)d_ws + csr_offB);
        const int fillBlocks = 2048;
        hgA_prep       <<<prepG, 256, 0, stream>>>(deg, N, W1, W2, w1bB, w2bB, NW1, NW2);
        hgA_count      <<<2048, 256, 0, stream>>>(dst, deg, E);
        hgA_scan_l1    <<<1,   1024, 0, stream>>>(
            deg, rowst, cursor, N, x, w1bB, b1, xtb, 0);
        hgA_fill_layer1<<<fillBlocks + blkT, 256, 0, stream>>>(
            src, dst, ew, cursor, csr, E, fillBlocks, x, w1bB, b1, xtb, N);
        hgA_gather     <<<blkG16, 256, 0, stream>>>(rowst, csr, xtb, agg, N);
        hgA_layer2_mfma<<<blkT, 256, 0, stream>>>(agg, w2bB, b2, xtb, N);
        hgA_gather_out <<<blkG16, 256, 0, stream>>>(rowst, csr, xtb, out, N);
    } else {
        // round-9 fallback: xt fp32 in d_out, agg fp32 in ws
        float* xt_fb  = (float*)d_out;
        float* agg_fb = (float*)d_ws;
        hgA_layer1_fp32<<<blkT, 256, 0, stream>>>(x, W1, b1, xt_fb, N);
        hgA_zero     <<<1024,  256, 0, stream>>>(agg_fb, n4);
        hgA_scatter  <<<16384, 256, 0, stream>>>(src, dst, ew, xt_fb, agg_fb, E);
        hgA_layer2_fb<<<2048,  256, 0, stream>>>(agg_fb, W2, b2, xt_fb, N);
        hgA_zero     <<<1024,  256, 0, stream>>>(agg_fb, n4);
        hgA_scatter  <<<16384, 256, 0, stream>>>(src, dst, ew, xt_fb, agg_fb, E);
        hgA_final_fb <<<2048,  256, 0, stream>>>(agg_fb, out, N);
    }
}